// Round 7
// baseline (445.156 us; speedup 1.0000x reference)
//
#include <hip/hip_runtime.h>
#include <hip/hip_bf16.h>
#include <math.h>

#define N_NODES 100000
#define N_EDGES 1600000
#define IN_F 128
#define HID_F 128
#define OUT_F 64
#define K_TOT 384                          // 3 basis planes x 128
#define NB_SCAN ((N_NODES + 255) / 256)    // 391
#define XLDS_STRIDE 132                    // 128 + 4 pad -> conflict-free b128 reads

// bucket sort parameters
#define BK_BITS 9
#define BK_SIZE 512                        // nodes per bucket
#define NBUCK ((N_NODES + BK_SIZE - 1) / BK_SIZE)   // 196
#define EPB 4096                           // edges per sort block
#define NBLK_SORT ((N_EDGES + EPB - 1) / EPB)       // 391
// packed edge record: [31:23] local tgt (9b), [22:0] src (17b used)
#define PK_SRC_MASK 0x7fffffu

typedef __attribute__((ext_vector_type(8))) short s8v;   // 8 bf16 (MFMA A/B frag)
typedef __attribute__((ext_vector_type(4))) float f4v;   // MFMA C/D frag

__device__ __forceinline__ short f2bf(float f) {
    __hip_bfloat16 h = __float2bfloat16(f);
    return __builtin_bit_cast(short, h);
}
__device__ __forceinline__ float bfhi2f(unsigned u) {
    return __builtin_bit_cast(float, u & 0xffff0000u);
}
__device__ __forceinline__ float bflo2f(unsigned u) {
    return __builtin_bit_cast(float, u << 16);
}

// ---------------------------------------------------------------------------
// Fold KAN weights into bf16 MFMA-B chunk layout: Wb[c][n][8], c = k>>3.
// ---------------------------------------------------------------------------
__global__ __launch_bounds__(256) void fold_weights_bf16(
    const float* __restrict__ w1, const float* __restrict__ c1,
    const float* __restrict__ w2, const float* __restrict__ c2,
    short* __restrict__ Wb1, short* __restrict__ Wb2)
{
    int idx = blockIdx.x * 256 + threadIdx.x;
    if (idx < K_TOT * HID_F) {
        int k = idx >> 7, n = idx & 127;
        int p = k >> 7, f = k & 127;
        int si = f * HID_F + n;
        float v = (p == 0) ? (w1[si] + 0.1f * c1[si * 3])
                           : 0.1f * c1[si * 3 + p];
        Wb1[(((k >> 3) * HID_F) + n) * 8 + (k & 7)] = f2bf(v);
    } else {
        idx -= K_TOT * HID_F;
        if (idx < K_TOT * OUT_F) {
            int k = idx >> 6, n = idx & 63;
            int p = k >> 7, f = k & 127;
            int si = f * OUT_F + n;
            float v = (p == 0) ? (w2[si] + 0.1f * c2[si * 3])
                               : 0.1f * c2[si * 3 + p];
            Wb2[(((k >> 3) * OUT_F) + n) * 8 + (k & 7)] = f2bf(v);
        }
    }
}

// ---------------------------------------------------------------------------
// Bucket sort pass A: coarse histogram (LDS) -> global bucket counts.
// ---------------------------------------------------------------------------
__global__ __launch_bounds__(256) void bucket_hist(
    const int* __restrict__ tgt, int* __restrict__ bucket_cnt)
{
    __shared__ int h[NBUCK];
    int tid = threadIdx.x;
    for (int i = tid; i < NBUCK; i += 256) h[i] = 0;
    __syncthreads();
    int e0 = blockIdx.x * EPB;
    int n = min(EPB, N_EDGES - e0);
    for (int i = tid; i < n; i += 256)
        atomicAdd(&h[tgt[e0 + i] >> BK_BITS], 1);
    __syncthreads();
    for (int i = tid; i < NBUCK; i += 256)
        if (h[i]) atomicAdd(&bucket_cnt[i], h[i]);
}

// Pass B: single-block exclusive scan of bucket counts -> offsets + cursors.
__global__ __launch_bounds__(256) void bucket_scan(
    const int* __restrict__ cnt, int* __restrict__ boff, int* __restrict__ bcur)
{
    __shared__ int s[256];
    int tid = threadIdx.x;
    int v = (tid < NBUCK) ? cnt[tid] : 0;
    s[tid] = v;
    __syncthreads();
    for (int o = 1; o < 256; o <<= 1) {
        int t = (tid >= o) ? s[tid - o] : 0;
        __syncthreads();
        s[tid] += t;
        __syncthreads();
    }
    int excl = s[tid] - v;
    if (tid < NBUCK) { boff[tid] = excl; bcur[tid] = excl; }
    if (tid == NBUCK - 1) boff[NBUCK] = excl + v;
}

// Pass C: scatter edges into bucket-sorted packed records (9b tgt | 23b src).
__global__ __launch_bounds__(256) void bucket_scatter(
    const int* __restrict__ src, const int* __restrict__ tgt,
    int* __restrict__ bcur, unsigned* __restrict__ spk)
{
    __shared__ int h[NBUCK];
    __shared__ int base[NBUCK];
    int tid = threadIdx.x;
    for (int i = tid; i < NBUCK; i += 256) h[i] = 0;
    __syncthreads();
    int e0 = blockIdx.x * EPB;
    int n = min(EPB, N_EDGES - e0);
    for (int i = tid; i < n; i += 256)
        atomicAdd(&h[tgt[e0 + i] >> BK_BITS], 1);
    __syncthreads();
    for (int i = tid; i < NBUCK; i += 256) {
        int c = h[i];
        base[i] = c ? atomicAdd(&bcur[i], c) : 0;
        h[i] = 0;
    }
    __syncthreads();
    for (int i = tid; i < n; i += 256) {
        int t = tgt[e0 + i];
        int b = t >> BK_BITS;
        int pos = base[b] + atomicAdd(&h[b], 1);
        spk[pos] = ((unsigned)(t - (b << BK_BITS)) << 23) | (unsigned)src[e0 + i];
    }
}

// Pass D: per-bucket degree via LDS histogram.
__global__ __launch_bounds__(256) void bucket_deg(
    const int* __restrict__ boff, const unsigned* __restrict__ spk,
    int* __restrict__ deg)
{
    __shared__ int d[BK_SIZE];
    int tid = threadIdx.x;
    int b = blockIdx.x;
    for (int i = tid; i < BK_SIZE; i += 256) d[i] = 0;
    __syncthreads();
    int e0 = boff[b], e1 = boff[b + 1];
    for (int i = e0 + tid; i < e1; i += 256)
        atomicAdd(&d[spk[i] >> 23], 1);
    __syncthreads();
    int nbase = b << BK_BITS;
    for (int i = tid; i < BK_SIZE; i += 256) {
        int nd = nbase + i;
        if (nd < N_NODES) deg[nd] = d[i];
    }
}

// ---------------------------------------------------------------------------
// row_start scan over deg (3-kernel).
// ---------------------------------------------------------------------------
__global__ __launch_bounds__(256) void scan_bsum(
    const int* __restrict__ deg, int* __restrict__ bsum, int n)
{
    __shared__ int s[256];
    int tid = threadIdx.x;
    int i = blockIdx.x * 256 + tid;
    s[tid] = (i < n) ? deg[i] : 0;
    __syncthreads();
    for (int o = 128; o > 0; o >>= 1) {
        if (tid < o) s[tid] += s[tid + o];
        __syncthreads();
    }
    if (tid == 0) bsum[blockIdx.x] = s[0];
}

__global__ __launch_bounds__(512) void scan_top(int* __restrict__ bsum, int nb)
{
    __shared__ int s[512];
    int tid = threadIdx.x;
    int v = (tid < nb) ? bsum[tid] : 0;
    s[tid] = v;
    __syncthreads();
    for (int o = 1; o < 512; o <<= 1) {
        int t = (tid >= o) ? s[tid - o] : 0;
        __syncthreads();
        s[tid] += t;
        __syncthreads();
    }
    if (tid < nb) bsum[tid] = s[tid] - v;   // exclusive
}

__global__ __launch_bounds__(256) void scan_final(
    const int* __restrict__ deg, const int* __restrict__ bsum,
    int* __restrict__ row_start, int n)
{
    __shared__ int s[256];
    int tid = threadIdx.x;
    int i = blockIdx.x * 256 + tid;
    int v = (i < n) ? deg[i] : 0;
    s[tid] = v;
    __syncthreads();
    for (int o = 1; o < 256; o <<= 1) {
        int t = (tid >= o) ? s[tid - o] : 0;
        __syncthreads();
        s[tid] += t;
        __syncthreads();
    }
    int excl = s[tid] - v + bsum[blockIdx.x];
    if (i < n) row_start[i] = excl;
    if (i == n - 1) row_start[n] = excl + v;
}

// Pass E: fine CSR fill (LDS cursors, contiguous write window per block).
__global__ __launch_bounds__(256) void csr_fine(
    const int* __restrict__ boff, const unsigned* __restrict__ spk,
    const int* __restrict__ row_start, int* __restrict__ csr_src)
{
    __shared__ int cur[BK_SIZE];
    int tid = threadIdx.x;
    int b = blockIdx.x;
    int nbase = b << BK_BITS;
    for (int i = tid; i < BK_SIZE; i += 256) {
        int nd = nbase + i;
        cur[i] = (nd < N_NODES) ? row_start[nd] : 0;
    }
    __syncthreads();
    int e0 = boff[b], e1 = boff[b + 1];
    for (int i = e0 + tid; i < e1; i += 256) {
        unsigned pk = spk[i];
        int pos = atomicAdd(&cur[pk >> 23], 1);
        csr_src[pos] = (int)(pk & PK_SRC_MASK);
    }
}

// ---------------------------------------------------------------------------
// KAN1 via MFMA bf16 (block = 64 nodes x 128 out, 4 waves 2x2).
// ---------------------------------------------------------------------------
__global__ __launch_bounds__(256) void kan1_mfma(
    const float* __restrict__ x, const short* __restrict__ Wb,
    const float* __restrict__ bias, short* __restrict__ h1)
{
    __shared__ float sx[64 * XLDS_STRIDE];
    const int tid  = threadIdx.x;
    const int lane = tid & 63;
    const int wave = tid >> 6;
    const int node0 = blockIdx.x * 64;
    const int q = lane >> 4, r = lane & 15;

#pragma unroll
    for (int it = 0; it < 8; ++it) {
        int idx = tid + 256 * it;
        int m = idx >> 5, c4 = (idx & 31) * 4;
        int gm = min(node0 + m, N_NODES - 1);
        float4 v = *(const float4*)(x + (size_t)gm * IN_F + c4);
        *(float4*)(sx + m * XLDS_STRIDE + c4) = v;
    }
    __syncthreads();

    const int wm = (wave & 1) * 32;
    const int wn = (wave >> 1) * 64;

    f4v acc[2][4];
#pragma unroll
    for (int i = 0; i < 2; ++i)
#pragma unroll
        for (int j = 0; j < 4; ++j)
            acc[i][j] = (f4v){0.f, 0.f, 0.f, 0.f};

    float bj[4];
#pragma unroll
    for (int j = 0; j < 4; ++j) bj[j] = bias[wn + j * 16 + r];

#pragma unroll
    for (int kb = 0; kb < 12; ++kb) {
        const int p  = kb >> 2;
        const int f0 = (kb & 3) * 32 + q * 8;

        s8v afrag[2];
#pragma unroll
        for (int i = 0; i < 2; ++i) {
            const float* xs = sx + (wm + i * 16 + r) * XLDS_STRIDE + f0;
            float4 v0 = *(const float4*)xs;
            float4 v1 = *(const float4*)(xs + 4);
            float v[8] = {v0.x, v0.y, v0.z, v0.w, v1.x, v1.y, v1.z, v1.w};
            s8v a;
#pragma unroll
            for (int t = 0; t < 8; ++t) {
                float e = v[t];
                if (p >= 1) e *= v[t];
                if (p == 2) e *= v[t];
                a[t] = f2bf(e);
            }
            afrag[i] = a;
        }
#pragma unroll
        for (int j = 0; j < 4; ++j) {
            const s8v b = *(const s8v*)(Wb + (((kb * 4 + q) * HID_F) + wn + j * 16 + r) * 8);
            acc[0][j] = __builtin_amdgcn_mfma_f32_16x16x32_bf16(afrag[0], b, acc[0][j], 0, 0, 0);
            acc[1][j] = __builtin_amdgcn_mfma_f32_16x16x32_bf16(afrag[1], b, acc[1][j], 0, 0, 0);
        }
    }

#pragma unroll
    for (int i = 0; i < 2; ++i)
#pragma unroll
        for (int j = 0; j < 4; ++j)
#pragma unroll
            for (int e = 0; e < 4; ++e) {
                int grow = node0 + wm + i * 16 + q * 4 + e;
                if (grow < N_NODES) {
                    int gcol = wn + j * 16 + r;
                    h1[(size_t)grow * HID_F + gcol] =
                        f2bf(fmaxf(acc[i][j][e] + bj[j], 0.f));
                }
            }
}

// ---------------------------------------------------------------------------
// FUSED aggregate-1 + KAN2.  Block = 64 nodes.
// Phase 1: each wave gathers 16 nodes (8-chain MLP gather of bf16 h1 rows),
//          scales by 1/deg (from row_start diff), writes fp32 rows to LDS.
// Phase 2: kan2 MFMA from the LDS tile (identical math to the old kan2).
// Removes the a1 global round-trip (~100 MB HBM traffic).
// ---------------------------------------------------------------------------
__global__ __launch_bounds__(256) void agg_kan2(
    const unsigned* __restrict__ h1u, const int* __restrict__ row_start,
    const int* __restrict__ csr_src, const short* __restrict__ Wb,
    const float* __restrict__ bias, short* __restrict__ h2)
{
    __shared__ float sx[64 * XLDS_STRIDE];
    const int tid  = threadIdx.x;
    const int lane = tid & 63;
    const int wave = tid >> 6;
    const int node0 = blockIdx.x * 64;
    const int q = lane >> 4, r = lane & 15;

    // ---- phase 1: gather 16 nodes per wave ----
    for (int i = 0; i < 16; ++i) {
        const int m = wave * 16 + i;
        const int node = node0 + m;
        float ax[8], ay[8];
#pragma unroll
        for (int t = 0; t < 8; ++t) { ax[t] = 0.f; ay[t] = 0.f; }
        float di = 0.f;
        if (node < N_NODES) {
            int e0 = row_start[node], e1 = row_start[node + 1];
            di = 1.0f / fmaxf((float)(e1 - e0), 1.0f);
            for (int base = e0; base < e1; base += 64) {
                int idx = base + lane;
                int sreg = (idx < e1) ? csr_src[idx] : 0;
                int cnt = min(64, e1 - base);
                int j = 0;
                for (; j + 8 <= cnt; j += 8) {
                    unsigned u[8];
#pragma unroll
                    for (int t = 0; t < 8; ++t) {
                        int sj = __shfl(sreg, j + t);
                        u[t] = h1u[(size_t)sj * 64 + lane];
                    }
#pragma unroll
                    for (int t = 0; t < 8; ++t) {
                        ax[t] += bflo2f(u[t]);
                        ay[t] += bfhi2f(u[t]);
                    }
                }
                for (; j < cnt; ++j) {
                    int sj = __shfl(sreg, j);
                    unsigned u = h1u[(size_t)sj * 64 + lane];
                    ax[0] += bflo2f(u);
                    ay[0] += bfhi2f(u);
                }
            }
        }
        float vx = (((ax[0] + ax[1]) + (ax[2] + ax[3])) +
                    ((ax[4] + ax[5]) + (ax[6] + ax[7]))) * di;
        float vy = (((ay[0] + ay[1]) + (ay[2] + ay[3])) +
                    ((ay[4] + ay[5]) + (ay[6] + ay[7]))) * di;
        float2 wv; wv.x = vx; wv.y = vy;
        *(float2*)(sx + m * XLDS_STRIDE + 2 * lane) = wv;
    }
    __syncthreads();

    // ---- phase 2: KAN2 MFMA ----
    const int wm = (wave & 1) * 32;
    const int wn = (wave >> 1) * 32;

    f4v acc[2][2];
#pragma unroll
    for (int i = 0; i < 2; ++i)
#pragma unroll
        for (int j = 0; j < 2; ++j)
            acc[i][j] = (f4v){0.f, 0.f, 0.f, 0.f};

    float bj[2];
#pragma unroll
    for (int j = 0; j < 2; ++j) bj[j] = bias[wn + j * 16 + r];

#pragma unroll
    for (int kb = 0; kb < 12; ++kb) {
        const int p  = kb >> 2;
        const int f0 = (kb & 3) * 32 + q * 8;

        s8v afrag[2];
#pragma unroll
        for (int i = 0; i < 2; ++i) {
            const float* xs = sx + (wm + i * 16 + r) * XLDS_STRIDE + f0;
            float4 v0 = *(const float4*)xs;
            float4 v1 = *(const float4*)(xs + 4);
            float v[8] = {v0.x, v0.y, v0.z, v0.w, v1.x, v1.y, v1.z, v1.w};
            s8v a;
#pragma unroll
            for (int t = 0; t < 8; ++t) {
                float e = v[t];
                if (p >= 1) e *= v[t];
                if (p == 2) e *= v[t];
                a[t] = f2bf(e);
            }
            afrag[i] = a;
        }
#pragma unroll
        for (int j = 0; j < 2; ++j) {
            const s8v b = *(const s8v*)(Wb + (((kb * 4 + q) * OUT_F) + wn + j * 16 + r) * 8);
            acc[0][j] = __builtin_amdgcn_mfma_f32_16x16x32_bf16(afrag[0], b, acc[0][j], 0, 0, 0);
            acc[1][j] = __builtin_amdgcn_mfma_f32_16x16x32_bf16(afrag[1], b, acc[1][j], 0, 0, 0);
        }
    }

#pragma unroll
    for (int i = 0; i < 2; ++i)
#pragma unroll
        for (int j = 0; j < 2; ++j)
#pragma unroll
            for (int e = 0; e < 4; ++e) {
                int grow = node0 + wm + i * 16 + q * 4 + e;
                if (grow < N_NODES) {
                    int gcol = wn + j * 16 + r;
                    h2[(size_t)grow * OUT_F + gcol] = f2bf(acc[i][j][e] + bj[j]);
                }
            }
}

// ---------------------------------------------------------------------------
// Gather-aggregate over 64 bf16 feats fused with 1/deg + log_softmax.
// 8 accumulator chains; deg derived from row_start.
// ---------------------------------------------------------------------------
__global__ __launch_bounds__(256) void gather64_lsm(
    const unsigned short* __restrict__ h2u, const int* __restrict__ row_start,
    const int* __restrict__ csr_src, float* __restrict__ out)
{
    const int lane = threadIdx.x & 63;
    const int wave = threadIdx.x >> 6;
    const int node = blockIdx.x * 4 + wave;
    if (node >= N_NODES) return;

    int e0 = row_start[node], e1 = row_start[node + 1];
    float a[8];
#pragma unroll
    for (int t = 0; t < 8; ++t) a[t] = 0.f;

    for (int base = e0; base < e1; base += 64) {
        int idx = base + lane;
        int sreg = (idx < e1) ? csr_src[idx] : 0;
        int cnt = min(64, e1 - base);
        int j = 0;
        for (; j + 8 <= cnt; j += 8) {
            unsigned short u[8];
#pragma unroll
            for (int t = 0; t < 8; ++t) {
                int sj = __shfl(sreg, j + t);
                u[t] = h2u[(size_t)sj * OUT_F + lane];
            }
#pragma unroll
            for (int t = 0; t < 8; ++t)
                a[t] += bflo2f((unsigned)u[t]);
        }
        for (; j < cnt; ++j) {
            int sj = __shfl(sreg, j);
            a[0] += bflo2f((unsigned)h2u[(size_t)sj * OUT_F + lane]);
        }
    }
    float acc = ((a[0] + a[1]) + (a[2] + a[3])) + ((a[4] + a[5]) + (a[6] + a[7]));

    float di = 1.0f / fmaxf((float)(e1 - e0), 1.0f);
    float v = acc * di;

    float m = v;
#pragma unroll
    for (int off = 32; off >= 1; off >>= 1)
        m = fmaxf(m, __shfl_xor(m, off));
    float e = expf(v - m);
    float s = e;
#pragma unroll
    for (int off = 32; off >= 1; off >>= 1)
        s += __shfl_xor(s, off);
    out[(size_t)node * OUT_F + lane] = v - m - logf(s);
}

// ---------------------------------------------------------------------------
extern "C" void kernel_launch(void* const* d_in, const int* in_sizes, int n_in,
                              void* d_out, int out_size, void* d_ws, size_t ws_size,
                              hipStream_t stream)
{
    const float* x  = (const float*)d_in[0];
    const int*   ei = (const int*)d_in[1];
    const float* w1 = (const float*)d_in[2];
    const float* b1 = (const float*)d_in[3];
    const float* c1 = (const float*)d_in[4];
    const float* w2 = (const float*)d_in[5];
    const float* b2 = (const float*)d_in[6];
    const float* c2 = (const float*)d_in[7];
    float* out = (float*)d_out;

    const int* src = ei;            // edge_index[0]
    const int* tgt = ei + N_EDGES;  // edge_index[1]

    char* ws = (char*)d_ws;
    size_t off = 0;
    auto carve = [&](size_t bytes) -> void* {
        void* p = ws + off;
        off = (off + bytes + 255) & ~(size_t)255;
        return p;
    };
    short*    Wb1       = (short*)carve((size_t)K_TOT * HID_F * 2);
    short*    Wb2       = (short*)carve((size_t)K_TOT * OUT_F * 2);
    int*      deg       = (int*)carve((size_t)N_NODES * 4);
    int*      row_start = (int*)carve(((size_t)N_NODES + 1) * 4);
    int*      bsum      = (int*)carve((size_t)NB_SCAN * 4);
    int*      bucket_cnt= (int*)carve((size_t)NBUCK * 4);
    int*      boff      = (int*)carve(((size_t)NBUCK + 1) * 4);
    int*      bcur      = (int*)carve((size_t)NBUCK * 4);
    unsigned* spk       = (unsigned*)carve((size_t)N_EDGES * 4);
    int*      csr_src   = (int*)carve((size_t)N_EDGES * 4);
    short*    h1        = (short*)carve((size_t)N_NODES * HID_F * 2);   // bf16
    short*    h2        = (short*)carve((size_t)N_NODES * OUT_F * 2);   // bf16

    const int grid_mm = (N_NODES + 63) / 64;   // 1563

    // --- CSR build via bucket sort ------------------------------------------
    hipMemsetAsync(bucket_cnt, 0, (size_t)NBUCK * 4, stream);
    bucket_hist<<<NBLK_SORT, 256, 0, stream>>>(tgt, bucket_cnt);
    bucket_scan<<<1, 256, 0, stream>>>(bucket_cnt, boff, bcur);
    bucket_scatter<<<NBLK_SORT, 256, 0, stream>>>(src, tgt, bcur, spk);
    bucket_deg<<<NBUCK, 256, 0, stream>>>(boff, spk, deg);
    scan_bsum<<<NB_SCAN, 256, 0, stream>>>(deg, bsum, N_NODES);
    scan_top<<<1, 512, 0, stream>>>(bsum, NB_SCAN);
    scan_final<<<NB_SCAN, 256, 0, stream>>>(deg, bsum, row_start, N_NODES);
    csr_fine<<<NBUCK, 256, 0, stream>>>(boff, spk, row_start, csr_src);

    // --- weights + layer 1 ---------------------------------------------------
    fold_weights_bf16<<<(K_TOT * HID_F + K_TOT * OUT_F + 255) / 256, 256, 0, stream>>>(
        w1, c1, w2, c2, Wb1, Wb2);
    kan1_mfma<<<grid_mm, 256, 0, stream>>>(x, Wb1, b1, h1);

    // --- aggregate-1 + layer 2 (fused) ---------------------------------------
    agg_kan2<<<grid_mm, 256, 0, stream>>>(
        (const unsigned*)h1, row_start, csr_src, Wb2, b2, h2);

    // --- aggregate 2 + log_softmax (fused) -----------------------------------
    gather64_lsm<<<(N_NODES + 3) / 4, 256, 0, stream>>>(
        (const unsigned short*)h2, row_start, csr_src, out);
}

// Round 8
// 339.211 us; speedup vs baseline: 1.3123x; 1.3123x over previous
//
#include <hip/hip_runtime.h>
#include <hip/hip_bf16.h>
#include <math.h>

#define N_NODES 100000
#define N_EDGES 1600000
#define IN_F 128
#define HID_F 128
#define OUT_F 64
#define K_TOT 384                          // 3 basis planes x 128
#define XLDS_STRIDE 132                    // 128 + 4 pad -> conflict-free b128 reads

// bucket sort parameters
#define BK_BITS 9
#define BK_SIZE 512                        // nodes per bucket
#define NBUCK ((N_NODES + BK_SIZE - 1) / BK_SIZE)   // 196
#define EPB 4096                           // edges per sort block
#define NBLK_SORT ((N_EDGES + EPB - 1) / EPB)       // 391
// packed edge record: [31:23] local tgt (9b), [22:0] src (17b used)
#define PK_SRC_MASK 0x7fffffu

typedef __attribute__((ext_vector_type(8))) short s8v;   // 8 bf16 (MFMA A/B frag)
typedef __attribute__((ext_vector_type(4))) float f4v;   // MFMA C/D frag

__device__ __forceinline__ short f2bf(float f) {
    __hip_bfloat16 h = __float2bfloat16(f);
    return __builtin_bit_cast(short, h);
}
__device__ __forceinline__ float bfhi2f(unsigned u) {
    return __builtin_bit_cast(float, u & 0xffff0000u);
}
__device__ __forceinline__ float bflo2f(unsigned u) {
    return __builtin_bit_cast(float, u << 16);
}

// ---------------------------------------------------------------------------
// Fold KAN weights into bf16 MFMA-B chunk layout: Wb[c][n][8], c = k>>3.
// ---------------------------------------------------------------------------
__global__ __launch_bounds__(256) void fold_weights_bf16(
    const float* __restrict__ w1, const float* __restrict__ c1,
    const float* __restrict__ w2, const float* __restrict__ c2,
    short* __restrict__ Wb1, short* __restrict__ Wb2)
{
    int idx = blockIdx.x * 256 + threadIdx.x;
    if (idx < K_TOT * HID_F) {
        int k = idx >> 7, n = idx & 127;
        int p = k >> 7, f = k & 127;
        int si = f * HID_F + n;
        float v = (p == 0) ? (w1[si] + 0.1f * c1[si * 3])
                           : 0.1f * c1[si * 3 + p];
        Wb1[(((k >> 3) * HID_F) + n) * 8 + (k & 7)] = f2bf(v);
    } else {
        idx -= K_TOT * HID_F;
        if (idx < K_TOT * OUT_F) {
            int k = idx >> 6, n = idx & 63;
            int p = k >> 7, f = k & 127;
            int si = f * OUT_F + n;
            float v = (p == 0) ? (w2[si] + 0.1f * c2[si * 3])
                               : 0.1f * c2[si * 3 + p];
            Wb2[(((k >> 3) * OUT_F) + n) * 8 + (k & 7)] = f2bf(v);
        }
    }
}

// ---------------------------------------------------------------------------
// Bucket sort pass A: coarse histogram (LDS) -> global bucket counts.
// ---------------------------------------------------------------------------
__global__ __launch_bounds__(256) void bucket_hist(
    const int* __restrict__ tgt, int* __restrict__ bucket_cnt)
{
    __shared__ int h[NBUCK];
    int tid = threadIdx.x;
    for (int i = tid; i < NBUCK; i += 256) h[i] = 0;
    __syncthreads();
    int e0 = blockIdx.x * EPB;
    int n = min(EPB, N_EDGES - e0);
    for (int i = tid; i < n; i += 256)
        atomicAdd(&h[tgt[e0 + i] >> BK_BITS], 1);
    __syncthreads();
    for (int i = tid; i < NBUCK; i += 256)
        if (h[i]) atomicAdd(&bucket_cnt[i], h[i]);
}

// Pass B: single-block exclusive scan of bucket counts -> offsets + cursors.
__global__ __launch_bounds__(256) void bucket_scan(
    const int* __restrict__ cnt, int* __restrict__ boff, int* __restrict__ bcur)
{
    __shared__ int s[256];
    int tid = threadIdx.x;
    int v = (tid < NBUCK) ? cnt[tid] : 0;
    s[tid] = v;
    __syncthreads();
    for (int o = 1; o < 256; o <<= 1) {
        int t = (tid >= o) ? s[tid - o] : 0;
        __syncthreads();
        s[tid] += t;
        __syncthreads();
    }
    int excl = s[tid] - v;
    if (tid < NBUCK) { boff[tid] = excl; bcur[tid] = excl; }
    if (tid == NBUCK - 1) boff[NBUCK] = excl + v;
}

// Pass C: scatter edges into bucket-sorted packed records (9b tgt | 23b src).
__global__ __launch_bounds__(256) void bucket_scatter(
    const int* __restrict__ src, const int* __restrict__ tgt,
    int* __restrict__ bcur, unsigned* __restrict__ spk)
{
    __shared__ int h[NBUCK];
    __shared__ int base[NBUCK];
    int tid = threadIdx.x;
    for (int i = tid; i < NBUCK; i += 256) h[i] = 0;
    __syncthreads();
    int e0 = blockIdx.x * EPB;
    int n = min(EPB, N_EDGES - e0);
    for (int i = tid; i < n; i += 256)
        atomicAdd(&h[tgt[e0 + i] >> BK_BITS], 1);
    __syncthreads();
    for (int i = tid; i < NBUCK; i += 256) {
        int c = h[i];
        base[i] = c ? atomicAdd(&bcur[i], c) : 0;
        h[i] = 0;
    }
    __syncthreads();
    for (int i = tid; i < n; i += 256) {
        int t = tgt[e0 + i];
        int b = t >> BK_BITS;
        int pos = base[b] + atomicAdd(&h[b], 1);
        spk[pos] = ((unsigned)(t - (b << BK_BITS)) << 23) | (unsigned)src[e0 + i];
    }
}

// Pass D (fused deg + row_start): per-bucket LDS degree histogram, then a
// block-level exclusive scan; row_start[node] = boff[b] + local_prefix.
// Valid because buckets partition nodes contiguously AND spk is
// bucket-grouped.  Replaces bucket_deg + scan_bsum + scan_top + scan_final.
__global__ __launch_bounds__(256) void bucket_rowstart(
    const int* __restrict__ boff, const unsigned* __restrict__ spk,
    int* __restrict__ row_start)
{
    __shared__ int d[BK_SIZE];
    __shared__ int s[256];
    int tid = threadIdx.x;
    int b = blockIdx.x;
    d[tid] = 0; d[tid + 256] = 0;
    __syncthreads();
    int e0 = boff[b], e1 = boff[b + 1];
    for (int i = e0 + tid; i < e1; i += 256)
        atomicAdd(&d[spk[i] >> 23], 1);
    __syncthreads();
    // exclusive scan of 512 counters (2 per thread)
    int a0 = d[2 * tid], a1c = d[2 * tid + 1];
    int tsum = a0 + a1c;
    s[tid] = tsum;
    __syncthreads();
    for (int o = 1; o < 256; o <<= 1) {
        int t = (tid >= o) ? s[tid - o] : 0;
        __syncthreads();
        s[tid] += t;
        __syncthreads();
    }
    int excl = s[tid] - tsum;
    int nbase = b << BK_BITS;
    int rs0 = e0 + excl;
    if (nbase + 2 * tid < N_NODES)     row_start[nbase + 2 * tid] = rs0;
    if (nbase + 2 * tid + 1 < N_NODES) row_start[nbase + 2 * tid + 1] = rs0 + a0;
    if (b == NBUCK - 1 && tid == 0)    row_start[N_NODES] = boff[NBUCK];
}

// Pass E: fine CSR fill (LDS cursors, contiguous write window per block).
__global__ __launch_bounds__(256) void csr_fine(
    const int* __restrict__ boff, const unsigned* __restrict__ spk,
    const int* __restrict__ row_start, int* __restrict__ csr_src)
{
    __shared__ int cur[BK_SIZE];
    int tid = threadIdx.x;
    int b = blockIdx.x;
    int nbase = b << BK_BITS;
    for (int i = tid; i < BK_SIZE; i += 256) {
        int nd = nbase + i;
        cur[i] = (nd < N_NODES) ? row_start[nd] : 0;
    }
    __syncthreads();
    int e0 = boff[b], e1 = boff[b + 1];
    for (int i = e0 + tid; i < e1; i += 256) {
        unsigned pk = spk[i];
        int pos = atomicAdd(&cur[pk >> 23], 1);
        csr_src[pos] = (int)(pk & PK_SRC_MASK);
    }
}

// ---------------------------------------------------------------------------
// KAN1 via MFMA bf16 (block = 64 nodes x 128 out, 4 waves 2x2).
// ---------------------------------------------------------------------------
__global__ __launch_bounds__(256) void kan1_mfma(
    const float* __restrict__ x, const short* __restrict__ Wb,
    const float* __restrict__ bias, short* __restrict__ h1)
{
    __shared__ float sx[64 * XLDS_STRIDE];
    const int tid  = threadIdx.x;
    const int lane = tid & 63;
    const int wave = tid >> 6;
    const int node0 = blockIdx.x * 64;
    const int q = lane >> 4, r = lane & 15;

#pragma unroll
    for (int it = 0; it < 8; ++it) {
        int idx = tid + 256 * it;
        int m = idx >> 5, c4 = (idx & 31) * 4;
        int gm = min(node0 + m, N_NODES - 1);
        float4 v = *(const float4*)(x + (size_t)gm * IN_F + c4);
        *(float4*)(sx + m * XLDS_STRIDE + c4) = v;
    }
    __syncthreads();

    const int wm = (wave & 1) * 32;
    const int wn = (wave >> 1) * 64;

    f4v acc[2][4];
#pragma unroll
    for (int i = 0; i < 2; ++i)
#pragma unroll
        for (int j = 0; j < 4; ++j)
            acc[i][j] = (f4v){0.f, 0.f, 0.f, 0.f};

    float bj[4];
#pragma unroll
    for (int j = 0; j < 4; ++j) bj[j] = bias[wn + j * 16 + r];

#pragma unroll
    for (int kb = 0; kb < 12; ++kb) {
        const int p  = kb >> 2;
        const int f0 = (kb & 3) * 32 + q * 8;

        s8v afrag[2];
#pragma unroll
        for (int i = 0; i < 2; ++i) {
            const float* xs = sx + (wm + i * 16 + r) * XLDS_STRIDE + f0;
            float4 v0 = *(const float4*)xs;
            float4 v1 = *(const float4*)(xs + 4);
            float v[8] = {v0.x, v0.y, v0.z, v0.w, v1.x, v1.y, v1.z, v1.w};
            s8v a;
#pragma unroll
            for (int t = 0; t < 8; ++t) {
                float e = v[t];
                if (p >= 1) e *= v[t];
                if (p == 2) e *= v[t];
                a[t] = f2bf(e);
            }
            afrag[i] = a;
        }
#pragma unroll
        for (int j = 0; j < 4; ++j) {
            const s8v b = *(const s8v*)(Wb + (((kb * 4 + q) * HID_F) + wn + j * 16 + r) * 8);
            acc[0][j] = __builtin_amdgcn_mfma_f32_16x16x32_bf16(afrag[0], b, acc[0][j], 0, 0, 0);
            acc[1][j] = __builtin_amdgcn_mfma_f32_16x16x32_bf16(afrag[1], b, acc[1][j], 0, 0, 0);
        }
    }

#pragma unroll
    for (int i = 0; i < 2; ++i)
#pragma unroll
        for (int j = 0; j < 4; ++j)
#pragma unroll
            for (int e = 0; e < 4; ++e) {
                int grow = node0 + wm + i * 16 + q * 4 + e;
                if (grow < N_NODES) {
                    int gcol = wn + j * 16 + r;
                    h1[(size_t)grow * HID_F + gcol] =
                        f2bf(fmaxf(acc[i][j][e] + bj[j], 0.f));
                }
            }
}

// ---------------------------------------------------------------------------
// Gather-aggregate over 128 bf16 feats -> fp32 out.  One wave per node;
// masked 8-wide chunks: every load group is 8 independent loads (no serial
// remainder chain).
// ---------------------------------------------------------------------------
__global__ __launch_bounds__(256) void gather128(
    const unsigned* __restrict__ h1u, const int* __restrict__ row_start,
    const int* __restrict__ csr_src, float* __restrict__ out)
{
    const int lane = threadIdx.x & 63;
    const int wave = threadIdx.x >> 6;
    const int node = blockIdx.x * 4 + wave;
    if (node >= N_NODES) return;

    int e0 = row_start[node], e1 = row_start[node + 1];
    float ax[8], ay[8];
#pragma unroll
    for (int t = 0; t < 8; ++t) { ax[t] = 0.f; ay[t] = 0.f; }

    for (int base = e0; base < e1; base += 64) {
        int idx = base + lane;
        int sreg = (idx < e1) ? csr_src[idx] : 0;
        int cnt = min(64, e1 - base);
        for (int j = 0; j < cnt; j += 8) {
            unsigned u[8];
#pragma unroll
            for (int t = 0; t < 8; ++t) {
                int jj = j + t;
                int sj = __shfl(sreg, jj < cnt ? jj : 0);
                u[t] = h1u[(size_t)sj * 64 + lane];
            }
#pragma unroll
            for (int t = 0; t < 8; ++t)
                if (j + t < cnt) {
                    ax[t] += bflo2f(u[t]);
                    ay[t] += bfhi2f(u[t]);
                }
        }
    }
    float sx = ((ax[0] + ax[1]) + (ax[2] + ax[3])) + ((ax[4] + ax[5]) + (ax[6] + ax[7]));
    float sy = ((ay[0] + ay[1]) + (ay[2] + ay[3])) + ((ay[4] + ay[5]) + (ay[6] + ay[7]));
    float2 rv; rv.x = sx; rv.y = sy;
    ((float2*)out)[(size_t)node * 64 + lane] = rv;
}

// ---------------------------------------------------------------------------
// KAN2 via MFMA bf16 (block = 64 nodes x 64 out); 1/deg (row_start diff)
// fused at LDS staging.
// ---------------------------------------------------------------------------
__global__ __launch_bounds__(256) void kan2_mfma(
    const float* __restrict__ a1, const int* __restrict__ row_start,
    const short* __restrict__ Wb, const float* __restrict__ bias,
    short* __restrict__ h2)
{
    __shared__ float sx[64 * XLDS_STRIDE];
    const int tid  = threadIdx.x;
    const int lane = tid & 63;
    const int wave = tid >> 6;
    const int node0 = blockIdx.x * 64;
    const int q = lane >> 4, r = lane & 15;

#pragma unroll
    for (int it = 0; it < 8; ++it) {
        int idx = tid + 256 * it;
        int m = idx >> 5, c4 = (idx & 31) * 4;
        int gm = min(node0 + m, N_NODES - 1);
        float di = 1.0f / fmaxf((float)(row_start[gm + 1] - row_start[gm]), 1.0f);
        float4 v = *(const float4*)(a1 + (size_t)gm * IN_F + c4);
        v.x *= di; v.y *= di; v.z *= di; v.w *= di;
        *(float4*)(sx + m * XLDS_STRIDE + c4) = v;
    }
    __syncthreads();

    const int wm = (wave & 1) * 32;
    const int wn = (wave >> 1) * 32;

    f4v acc[2][2];
#pragma unroll
    for (int i = 0; i < 2; ++i)
#pragma unroll
        for (int j = 0; j < 2; ++j)
            acc[i][j] = (f4v){0.f, 0.f, 0.f, 0.f};

    float bj[2];
#pragma unroll
    for (int j = 0; j < 2; ++j) bj[j] = bias[wn + j * 16 + r];

#pragma unroll
    for (int kb = 0; kb < 12; ++kb) {
        const int p  = kb >> 2;
        const int f0 = (kb & 3) * 32 + q * 8;

        s8v afrag[2];
#pragma unroll
        for (int i = 0; i < 2; ++i) {
            const float* xs = sx + (wm + i * 16 + r) * XLDS_STRIDE + f0;
            float4 v0 = *(const float4*)xs;
            float4 v1 = *(const float4*)(xs + 4);
            float v[8] = {v0.x, v0.y, v0.z, v0.w, v1.x, v1.y, v1.z, v1.w};
            s8v a;
#pragma unroll
            for (int t = 0; t < 8; ++t) {
                float e = v[t];
                if (p >= 1) e *= v[t];
                if (p == 2) e *= v[t];
                a[t] = f2bf(e);
            }
            afrag[i] = a;
        }
#pragma unroll
        for (int j = 0; j < 2; ++j) {
            const s8v b = *(const s8v*)(Wb + (((kb * 4 + q) * OUT_F) + wn + j * 16 + r) * 8);
            acc[0][j] = __builtin_amdgcn_mfma_f32_16x16x32_bf16(afrag[0], b, acc[0][j], 0, 0, 0);
            acc[1][j] = __builtin_amdgcn_mfma_f32_16x16x32_bf16(afrag[1], b, acc[1][j], 0, 0, 0);
        }
    }

#pragma unroll
    for (int i = 0; i < 2; ++i)
#pragma unroll
        for (int j = 0; j < 2; ++j)
#pragma unroll
            for (int e = 0; e < 4; ++e) {
                int grow = node0 + wm + i * 16 + q * 4 + e;
                if (grow < N_NODES) {
                    int gcol = wn + j * 16 + r;
                    h2[(size_t)grow * OUT_F + gcol] = f2bf(acc[i][j][e] + bj[j]);
                }
            }
}

// ---------------------------------------------------------------------------
// Gather-aggregate over 64 bf16 feats fused with 1/deg + log_softmax.
// Masked 8-wide chunks (same MLP fix as gather128).
// ---------------------------------------------------------------------------
__global__ __launch_bounds__(256) void gather64_lsm(
    const unsigned short* __restrict__ h2u, const int* __restrict__ row_start,
    const int* __restrict__ csr_src, float* __restrict__ out)
{
    const int lane = threadIdx.x & 63;
    const int wave = threadIdx.x >> 6;
    const int node = blockIdx.x * 4 + wave;
    if (node >= N_NODES) return;

    int e0 = row_start[node], e1 = row_start[node + 1];
    float a[8];
#pragma unroll
    for (int t = 0; t < 8; ++t) a[t] = 0.f;

    for (int base = e0; base < e1; base += 64) {
        int idx = base + lane;
        int sreg = (idx < e1) ? csr_src[idx] : 0;
        int cnt = min(64, e1 - base);
        for (int j = 0; j < cnt; j += 8) {
            unsigned short u[8];
#pragma unroll
            for (int t = 0; t < 8; ++t) {
                int jj = j + t;
                int sj = __shfl(sreg, jj < cnt ? jj : 0);
                u[t] = h2u[(size_t)sj * OUT_F + lane];
            }
#pragma unroll
            for (int t = 0; t < 8; ++t)
                if (j + t < cnt) a[t] += bflo2f((unsigned)u[t]);
        }
    }
    float acc = ((a[0] + a[1]) + (a[2] + a[3])) + ((a[4] + a[5]) + (a[6] + a[7]));

    float di = 1.0f / fmaxf((float)(e1 - e0), 1.0f);
    float v = acc * di;

    float m = v;
#pragma unroll
    for (int off = 32; off >= 1; off >>= 1)
        m = fmaxf(m, __shfl_xor(m, off));
    float e = expf(v - m);
    float s = e;
#pragma unroll
    for (int off = 32; off >= 1; off >>= 1)
        s += __shfl_xor(s, off);
    out[(size_t)node * OUT_F + lane] = v - m - logf(s);
}

// ---------------------------------------------------------------------------
extern "C" void kernel_launch(void* const* d_in, const int* in_sizes, int n_in,
                              void* d_out, int out_size, void* d_ws, size_t ws_size,
                              hipStream_t stream)
{
    const float* x  = (const float*)d_in[0];
    const int*   ei = (const int*)d_in[1];
    const float* w1 = (const float*)d_in[2];
    const float* b1 = (const float*)d_in[3];
    const float* c1 = (const float*)d_in[4];
    const float* w2 = (const float*)d_in[5];
    const float* b2 = (const float*)d_in[6];
    const float* c2 = (const float*)d_in[7];
    float* out = (float*)d_out;

    const int* src = ei;            // edge_index[0]
    const int* tgt = ei + N_EDGES;  // edge_index[1]

    char* ws = (char*)d_ws;
    size_t off = 0;
    auto carve = [&](size_t bytes) -> void* {
        void* p = ws + off;
        off = (off + bytes + 255) & ~(size_t)255;
        return p;
    };
    short*    Wb1       = (short*)carve((size_t)K_TOT * HID_F * 2);
    short*    Wb2       = (short*)carve((size_t)K_TOT * OUT_F * 2);
    int*      row_start = (int*)carve(((size_t)N_NODES + 1) * 4);
    int*      bucket_cnt= (int*)carve((size_t)NBUCK * 4);
    int*      boff      = (int*)carve(((size_t)NBUCK + 1) * 4);
    int*      bcur      = (int*)carve((size_t)NBUCK * 4);
    unsigned* spk       = (unsigned*)carve((size_t)N_EDGES * 4);
    int*      csr_src   = (int*)carve((size_t)N_EDGES * 4);
    short*    h1        = (short*)carve((size_t)N_NODES * HID_F * 2);   // bf16
    float*    a1        = (float*)carve((size_t)N_NODES * IN_F * 4);    // fp32
    short*    h2        = (short*)carve((size_t)N_NODES * OUT_F * 2);   // bf16

    const int grid_mm = (N_NODES + 63) / 64;   // 1563

    // --- CSR build via bucket sort ------------------------------------------
    hipMemsetAsync(bucket_cnt, 0, (size_t)NBUCK * 4, stream);
    bucket_hist<<<NBLK_SORT, 256, 0, stream>>>(tgt, bucket_cnt);
    bucket_scan<<<1, 256, 0, stream>>>(bucket_cnt, boff, bcur);
    bucket_scatter<<<NBLK_SORT, 256, 0, stream>>>(src, tgt, bcur, spk);
    bucket_rowstart<<<NBUCK, 256, 0, stream>>>(boff, spk, row_start);
    csr_fine<<<NBUCK, 256, 0, stream>>>(boff, spk, row_start, csr_src);

    // --- weights + layer 1 ---------------------------------------------------
    fold_weights_bf16<<<(K_TOT * HID_F + K_TOT * OUT_F + 255) / 256, 256, 0, stream>>>(
        w1, c1, w2, c2, Wb1, Wb2);
    kan1_mfma<<<grid_mm, 256, 0, stream>>>(x, Wb1, b1, h1);

    // --- aggregate 1 (gather, no atomics) ------------------------------------
    gather128<<<(N_NODES + 3) / 4, 256, 0, stream>>>((const unsigned*)h1, row_start, csr_src, a1);

    // --- layer 2 -------------------------------------------------------------
    kan2_mfma<<<grid_mm, 256, 0, stream>>>(a1, row_start, Wb2, b2, h2);

    // --- aggregate 2 + log_softmax (fused) -----------------------------------
    gather64_lsm<<<(N_NODES + 3) / 4, 256, 0, stream>>>(
        (const unsigned short*)h2, row_start, csr_src, out);
}

// Round 9
// 311.371 us; speedup vs baseline: 1.4297x; 1.0894x over previous
//
#include <hip/hip_runtime.h>
#include <hip/hip_bf16.h>
#include <math.h>

#define N_NODES 100000
#define N_EDGES 1600000
#define IN_F 128
#define HID_F 128
#define OUT_F 64
#define K_TOT 384                          // 3 basis planes x 128
#define XLDS_STRIDE 132                    // 128 + 4 pad -> conflict-free b128 reads

// bucket sort parameters
#define BK_BITS 9
#define BK_SIZE 512                        // nodes per bucket
#define NBUCK ((N_NODES + BK_SIZE - 1) / BK_SIZE)   // 196
#define EPB 4096                           // edges per sort block
#define NBLK_SORT ((N_EDGES + EPB - 1) / EPB)       // 391
// packed edge record: [31:23] local tgt (9b), [22:0] src (17b used)
#define PK_SRC_MASK 0x7fffffu
#define PAD8(d) (((d) + 7) & ~7)

typedef __attribute__((ext_vector_type(8))) short s8v;   // 8 bf16 (MFMA A/B frag)
typedef __attribute__((ext_vector_type(4))) float f4v;   // MFMA C/D frag

__device__ __forceinline__ short f2bf(float f) {
    __hip_bfloat16 h = __float2bfloat16(f);
    return __builtin_bit_cast(short, h);
}
__device__ __forceinline__ float bfhi2f(unsigned u) {
    return __builtin_bit_cast(float, u & 0xffff0000u);
}
__device__ __forceinline__ float bflo2f(unsigned u) {
    return __builtin_bit_cast(float, u << 16);
}

// ---------------------------------------------------------------------------
// Fold KAN weights into bf16 MFMA-B chunk layout; also zero the sentinel
// rows (index N_NODES) of h1/h2 that padded CSR entries gather from.
// ---------------------------------------------------------------------------
__global__ __launch_bounds__(256) void fold_weights_bf16(
    const float* __restrict__ w1, const float* __restrict__ c1,
    const float* __restrict__ w2, const float* __restrict__ c2,
    short* __restrict__ Wb1, short* __restrict__ Wb2,
    unsigned* __restrict__ h1u, unsigned* __restrict__ h2u)
{
    if (blockIdx.x == 0) {
        if (threadIdx.x < 64) h1u[(size_t)N_NODES * 64 + threadIdx.x] = 0;
        if (threadIdx.x < 32) h2u[(size_t)N_NODES * 32 + threadIdx.x] = 0;
    }
    int idx = blockIdx.x * 256 + threadIdx.x;
    if (idx < K_TOT * HID_F) {
        int k = idx >> 7, n = idx & 127;
        int p = k >> 7, f = k & 127;
        int si = f * HID_F + n;
        float v = (p == 0) ? (w1[si] + 0.1f * c1[si * 3])
                           : 0.1f * c1[si * 3 + p];
        Wb1[(((k >> 3) * HID_F) + n) * 8 + (k & 7)] = f2bf(v);
    } else {
        idx -= K_TOT * HID_F;
        if (idx < K_TOT * OUT_F) {
            int k = idx >> 6, n = idx & 63;
            int p = k >> 7, f = k & 127;
            int si = f * OUT_F + n;
            float v = (p == 0) ? (w2[si] + 0.1f * c2[si * 3])
                               : 0.1f * c2[si * 3 + p];
            Wb2[(((k >> 3) * OUT_F) + n) * 8 + (k & 7)] = f2bf(v);
        }
    }
}

// ---------------------------------------------------------------------------
// Bucket sort pass A: coarse histogram (LDS) -> global bucket counts.
// ---------------------------------------------------------------------------
__global__ __launch_bounds__(256) void bucket_hist(
    const int* __restrict__ tgt, int* __restrict__ bucket_cnt)
{
    __shared__ int h[NBUCK];
    int tid = threadIdx.x;
    for (int i = tid; i < NBUCK; i += 256) h[i] = 0;
    __syncthreads();
    int e0 = blockIdx.x * EPB;
    int n = min(EPB, N_EDGES - e0);
    for (int i = tid; i < n; i += 256)
        atomicAdd(&h[tgt[e0 + i] >> BK_BITS], 1);
    __syncthreads();
    for (int i = tid; i < NBUCK; i += 256)
        if (h[i]) atomicAdd(&bucket_cnt[i], h[i]);
}

// Pass B: single-block exclusive scan of NBUCK counts -> offsets + cursors.
// (Also reused to scan padded bucket sums -> pboff.)
__global__ __launch_bounds__(256) void bucket_scan(
    const int* __restrict__ cnt, int* __restrict__ boff, int* __restrict__ bcur)
{
    __shared__ int s[256];
    int tid = threadIdx.x;
    int v = (tid < NBUCK) ? cnt[tid] : 0;
    s[tid] = v;
    __syncthreads();
    for (int o = 1; o < 256; o <<= 1) {
        int t = (tid >= o) ? s[tid - o] : 0;
        __syncthreads();
        s[tid] += t;
        __syncthreads();
    }
    int excl = s[tid] - v;
    if (tid < NBUCK) { boff[tid] = excl; bcur[tid] = excl; }
    if (tid == NBUCK - 1) boff[NBUCK] = excl + v;
}

// Pass C: scatter edges into bucket-sorted packed records (9b tgt | 23b src).
__global__ __launch_bounds__(256) void bucket_scatter(
    const int* __restrict__ src, const int* __restrict__ tgt,
    int* __restrict__ bcur, unsigned* __restrict__ spk)
{
    __shared__ int h[NBUCK];
    __shared__ int base[NBUCK];
    int tid = threadIdx.x;
    for (int i = tid; i < NBUCK; i += 256) h[i] = 0;
    __syncthreads();
    int e0 = blockIdx.x * EPB;
    int n = min(EPB, N_EDGES - e0);
    for (int i = tid; i < n; i += 256)
        atomicAdd(&h[tgt[e0 + i] >> BK_BITS], 1);
    __syncthreads();
    for (int i = tid; i < NBUCK; i += 256) {
        int c = h[i];
        base[i] = c ? atomicAdd(&bcur[i], c) : 0;
        h[i] = 0;
    }
    __syncthreads();
    for (int i = tid; i < n; i += 256) {
        int t = tgt[e0 + i];
        int b = t >> BK_BITS;
        int pos = base[b] + atomicAdd(&h[b], 1);
        spk[pos] = ((unsigned)(t - (b << BK_BITS)) << 23) | (unsigned)src[e0 + i];
    }
}

// Pass D: per-bucket degree histogram -> real row_start (block scan) and
// per-bucket PADDED total (for prow).
__global__ __launch_bounds__(256) void bucket_rowstart(
    const int* __restrict__ boff, const unsigned* __restrict__ spk,
    int* __restrict__ row_start, int* __restrict__ pbsum)
{
    __shared__ int d[BK_SIZE];
    __shared__ int s[256];
    int tid = threadIdx.x;
    int b = blockIdx.x;
    d[tid] = 0; d[tid + 256] = 0;
    __syncthreads();
    int e0 = boff[b], e1 = boff[b + 1];
    for (int i = e0 + tid; i < e1; i += 256)
        atomicAdd(&d[spk[i] >> 23], 1);
    __syncthreads();
    int a0 = d[2 * tid], a1c = d[2 * tid + 1];
    int tsum = a0 + a1c;
    s[tid] = tsum;
    __syncthreads();
    for (int o = 1; o < 256; o <<= 1) {
        int t = (tid >= o) ? s[tid - o] : 0;
        __syncthreads();
        s[tid] += t;
        __syncthreads();
    }
    int excl = s[tid] - tsum;
    int nbase = b << BK_BITS;
    int n0 = nbase + 2 * tid, n1 = n0 + 1;
    int rs0 = e0 + excl;
    if (n0 < N_NODES) row_start[n0] = rs0;
    if (n1 < N_NODES) row_start[n1] = rs0 + a0;
    if (b == NBUCK - 1 && tid == 0) row_start[N_NODES] = boff[NBUCK];

    // padded bucket total
    int pc0 = (n0 < N_NODES) ? PAD8(a0) : 0;
    int pc1 = (n1 < N_NODES) ? PAD8(a1c) : 0;
    __syncthreads();
    s[tid] = pc0 + pc1;
    __syncthreads();
    for (int o = 128; o > 0; o >>= 1) {
        if (tid < o) s[tid] += s[tid + o];
        __syncthreads();
    }
    if (tid == 0) pbsum[b] = s[0];
}

// Pass D2: per-bucket scan of padded counts + pboff base -> prow.
__global__ __launch_bounds__(256) void bucket_prow(
    const int* __restrict__ row_start, const int* __restrict__ pboff,
    int* __restrict__ prow)
{
    __shared__ int s[256];
    int tid = threadIdx.x;
    int b = blockIdx.x;
    int nbase = b << BK_BITS;
    int n0 = nbase + 2 * tid, n1 = n0 + 1;
    int d0 = (n0 < N_NODES) ? row_start[n0 + 1] - row_start[n0] : 0;
    int d1 = (n1 < N_NODES) ? row_start[n1 + 1] - row_start[n1] : 0;
    int pc0 = (n0 < N_NODES) ? PAD8(d0) : 0;
    int pc1 = (n1 < N_NODES) ? PAD8(d1) : 0;
    int tsum = pc0 + pc1;
    s[tid] = tsum;
    __syncthreads();
    for (int o = 1; o < 256; o <<= 1) {
        int t = (tid >= o) ? s[tid - o] : 0;
        __syncthreads();
        s[tid] += t;
        __syncthreads();
    }
    int excl = s[tid] - tsum;
    int base = pboff[b] + excl;
    if (n0 < N_NODES) prow[n0] = base;
    if (n1 < N_NODES) prow[n1] = base + pc0;
    if (b == NBUCK - 1 && tid == 0) prow[N_NODES] = pboff[NBUCK];
}

// Pass E: fine CSR fill into padded layout + sentinel pad slots.
__global__ __launch_bounds__(256) void csr_fine_pad(
    const int* __restrict__ boff, const unsigned* __restrict__ spk,
    const int* __restrict__ prow, int* __restrict__ csr_pad)
{
    __shared__ int cur[BK_SIZE];
    int tid = threadIdx.x;
    int b = blockIdx.x;
    int nbase = b << BK_BITS;
    for (int i = tid; i < BK_SIZE; i += 256) {
        int nd = nbase + i;
        cur[i] = (nd < N_NODES) ? prow[nd] : 0;
    }
    __syncthreads();
    int e0 = boff[b], e1 = boff[b + 1];
    for (int i = e0 + tid; i < e1; i += 256) {
        unsigned pk = spk[i];
        int pos = atomicAdd(&cur[pk >> 23], 1);
        csr_pad[pos] = (int)(pk & PK_SRC_MASK);
    }
    __syncthreads();
    for (int i = tid; i < BK_SIZE; i += 256) {
        int nd = nbase + i;
        if (nd < N_NODES) {
            int kend = prow[nd + 1];
            for (int k = cur[i]; k < kend; ++k) csr_pad[k] = N_NODES;
        }
    }
}

// ---------------------------------------------------------------------------
// KAN1 via MFMA bf16 (block = 64 nodes x 128 out, 4 waves 2x2).
// ---------------------------------------------------------------------------
__global__ __launch_bounds__(256) void kan1_mfma(
    const float* __restrict__ x, const short* __restrict__ Wb,
    const float* __restrict__ bias, short* __restrict__ h1)
{
    __shared__ float sx[64 * XLDS_STRIDE];
    const int tid  = threadIdx.x;
    const int lane = tid & 63;
    const int wave = tid >> 6;
    const int node0 = blockIdx.x * 64;
    const int q = lane >> 4, r = lane & 15;

#pragma unroll
    for (int it = 0; it < 8; ++it) {
        int idx = tid + 256 * it;
        int m = idx >> 5, c4 = (idx & 31) * 4;
        int gm = min(node0 + m, N_NODES - 1);
        float4 v = *(const float4*)(x + (size_t)gm * IN_F + c4);
        *(float4*)(sx + m * XLDS_STRIDE + c4) = v;
    }
    __syncthreads();

    const int wm = (wave & 1) * 32;
    const int wn = (wave >> 1) * 64;

    f4v acc[2][4];
#pragma unroll
    for (int i = 0; i < 2; ++i)
#pragma unroll
        for (int j = 0; j < 4; ++j)
            acc[i][j] = (f4v){0.f, 0.f, 0.f, 0.f};

    float bj[4];
#pragma unroll
    for (int j = 0; j < 4; ++j) bj[j] = bias[wn + j * 16 + r];

#pragma unroll
    for (int kb = 0; kb < 12; ++kb) {
        const int p  = kb >> 2;
        const int f0 = (kb & 3) * 32 + q * 8;

        s8v afrag[2];
#pragma unroll
        for (int i = 0; i < 2; ++i) {
            const float* xs = sx + (wm + i * 16 + r) * XLDS_STRIDE + f0;
            float4 v0 = *(const float4*)xs;
            float4 v1 = *(const float4*)(xs + 4);
            float v[8] = {v0.x, v0.y, v0.z, v0.w, v1.x, v1.y, v1.z, v1.w};
            s8v a;
#pragma unroll
            for (int t = 0; t < 8; ++t) {
                float e = v[t];
                if (p >= 1) e *= v[t];
                if (p == 2) e *= v[t];
                a[t] = f2bf(e);
            }
            afrag[i] = a;
        }
#pragma unroll
        for (int j = 0; j < 4; ++j) {
            const s8v b = *(const s8v*)(Wb + (((kb * 4 + q) * HID_F) + wn + j * 16 + r) * 8);
            acc[0][j] = __builtin_amdgcn_mfma_f32_16x16x32_bf16(afrag[0], b, acc[0][j], 0, 0, 0);
            acc[1][j] = __builtin_amdgcn_mfma_f32_16x16x32_bf16(afrag[1], b, acc[1][j], 0, 0, 0);
        }
    }

#pragma unroll
    for (int i = 0; i < 2; ++i)
#pragma unroll
        for (int j = 0; j < 4; ++j)
#pragma unroll
            for (int e = 0; e < 4; ++e) {
                int grow = node0 + wm + i * 16 + q * 4 + e;
                if (grow < N_NODES) {
                    int gcol = wn + j * 16 + r;
                    h1[(size_t)grow * HID_F + gcol] =
                        f2bf(fmaxf(acc[i][j][e] + bj[j], 0.f));
                }
            }
}

// ---------------------------------------------------------------------------
// Gather-aggregate over 128 bf16 feats.  Padded CSR -> branch-free 8-deep
// load groups (pad slots gather the zero row).  Output packed bf16.
// ---------------------------------------------------------------------------
__global__ __launch_bounds__(256) void gather128(
    const unsigned* __restrict__ h1u, const int* __restrict__ prow,
    const int* __restrict__ csr_pad, unsigned* __restrict__ a1u)
{
    const int lane = threadIdx.x & 63;
    const int wave = threadIdx.x >> 6;
    const int node = blockIdx.x * 4 + wave;
    if (node >= N_NODES) return;

    int p0 = prow[node], p1 = prow[node + 1];
    float ax[8], ay[8];
#pragma unroll
    for (int t = 0; t < 8; ++t) { ax[t] = 0.f; ay[t] = 0.f; }

    for (int base = p0; base < p1; base += 64) {
        int sreg = csr_pad[min(base + lane, p1 - 1)];
        int cnt = min(64, p1 - base);          // multiple of 8
        for (int j = 0; j < cnt; j += 8) {
            unsigned u[8];
#pragma unroll
            for (int t = 0; t < 8; ++t) {
                int sj = __shfl(sreg, j + t);
                u[t] = h1u[(size_t)sj * 64 + lane];
            }
#pragma unroll
            for (int t = 0; t < 8; ++t) {
                ax[t] += bflo2f(u[t]);
                ay[t] += bfhi2f(u[t]);
            }
        }
    }
    float sx = ((ax[0] + ax[1]) + (ax[2] + ax[3])) + ((ax[4] + ax[5]) + (ax[6] + ax[7]));
    float sy = ((ay[0] + ay[1]) + (ay[2] + ay[3])) + ((ay[4] + ay[5]) + (ay[6] + ay[7]));
    unsigned o = ((unsigned)(unsigned short)f2bf(sy) << 16) |
                 (unsigned)(unsigned short)f2bf(sx);
    a1u[(size_t)node * 64 + lane] = o;
}

// ---------------------------------------------------------------------------
// KAN2 via MFMA bf16; reads packed-bf16 a1, applies 1/deg at LDS staging.
// ---------------------------------------------------------------------------
__global__ __launch_bounds__(256) void kan2_mfma(
    const unsigned* __restrict__ a1u, const int* __restrict__ row_start,
    const short* __restrict__ Wb, const float* __restrict__ bias,
    short* __restrict__ h2)
{
    __shared__ float sx[64 * XLDS_STRIDE];
    const int tid  = threadIdx.x;
    const int lane = tid & 63;
    const int wave = tid >> 6;
    const int node0 = blockIdx.x * 64;
    const int q = lane >> 4, r = lane & 15;

    const uint2* a1v = (const uint2*)a1u;
#pragma unroll
    for (int it = 0; it < 8; ++it) {
        int idx = tid + 256 * it;              // 0..2047 = 64 rows x 32 uint2
        int m = idx >> 5, c2 = idx & 31;
        int gm = min(node0 + m, N_NODES - 1);
        float di = 1.0f / fmaxf((float)(row_start[gm + 1] - row_start[gm]), 1.0f);
        uint2 u = a1v[(size_t)gm * 32 + c2];
        float4 v;
        v.x = bflo2f(u.x) * di; v.y = bfhi2f(u.x) * di;
        v.z = bflo2f(u.y) * di; v.w = bfhi2f(u.y) * di;
        *(float4*)(sx + m * XLDS_STRIDE + 4 * c2) = v;
    }
    __syncthreads();

    const int wm = (wave & 1) * 32;
    const int wn = (wave >> 1) * 32;

    f4v acc[2][2];
#pragma unroll
    for (int i = 0; i < 2; ++i)
#pragma unroll
        for (int j = 0; j < 2; ++j)
            acc[i][j] = (f4v){0.f, 0.f, 0.f, 0.f};

    float bj[2];
#pragma unroll
    for (int j = 0; j < 2; ++j) bj[j] = bias[wn + j * 16 + r];

#pragma unroll
    for (int kb = 0; kb < 12; ++kb) {
        const int p  = kb >> 2;
        const int f0 = (kb & 3) * 32 + q * 8;

        s8v afrag[2];
#pragma unroll
        for (int i = 0; i < 2; ++i) {
            const float* xs = sx + (wm + i * 16 + r) * XLDS_STRIDE + f0;
            float4 v0 = *(const float4*)xs;
            float4 v1 = *(const float4*)(xs + 4);
            float v[8] = {v0.x, v0.y, v0.z, v0.w, v1.x, v1.y, v1.z, v1.w};
            s8v a;
#pragma unroll
            for (int t = 0; t < 8; ++t) {
                float e = v[t];
                if (p >= 1) e *= v[t];
                if (p == 2) e *= v[t];
                a[t] = f2bf(e);
            }
            afrag[i] = a;
        }
#pragma unroll
        for (int j = 0; j < 2; ++j) {
            const s8v b = *(const s8v*)(Wb + (((kb * 4 + q) * OUT_F) + wn + j * 16 + r) * 8);
            acc[0][j] = __builtin_amdgcn_mfma_f32_16x16x32_bf16(afrag[0], b, acc[0][j], 0, 0, 0);
            acc[1][j] = __builtin_amdgcn_mfma_f32_16x16x32_bf16(afrag[1], b, acc[1][j], 0, 0, 0);
        }
    }

#pragma unroll
    for (int i = 0; i < 2; ++i)
#pragma unroll
        for (int j = 0; j < 2; ++j)
#pragma unroll
            for (int e = 0; e < 4; ++e) {
                int grow = node0 + wm + i * 16 + q * 4 + e;
                if (grow < N_NODES) {
                    int gcol = wn + j * 16 + r;
                    h2[(size_t)grow * OUT_F + gcol] = f2bf(acc[i][j][e] + bj[j]);
                }
            }
}

// ---------------------------------------------------------------------------
// Gather-aggregate over 64 bf16 feats + 1/deg + log_softmax.
// TWO nodes per wave: each 32-lane half handles one node with uint loads
// (2 feats/lane).  Padded CSR -> no per-element masks; group-level
// half-uniform guard handles unequal degrees.
// ---------------------------------------------------------------------------
__global__ __launch_bounds__(256) void gather64_lsm(
    const unsigned* __restrict__ h2u, const int* __restrict__ row_start,
    const int* __restrict__ prow, const int* __restrict__ csr_pad,
    float* __restrict__ out)
{
    const int lane = threadIdx.x & 63;
    const int wave = threadIdx.x >> 6;
    const int hl   = lane & 31;
    const int half = lane >> 5;
    const int node = blockIdx.x * 8 + wave * 2 + half;   // grid exact: 12500*8

    int p0 = prow[node], p1 = prow[node + 1];
    int cnt = p1 - p0;
    int degr = row_start[node + 1] - row_start[node];
    int cmax = max(cnt, __shfl_xor(cnt, 32));

    float alo[8], ahi[8];
#pragma unroll
    for (int t = 0; t < 8; ++t) { alo[t] = 0.f; ahi[t] = 0.f; }

    for (int base = 0; base < cmax; base += 32) {
        int idx = max(min(p0 + base + hl, p1 - 1), 0);
        int sreg = csr_pad[idx];
        int lim = min(32, cmax - base);
        for (int j = 0; j < lim; j += 8) {
            if (base + j < cnt) {
                unsigned u[8];
#pragma unroll
                for (int t = 0; t < 8; ++t) {
                    int sj = __shfl(sreg, (half << 5) + j + t);
                    u[t] = h2u[(size_t)sj * 32 + hl];
                }
#pragma unroll
                for (int t = 0; t < 8; ++t) {
                    alo[t] += bflo2f(u[t]);
                    ahi[t] += bfhi2f(u[t]);
                }
            }
        }
    }
    float slo = ((alo[0] + alo[1]) + (alo[2] + alo[3])) + ((alo[4] + alo[5]) + (alo[6] + alo[7]));
    float shi = ((ahi[0] + ahi[1]) + (ahi[2] + ahi[3])) + ((ahi[4] + ahi[5]) + (ahi[6] + ahi[7]));

    float di = 1.0f / fmaxf((float)degr, 1.0f);
    float vlo = slo * di, vhi = shi * di;

    float m = fmaxf(vlo, vhi);
#pragma unroll
    for (int off = 16; off >= 1; off >>= 1)
        m = fmaxf(m, __shfl_xor(m, off));     // stays within the 32-lane half
    float e = expf(vlo - m) + expf(vhi - m);
#pragma unroll
    for (int off = 16; off >= 1; off >>= 1)
        e += __shfl_xor(e, off);
    float ls = logf(e);
    float2 o; o.x = vlo - m - ls; o.y = vhi - m - ls;
    *(float2*)(out + (size_t)node * OUT_F + 2 * hl) = o;
}

// ---------------------------------------------------------------------------
extern "C" void kernel_launch(void* const* d_in, const int* in_sizes, int n_in,
                              void* d_out, int out_size, void* d_ws, size_t ws_size,
                              hipStream_t stream)
{
    const float* x  = (const float*)d_in[0];
    const int*   ei = (const int*)d_in[1];
    const float* w1 = (const float*)d_in[2];
    const float* b1 = (const float*)d_in[3];
    const float* c1 = (const float*)d_in[4];
    const float* w2 = (const float*)d_in[5];
    const float* b2 = (const float*)d_in[6];
    const float* c2 = (const float*)d_in[7];
    float* out = (float*)d_out;

    const int* src = ei;            // edge_index[0]
    const int* tgt = ei + N_EDGES;  // edge_index[1]

    char* ws = (char*)d_ws;
    size_t off = 0;
    auto carve = [&](size_t bytes) -> void* {
        void* p = ws + off;
        off = (off + bytes + 255) & ~(size_t)255;
        return p;
    };
    short*    Wb1       = (short*)carve((size_t)K_TOT * HID_F * 2);
    short*    Wb2       = (short*)carve((size_t)K_TOT * OUT_F * 2);
    int*      row_start = (int*)carve(((size_t)N_NODES + 1) * 4);
    int*      prow      = (int*)carve(((size_t)N_NODES + 1) * 4);
    int*      bucket_cnt= (int*)carve((size_t)NBUCK * 4);
    int*      boff      = (int*)carve(((size_t)NBUCK + 1) * 4);
    int*      bcur      = (int*)carve((size_t)NBUCK * 4);
    int*      pbsum     = (int*)carve((size_t)NBUCK * 4);
    int*      pboff     = (int*)carve(((size_t)NBUCK + 1) * 4);
    int*      pbcur     = (int*)carve((size_t)NBUCK * 4);
    unsigned* spk       = (unsigned*)carve((size_t)N_EDGES * 4);
    int*      csr_pad   = (int*)carve(((size_t)N_EDGES + 7 * (size_t)N_NODES + 64) * 4);
    short*    h1        = (short*)carve(((size_t)N_NODES + 1) * HID_F * 2);  // +sentinel row
    unsigned* a1u       = (unsigned*)carve((size_t)N_NODES * 64 * 4);        // packed bf16
    short*    h2        = (short*)carve(((size_t)N_NODES + 1) * OUT_F * 2);  // +sentinel row

    const int grid_mm = (N_NODES + 63) / 64;   // 1563

    // --- CSR build via bucket sort (padded layout) ---------------------------
    hipMemsetAsync(bucket_cnt, 0, (size_t)NBUCK * 4, stream);
    bucket_hist<<<NBLK_SORT, 256, 0, stream>>>(tgt, bucket_cnt);
    bucket_scan<<<1, 256, 0, stream>>>(bucket_cnt, boff, bcur);
    bucket_scatter<<<NBLK_SORT, 256, 0, stream>>>(src, tgt, bcur, spk);
    bucket_rowstart<<<NBUCK, 256, 0, stream>>>(boff, spk, row_start, pbsum);
    bucket_scan<<<1, 256, 0, stream>>>(pbsum, pboff, pbcur);
    bucket_prow<<<NBUCK, 256, 0, stream>>>(row_start, pboff, prow);
    csr_fine_pad<<<NBUCK, 256, 0, stream>>>(boff, spk, prow, csr_pad);

    // --- weights + sentinel zero rows + layer 1 ------------------------------
    fold_weights_bf16<<<(K_TOT * HID_F + K_TOT * OUT_F + 255) / 256, 256, 0, stream>>>(
        w1, c1, w2, c2, Wb1, Wb2, (unsigned*)h1, (unsigned*)h2);
    kan1_mfma<<<grid_mm, 256, 0, stream>>>(x, Wb1, b1, h1);

    // --- aggregate 1 (gather, maskless) --------------------------------------
    gather128<<<(N_NODES + 3) / 4, 256, 0, stream>>>(
        (const unsigned*)h1, prow, csr_pad, a1u);

    // --- layer 2 -------------------------------------------------------------
    kan2_mfma<<<grid_mm, 256, 0, stream>>>(a1u, row_start, Wb2, b2, h2);

    // --- aggregate 2 + log_softmax (fused, 2 nodes/wave) ---------------------
    gather64_lsm<<<(N_NODES + 7) / 8, 256, 0, stream>>>(
        (const unsigned*)h2, row_start, prow, csr_pad, out);
}

// Round 10
// 290.594 us; speedup vs baseline: 1.5319x; 1.0715x over previous
//
#include <hip/hip_runtime.h>
#include <hip/hip_bf16.h>
#include <math.h>

#define N_NODES 100000
#define N_EDGES 1600000
#define IN_F 128
#define HID_F 128
#define OUT_F 64
#define K_TOT 384                          // 3 basis planes x 128
#define XLDS_STRIDE 132                    // 128 + 4 pad -> conflict-free b128 reads

// bucket sort parameters
#define BK_BITS 9
#define BK_SIZE 512                        // nodes per bucket
#define NBUCK ((N_NODES + BK_SIZE - 1) / BK_SIZE)   // 196
#define EPB 4096                           // edges per sort block
#define NBLK_SORT ((N_EDGES + EPB - 1) / EPB)       // 391
// packed edge record: [31:23] local tgt (9b), [22:0] src (17b used)
#define PK_SRC_MASK 0x7fffffu
#define PAD8(d) (((d) + 7) & ~7)

typedef __attribute__((ext_vector_type(8))) short s8v;   // 8 bf16 (MFMA A/B frag)
typedef __attribute__((ext_vector_type(4))) float f4v;   // MFMA C/D frag

__device__ __forceinline__ short f2bf(float f) {
    __hip_bfloat16 h = __float2bfloat16(f);
    return __builtin_bit_cast(short, h);
}
__device__ __forceinline__ float bfhi2f(unsigned u) {
    return __builtin_bit_cast(float, u & 0xffff0000u);
}
__device__ __forceinline__ float bflo2f(unsigned u) {
    return __builtin_bit_cast(float, u << 16);
}

// ---------------------------------------------------------------------------
// Fold KAN weights into bf16 MFMA-B chunk layout; also zero the sentinel
// rows (index N_NODES) of h1 (fp8, 32 dwords) / h2 (bf16, 32 dwords).
// ---------------------------------------------------------------------------
__global__ __launch_bounds__(256) void fold_weights_bf16(
    const float* __restrict__ w1, const float* __restrict__ c1,
    const float* __restrict__ w2, const float* __restrict__ c2,
    short* __restrict__ Wb1, short* __restrict__ Wb2,
    unsigned* __restrict__ h1d, unsigned* __restrict__ h2u)
{
    if (blockIdx.x == 0) {
        if (threadIdx.x < 32) h1d[(size_t)N_NODES * 32 + threadIdx.x] = 0;
        if (threadIdx.x < 32) h2u[(size_t)N_NODES * 32 + threadIdx.x] = 0;
    }
    int idx = blockIdx.x * 256 + threadIdx.x;
    if (idx < K_TOT * HID_F) {
        int k = idx >> 7, n = idx & 127;
        int p = k >> 7, f = k & 127;
        int si = f * HID_F + n;
        float v = (p == 0) ? (w1[si] + 0.1f * c1[si * 3])
                           : 0.1f * c1[si * 3 + p];
        Wb1[(((k >> 3) * HID_F) + n) * 8 + (k & 7)] = f2bf(v);
    } else {
        idx -= K_TOT * HID_F;
        if (idx < K_TOT * OUT_F) {
            int k = idx >> 6, n = idx & 63;
            int p = k >> 7, f = k & 127;
            int si = f * OUT_F + n;
            float v = (p == 0) ? (w2[si] + 0.1f * c2[si * 3])
                               : 0.1f * c2[si * 3 + p];
            Wb2[(((k >> 3) * OUT_F) + n) * 8 + (k & 7)] = f2bf(v);
        }
    }
}

// ---------------------------------------------------------------------------
// Bucket sort pass A: coarse histogram (LDS) -> global bucket counts.
// ---------------------------------------------------------------------------
__global__ __launch_bounds__(256) void bucket_hist(
    const int* __restrict__ tgt, int* __restrict__ bucket_cnt)
{
    __shared__ int h[NBUCK];
    int tid = threadIdx.x;
    for (int i = tid; i < NBUCK; i += 256) h[i] = 0;
    __syncthreads();
    int e0 = blockIdx.x * EPB;
    int n = min(EPB, N_EDGES - e0);
    for (int i = tid; i < n; i += 256)
        atomicAdd(&h[tgt[e0 + i] >> BK_BITS], 1);
    __syncthreads();
    for (int i = tid; i < NBUCK; i += 256)
        if (h[i]) atomicAdd(&bucket_cnt[i], h[i]);
}

// Pass B: single-block exclusive scan of NBUCK counts -> offsets + cursors.
__global__ __launch_bounds__(256) void bucket_scan(
    const int* __restrict__ cnt, int* __restrict__ boff, int* __restrict__ bcur)
{
    __shared__ int s[256];
    int tid = threadIdx.x;
    int v = (tid < NBUCK) ? cnt[tid] : 0;
    s[tid] = v;
    __syncthreads();
    for (int o = 1; o < 256; o <<= 1) {
        int t = (tid >= o) ? s[tid - o] : 0;
        __syncthreads();
        s[tid] += t;
        __syncthreads();
    }
    int excl = s[tid] - v;
    if (tid < NBUCK) { boff[tid] = excl; bcur[tid] = excl; }
    if (tid == NBUCK - 1) boff[NBUCK] = excl + v;
}

// Pass C: scatter edges into bucket-sorted packed records (9b tgt | 23b src).
__global__ __launch_bounds__(256) void bucket_scatter(
    const int* __restrict__ src, const int* __restrict__ tgt,
    int* __restrict__ bcur, unsigned* __restrict__ spk)
{
    __shared__ int h[NBUCK];
    __shared__ int base[NBUCK];
    int tid = threadIdx.x;
    for (int i = tid; i < NBUCK; i += 256) h[i] = 0;
    __syncthreads();
    int e0 = blockIdx.x * EPB;
    int n = min(EPB, N_EDGES - e0);
    for (int i = tid; i < n; i += 256)
        atomicAdd(&h[tgt[e0 + i] >> BK_BITS], 1);
    __syncthreads();
    for (int i = tid; i < NBUCK; i += 256) {
        int c = h[i];
        base[i] = c ? atomicAdd(&bcur[i], c) : 0;
        h[i] = 0;
    }
    __syncthreads();
    for (int i = tid; i < n; i += 256) {
        int t = tgt[e0 + i];
        int b = t >> BK_BITS;
        int pos = base[b] + atomicAdd(&h[b], 1);
        spk[pos] = ((unsigned)(t - (b << BK_BITS)) << 23) | (unsigned)src[e0 + i];
    }
}

// Pass D: per-bucket degree histogram -> real row_start (block scan) and
// per-bucket PADDED total (for prow).
__global__ __launch_bounds__(256) void bucket_rowstart(
    const int* __restrict__ boff, const unsigned* __restrict__ spk,
    int* __restrict__ row_start, int* __restrict__ pbsum)
{
    __shared__ int d[BK_SIZE];
    __shared__ int s[256];
    int tid = threadIdx.x;
    int b = blockIdx.x;
    d[tid] = 0; d[tid + 256] = 0;
    __syncthreads();
    int e0 = boff[b], e1 = boff[b + 1];
    for (int i = e0 + tid; i < e1; i += 256)
        atomicAdd(&d[spk[i] >> 23], 1);
    __syncthreads();
    int a0 = d[2 * tid], a1c = d[2 * tid + 1];
    int tsum = a0 + a1c;
    s[tid] = tsum;
    __syncthreads();
    for (int o = 1; o < 256; o <<= 1) {
        int t = (tid >= o) ? s[tid - o] : 0;
        __syncthreads();
        s[tid] += t;
        __syncthreads();
    }
    int excl = s[tid] - tsum;
    int nbase = b << BK_BITS;
    int n0 = nbase + 2 * tid, n1 = n0 + 1;
    int rs0 = e0 + excl;
    if (n0 < N_NODES) row_start[n0] = rs0;
    if (n1 < N_NODES) row_start[n1] = rs0 + a0;
    if (b == NBUCK - 1 && tid == 0) row_start[N_NODES] = boff[NBUCK];

    // padded bucket total
    int pc0 = (n0 < N_NODES) ? PAD8(a0) : 0;
    int pc1 = (n1 < N_NODES) ? PAD8(a1c) : 0;
    __syncthreads();
    s[tid] = pc0 + pc1;
    __syncthreads();
    for (int o = 128; o > 0; o >>= 1) {
        if (tid < o) s[tid] += s[tid + o];
        __syncthreads();
    }
    if (tid == 0) pbsum[b] = s[0];
}

// Pass D2: per-bucket scan of padded counts + pboff base -> prow.
__global__ __launch_bounds__(256) void bucket_prow(
    const int* __restrict__ row_start, const int* __restrict__ pboff,
    int* __restrict__ prow)
{
    __shared__ int s[256];
    int tid = threadIdx.x;
    int b = blockIdx.x;
    int nbase = b << BK_BITS;
    int n0 = nbase + 2 * tid, n1 = n0 + 1;
    int d0 = (n0 < N_NODES) ? row_start[n0 + 1] - row_start[n0] : 0;
    int d1 = (n1 < N_NODES) ? row_start[n1 + 1] - row_start[n1] : 0;
    int pc0 = (n0 < N_NODES) ? PAD8(d0) : 0;
    int pc1 = (n1 < N_NODES) ? PAD8(d1) : 0;
    int tsum = pc0 + pc1;
    s[tid] = tsum;
    __syncthreads();
    for (int o = 1; o < 256; o <<= 1) {
        int t = (tid >= o) ? s[tid - o] : 0;
        __syncthreads();
        s[tid] += t;
        __syncthreads();
    }
    int excl = s[tid] - tsum;
    int base = pboff[b] + excl;
    if (n0 < N_NODES) prow[n0] = base;
    if (n1 < N_NODES) prow[n1] = base + pc0;
    if (b == NBUCK - 1 && tid == 0) prow[N_NODES] = pboff[NBUCK];
}

// Pass E: fine CSR fill into padded layout + sentinel pad slots.
__global__ __launch_bounds__(256) void csr_fine_pad(
    const int* __restrict__ boff, const unsigned* __restrict__ spk,
    const int* __restrict__ prow, int* __restrict__ csr_pad)
{
    __shared__ int cur[BK_SIZE];
    int tid = threadIdx.x;
    int b = blockIdx.x;
    int nbase = b << BK_BITS;
    for (int i = tid; i < BK_SIZE; i += 256) {
        int nd = nbase + i;
        cur[i] = (nd < N_NODES) ? prow[nd] : 0;
    }
    __syncthreads();
    int e0 = boff[b], e1 = boff[b + 1];
    for (int i = e0 + tid; i < e1; i += 256) {
        unsigned pk = spk[i];
        int pos = atomicAdd(&cur[pk >> 23], 1);
        csr_pad[pos] = (int)(pk & PK_SRC_MASK);
    }
    __syncthreads();
    for (int i = tid; i < BK_SIZE; i += 256) {
        int nd = nbase + i;
        if (nd < N_NODES) {
            int kend = prow[nd + 1];
            for (int k = cur[i]; k < kend; ++k) csr_pad[k] = N_NODES;
        }
    }
}

// ---------------------------------------------------------------------------
// KAN1 via MFMA bf16 (block = 64 nodes x 128 out, 4 waves 2x2).
// Epilogue: +bias, ReLU, pack 4 cols {r, r+16, r+32, r+48}+wn into one fp8
// dword -> h1 stored fp8 in PERMUTED feature order (see gather128 for the
// inverse mapping).  Halves the gather traffic vs bf16.
// ---------------------------------------------------------------------------
__global__ __launch_bounds__(256) void kan1_mfma(
    const float* __restrict__ x, const short* __restrict__ Wb,
    const float* __restrict__ bias, unsigned* __restrict__ h1d)
{
    __shared__ float sx[64 * XLDS_STRIDE];
    const int tid  = threadIdx.x;
    const int lane = tid & 63;
    const int wave = tid >> 6;
    const int node0 = blockIdx.x * 64;
    const int q = lane >> 4, r = lane & 15;

#pragma unroll
    for (int it = 0; it < 8; ++it) {
        int idx = tid + 256 * it;
        int m = idx >> 5, c4 = (idx & 31) * 4;
        int gm = min(node0 + m, N_NODES - 1);
        float4 v = *(const float4*)(x + (size_t)gm * IN_F + c4);
        *(float4*)(sx + m * XLDS_STRIDE + c4) = v;
    }
    __syncthreads();

    const int wm = (wave & 1) * 32;
    const int wn = (wave >> 1) * 64;

    f4v acc[2][4];
#pragma unroll
    for (int i = 0; i < 2; ++i)
#pragma unroll
        for (int j = 0; j < 4; ++j)
            acc[i][j] = (f4v){0.f, 0.f, 0.f, 0.f};

    float bj[4];
#pragma unroll
    for (int j = 0; j < 4; ++j) bj[j] = bias[wn + j * 16 + r];

#pragma unroll
    for (int kb = 0; kb < 12; ++kb) {
        const int p  = kb >> 2;
        const int f0 = (kb & 3) * 32 + q * 8;

        s8v afrag[2];
#pragma unroll
        for (int i = 0; i < 2; ++i) {
            const float* xs = sx + (wm + i * 16 + r) * XLDS_STRIDE + f0;
            float4 v0 = *(const float4*)xs;
            float4 v1 = *(const float4*)(xs + 4);
            float v[8] = {v0.x, v0.y, v0.z, v0.w, v1.x, v1.y, v1.z, v1.w};
            s8v a;
#pragma unroll
            for (int t = 0; t < 8; ++t) {
                float e = v[t];
                if (p >= 1) e *= v[t];
                if (p == 2) e *= v[t];
                a[t] = f2bf(e);
            }
            afrag[i] = a;
        }
#pragma unroll
        for (int j = 0; j < 4; ++j) {
            const s8v b = *(const s8v*)(Wb + (((kb * 4 + q) * HID_F) + wn + j * 16 + r) * 8);
            acc[0][j] = __builtin_amdgcn_mfma_f32_16x16x32_bf16(afrag[0], b, acc[0][j], 0, 0, 0);
            acc[1][j] = __builtin_amdgcn_mfma_f32_16x16x32_bf16(afrag[1], b, acc[1][j], 0, 0, 0);
        }
    }

    // fp8 epilogue: storage dword d = 16*(wn>>6) + r holds features
    // {wn+r, wn+16+r, wn+32+r, wn+48+r} as bytes 0..3.
    const int dci = ((wn >> 6) << 4) + r;
#pragma unroll
    for (int i = 0; i < 2; ++i)
#pragma unroll
        for (int e = 0; e < 4; ++e) {
            int grow = node0 + wm + i * 16 + q * 4 + e;
            if (grow < N_NODES) {
                float v0 = fmaxf(acc[i][0][e] + bj[0], 0.f);
                float v1 = fmaxf(acc[i][1][e] + bj[1], 0.f);
                float v2 = fmaxf(acc[i][2][e] + bj[2], 0.f);
                float v3 = fmaxf(acc[i][3][e] + bj[3], 0.f);
                int pk = __builtin_amdgcn_cvt_pk_fp8_f32(v0, v1, 0, false);
                pk = __builtin_amdgcn_cvt_pk_fp8_f32(v2, v3, pk, true);
                h1d[(size_t)grow * 32 + dci] = (unsigned)pk;
            }
        }
}

// ---------------------------------------------------------------------------
// Gather-aggregate over 128 fp8 feats.  Each lane loads 2 B (2 fp8) per
// message (128 B/row, 2 cache lines).  HW cvt fp8->f32.  Output written
// bf16 in CANONICAL feature order (un-permutes kan1's packing):
//   d = lane>>1;  f0 = 64*(d>>4) + 32*(lane&1) + (d&15);  f1 = f0+16.
// ---------------------------------------------------------------------------
__global__ __launch_bounds__(256) void gather128(
    const unsigned short* __restrict__ h1s, const int* __restrict__ prow,
    const int* __restrict__ csr_pad, unsigned short* __restrict__ a1s)
{
    const int lane = threadIdx.x & 63;
    const int wave = threadIdx.x >> 6;
    const int node = blockIdx.x * 4 + wave;
    if (node >= N_NODES) return;

    int p0 = prow[node], p1 = prow[node + 1];
    float alo[8], ahi[8];
#pragma unroll
    for (int t = 0; t < 8; ++t) { alo[t] = 0.f; ahi[t] = 0.f; }

    for (int base = p0; base < p1; base += 64) {
        int sreg = csr_pad[min(base + lane, p1 - 1)];
        int cnt = min(64, p1 - base);          // multiple of 8
        for (int j = 0; j < cnt; j += 8) {
            int u[8];
#pragma unroll
            for (int t = 0; t < 8; ++t) {
                int sj = __shfl(sreg, j + t);
                u[t] = (int)h1s[(size_t)sj * 64 + lane];
            }
#pragma unroll
            for (int t = 0; t < 8; ++t) {
                alo[t] += __builtin_amdgcn_cvt_f32_fp8(u[t], 0);
                ahi[t] += __builtin_amdgcn_cvt_f32_fp8(u[t], 1);
            }
        }
    }
    float slo = ((alo[0] + alo[1]) + (alo[2] + alo[3])) + ((alo[4] + alo[5]) + (alo[6] + alo[7]));
    float shi = ((ahi[0] + ahi[1]) + (ahi[2] + ahi[3])) + ((ahi[4] + ahi[5]) + (ahi[6] + ahi[7]));

    const int d  = lane >> 1;
    const int f0 = ((d >> 4) << 6) + ((lane & 1) << 5) + (d & 15);
    a1s[(size_t)node * 128 + f0]      = (unsigned short)f2bf(slo);
    a1s[(size_t)node * 128 + f0 + 16] = (unsigned short)f2bf(shi);
}

// ---------------------------------------------------------------------------
// KAN2 via MFMA bf16; reads packed-bf16 a1 (canonical order), applies 1/deg
// at LDS staging.
// ---------------------------------------------------------------------------
__global__ __launch_bounds__(256) void kan2_mfma(
    const unsigned* __restrict__ a1u, const int* __restrict__ row_start,
    const short* __restrict__ Wb, const float* __restrict__ bias,
    short* __restrict__ h2)
{
    __shared__ float sx[64 * XLDS_STRIDE];
    const int tid  = threadIdx.x;
    const int lane = tid & 63;
    const int wave = tid >> 6;
    const int node0 = blockIdx.x * 64;
    const int q = lane >> 4, r = lane & 15;

    const uint2* a1v = (const uint2*)a1u;
#pragma unroll
    for (int it = 0; it < 8; ++it) {
        int idx = tid + 256 * it;              // 0..2047 = 64 rows x 32 uint2
        int m = idx >> 5, c2 = idx & 31;
        int gm = min(node0 + m, N_NODES - 1);
        float di = 1.0f / fmaxf((float)(row_start[gm + 1] - row_start[gm]), 1.0f);
        uint2 u = a1v[(size_t)gm * 32 + c2];
        float4 v;
        v.x = bflo2f(u.x) * di; v.y = bfhi2f(u.x) * di;
        v.z = bflo2f(u.y) * di; v.w = bfhi2f(u.y) * di;
        *(float4*)(sx + m * XLDS_STRIDE + 4 * c2) = v;
    }
    __syncthreads();

    const int wm = (wave & 1) * 32;
    const int wn = (wave >> 1) * 32;

    f4v acc[2][2];
#pragma unroll
    for (int i = 0; i < 2; ++i)
#pragma unroll
        for (int j = 0; j < 2; ++j)
            acc[i][j] = (f4v){0.f, 0.f, 0.f, 0.f};

    float bj[2];
#pragma unroll
    for (int j = 0; j < 2; ++j) bj[j] = bias[wn + j * 16 + r];

#pragma unroll
    for (int kb = 0; kb < 12; ++kb) {
        const int p  = kb >> 2;
        const int f0 = (kb & 3) * 32 + q * 8;

        s8v afrag[2];
#pragma unroll
        for (int i = 0; i < 2; ++i) {
            const float* xs = sx + (wm + i * 16 + r) * XLDS_STRIDE + f0;
            float4 v0 = *(const float4*)xs;
            float4 v1 = *(const float4*)(xs + 4);
            float v[8] = {v0.x, v0.y, v0.z, v0.w, v1.x, v1.y, v1.z, v1.w};
            s8v a;
#pragma unroll
            for (int t = 0; t < 8; ++t) {
                float e = v[t];
                if (p >= 1) e *= v[t];
                if (p == 2) e *= v[t];
                a[t] = f2bf(e);
            }
            afrag[i] = a;
        }
#pragma unroll
        for (int j = 0; j < 2; ++j) {
            const s8v b = *(const s8v*)(Wb + (((kb * 4 + q) * OUT_F) + wn + j * 16 + r) * 8);
            acc[0][j] = __builtin_amdgcn_mfma_f32_16x16x32_bf16(afrag[0], b, acc[0][j], 0, 0, 0);
            acc[1][j] = __builtin_amdgcn_mfma_f32_16x16x32_bf16(afrag[1], b, acc[1][j], 0, 0, 0);
        }
    }

#pragma unroll
    for (int i = 0; i < 2; ++i)
#pragma unroll
        for (int j = 0; j < 2; ++j)
#pragma unroll
            for (int e = 0; e < 4; ++e) {
                int grow = node0 + wm + i * 16 + q * 4 + e;
                if (grow < N_NODES) {
                    int gcol = wn + j * 16 + r;
                    h2[(size_t)grow * OUT_F + gcol] = f2bf(acc[i][j][e] + bj[j]);
                }
            }
}

// ---------------------------------------------------------------------------
// Gather-aggregate over 64 bf16 feats + 1/deg + log_softmax.
// TWO nodes per wave (32-lane halves), uint loads (2 feats/lane).
// ---------------------------------------------------------------------------
__global__ __launch_bounds__(256) void gather64_lsm(
    const unsigned* __restrict__ h2u, const int* __restrict__ row_start,
    const int* __restrict__ prow, const int* __restrict__ csr_pad,
    float* __restrict__ out)
{
    const int lane = threadIdx.x & 63;
    const int wave = threadIdx.x >> 6;
    const int hl   = lane & 31;
    const int half = lane >> 5;
    const int node = blockIdx.x * 8 + wave * 2 + half;   // grid exact: 12500*8

    int p0 = prow[node], p1 = prow[node + 1];
    int cnt = p1 - p0;
    int degr = row_start[node + 1] - row_start[node];
    int cmax = max(cnt, __shfl_xor(cnt, 32));

    float alo[8], ahi[8];
#pragma unroll
    for (int t = 0; t < 8; ++t) { alo[t] = 0.f; ahi[t] = 0.f; }

    for (int base = 0; base < cmax; base += 32) {
        int idx = max(min(p0 + base + hl, p1 - 1), 0);
        int sreg = csr_pad[idx];
        int lim = min(32, cmax - base);
        for (int j = 0; j < lim; j += 8) {
            if (base + j < cnt) {
                unsigned u[8];
#pragma unroll
                for (int t = 0; t < 8; ++t) {
                    int sj = __shfl(sreg, (half << 5) + j + t);
                    u[t] = h2u[(size_t)sj * 32 + hl];
                }
#pragma unroll
                for (int t = 0; t < 8; ++t) {
                    alo[t] += bflo2f(u[t]);
                    ahi[t] += bfhi2f(u[t]);
                }
            }
        }
    }
    float slo = ((alo[0] + alo[1]) + (alo[2] + alo[3])) + ((alo[4] + alo[5]) + (alo[6] + alo[7]));
    float shi = ((ahi[0] + ahi[1]) + (ahi[2] + ahi[3])) + ((ahi[4] + ahi[5]) + (ahi[6] + ahi[7]));

    float di = 1.0f / fmaxf((float)degr, 1.0f);
    float vlo = slo * di, vhi = shi * di;

    float m = fmaxf(vlo, vhi);
#pragma unroll
    for (int off = 16; off >= 1; off >>= 1)
        m = fmaxf(m, __shfl_xor(m, off));     // stays within the 32-lane half
    float e = expf(vlo - m) + expf(vhi - m);
#pragma unroll
    for (int off = 16; off >= 1; off >>= 1)
        e += __shfl_xor(e, off);
    float ls = logf(e);
    float2 o; o.x = vlo - m - ls; o.y = vhi - m - ls;
    *(float2*)(out + (size_t)node * OUT_F + 2 * hl) = o;
}

// ---------------------------------------------------------------------------
extern "C" void kernel_launch(void* const* d_in, const int* in_sizes, int n_in,
                              void* d_out, int out_size, void* d_ws, size_t ws_size,
                              hipStream_t stream)
{
    const float* x  = (const float*)d_in[0];
    const int*   ei = (const int*)d_in[1];
    const float* w1 = (const float*)d_in[2];
    const float* b1 = (const float*)d_in[3];
    const float* c1 = (const float*)d_in[4];
    const float* w2 = (const float*)d_in[5];
    const float* b2 = (const float*)d_in[6];
    const float* c2 = (const float*)d_in[7];
    float* out = (float*)d_out;

    const int* src = ei;            // edge_index[0]
    const int* tgt = ei + N_EDGES;  // edge_index[1]

    char* ws = (char*)d_ws;
    size_t off = 0;
    auto carve = [&](size_t bytes) -> void* {
        void* p = ws + off;
        off = (off + bytes + 255) & ~(size_t)255;
        return p;
    };
    short*    Wb1       = (short*)carve((size_t)K_TOT * HID_F * 2);
    short*    Wb2       = (short*)carve((size_t)K_TOT * OUT_F * 2);
    int*      row_start = (int*)carve(((size_t)N_NODES + 1) * 4);
    int*      prow      = (int*)carve(((size_t)N_NODES + 1) * 4);
    int*      bucket_cnt= (int*)carve((size_t)NBUCK * 4);
    int*      boff      = (int*)carve(((size_t)NBUCK + 1) * 4);
    int*      bcur      = (int*)carve((size_t)NBUCK * 4);
    int*      pbsum     = (int*)carve((size_t)NBUCK * 4);
    int*      pboff     = (int*)carve(((size_t)NBUCK + 1) * 4);
    int*      pbcur     = (int*)carve((size_t)NBUCK * 4);
    unsigned* spk       = (unsigned*)carve((size_t)N_EDGES * 4);
    int*      csr_pad   = (int*)carve(((size_t)N_EDGES + 7 * (size_t)N_NODES + 64) * 4);
    unsigned* h1d       = (unsigned*)carve(((size_t)N_NODES + 1) * 128);     // fp8, permuted
    unsigned* a1u       = (unsigned*)carve((size_t)N_NODES * 64 * 4);        // packed bf16
    short*    h2        = (short*)carve(((size_t)N_NODES + 1) * OUT_F * 2);  // bf16 +sentinel

    const int grid_mm = (N_NODES + 63) / 64;   // 1563

    // --- CSR build via bucket sort (padded layout) ---------------------------
    hipMemsetAsync(bucket_cnt, 0, (size_t)NBUCK * 4, stream);
    bucket_hist<<<NBLK_SORT, 256, 0, stream>>>(tgt, bucket_cnt);
    bucket_scan<<<1, 256, 0, stream>>>(bucket_cnt, boff, bcur);
    bucket_scatter<<<NBLK_SORT, 256, 0, stream>>>(src, tgt, bcur, spk);
    bucket_rowstart<<<NBUCK, 256, 0, stream>>>(boff, spk, row_start, pbsum);
    bucket_scan<<<1, 256, 0, stream>>>(pbsum, pboff, pbcur);
    bucket_prow<<<NBUCK, 256, 0, stream>>>(row_start, pboff, prow);
    csr_fine_pad<<<NBUCK, 256, 0, stream>>>(boff, spk, prow, csr_pad);

    // --- weights + sentinel zero rows + layer 1 ------------------------------
    fold_weights_bf16<<<(K_TOT * HID_F + K_TOT * OUT_F + 255) / 256, 256, 0, stream>>>(
        w1, c1, w2, c2, Wb1, Wb2, h1d, (unsigned*)h2);
    kan1_mfma<<<grid_mm, 256, 0, stream>>>(x, Wb1, b1, h1d);

    // --- aggregate 1 (gather, fp8 rows) --------------------------------------
    gather128<<<(N_NODES + 3) / 4, 256, 0, stream>>>(
        (const unsigned short*)h1d, prow, csr_pad, (unsigned short*)a1u);

    // --- layer 2 -------------------------------------------------------------
    kan2_mfma<<<grid_mm, 256, 0, stream>>>(a1u, row_start, Wb2, b2, h2);

    // --- aggregate 2 + log_softmax (fused, 2 nodes/wave) ---------------------
    gather64_lsm<<<(N_NODES + 7) / 8, 256, 0, stream>>>(
        (const unsigned*)h2, row_start, prow, csr_pad, out);
}

// Round 11
// 283.181 us; speedup vs baseline: 1.5720x; 1.0262x over previous
//
#include <hip/hip_runtime.h>
#include <hip/hip_bf16.h>
#include <math.h>

#define N_NODES 100000
#define N_EDGES 1600000
#define IN_F 128
#define HID_F 128
#define OUT_F 64
#define K_TOT 384                          // 3 basis planes x 128
#define XLDS_STRIDE 132                    // 128 + 4 pad -> conflict-free b128 reads

// bucket sort parameters
#define BK_BITS 9
#define BK_SIZE 512                        // nodes per bucket
#define NBUCK ((N_NODES + BK_SIZE - 1) / BK_SIZE)   // 196
#define EPB 4096                           // edges per sort block
#define NBLK_SORT ((N_EDGES + EPB - 1) / EPB)       // 391
// packed edge record: [31:23] local tgt (9b), [22:0] src (17b used)
#define PK_SRC_MASK 0x7fffffu
#define PAD8(d) (((d) + 7) & ~7)

typedef __attribute__((ext_vector_type(8))) short s8v;   // 8 bf16 (MFMA A/B frag)
typedef __attribute__((ext_vector_type(4))) float f4v;   // MFMA C/D frag
typedef __attribute__((ext_vector_type(2))) float f2v;   // cvt_pk_f32_fp8 result

__device__ __forceinline__ short f2bf(float f) {
    __hip_bfloat16 h = __float2bfloat16(f);
    return __builtin_bit_cast(short, h);
}
__device__ __forceinline__ float bfhi2f(unsigned u) {
    return __builtin_bit_cast(float, u & 0xffff0000u);
}
__device__ __forceinline__ float bflo2f(unsigned u) {
    return __builtin_bit_cast(float, u << 16);
}

// ---------------------------------------------------------------------------
// Fold KAN weights into bf16 MFMA-B chunk layout; also zero the sentinel
// rows (index N_NODES) of h1 (fp8, 32 dwords) / h2 (bf16, 32 dwords).
// ---------------------------------------------------------------------------
__global__ __launch_bounds__(256) void fold_weights_bf16(
    const float* __restrict__ w1, const float* __restrict__ c1,
    const float* __restrict__ w2, const float* __restrict__ c2,
    short* __restrict__ Wb1, short* __restrict__ Wb2,
    unsigned* __restrict__ h1d, unsigned* __restrict__ h2u)
{
    if (blockIdx.x == 0) {
        if (threadIdx.x < 32) h1d[(size_t)N_NODES * 32 + threadIdx.x] = 0;
        if (threadIdx.x < 32) h2u[(size_t)N_NODES * 32 + threadIdx.x] = 0;
    }
    int idx = blockIdx.x * 256 + threadIdx.x;
    if (idx < K_TOT * HID_F) {
        int k = idx >> 7, n = idx & 127;
        int p = k >> 7, f = k & 127;
        int si = f * HID_F + n;
        float v = (p == 0) ? (w1[si] + 0.1f * c1[si * 3])
                           : 0.1f * c1[si * 3 + p];
        Wb1[(((k >> 3) * HID_F) + n) * 8 + (k & 7)] = f2bf(v);
    } else {
        idx -= K_TOT * HID_F;
        if (idx < K_TOT * OUT_F) {
            int k = idx >> 6, n = idx & 63;
            int p = k >> 7, f = k & 127;
            int si = f * OUT_F + n;
            float v = (p == 0) ? (w2[si] + 0.1f * c2[si * 3])
                               : 0.1f * c2[si * 3 + p];
            Wb2[(((k >> 3) * OUT_F) + n) * 8 + (k & 7)] = f2bf(v);
        }
    }
}

// ---------------------------------------------------------------------------
// Bucket sort pass A: coarse histogram (LDS) -> global bucket counts.
// ---------------------------------------------------------------------------
__global__ __launch_bounds__(256) void bucket_hist(
    const int* __restrict__ tgt, int* __restrict__ bucket_cnt)
{
    __shared__ int h[NBUCK];
    int tid = threadIdx.x;
    for (int i = tid; i < NBUCK; i += 256) h[i] = 0;
    __syncthreads();
    int e0 = blockIdx.x * EPB;
    int n = min(EPB, N_EDGES - e0);
    for (int i = tid; i < n; i += 256)
        atomicAdd(&h[tgt[e0 + i] >> BK_BITS], 1);
    __syncthreads();
    for (int i = tid; i < NBUCK; i += 256)
        if (h[i]) atomicAdd(&bucket_cnt[i], h[i]);
}

// Pass B: single-block exclusive scan of NBUCK counts -> offsets + cursors.
__global__ __launch_bounds__(256) void bucket_scan(
    const int* __restrict__ cnt, int* __restrict__ boff, int* __restrict__ bcur)
{
    __shared__ int s[256];
    int tid = threadIdx.x;
    int v = (tid < NBUCK) ? cnt[tid] : 0;
    s[tid] = v;
    __syncthreads();
    for (int o = 1; o < 256; o <<= 1) {
        int t = (tid >= o) ? s[tid - o] : 0;
        __syncthreads();
        s[tid] += t;
        __syncthreads();
    }
    int excl = s[tid] - v;
    if (tid < NBUCK) { boff[tid] = excl; bcur[tid] = excl; }
    if (tid == NBUCK - 1) boff[NBUCK] = excl + v;
}

// Pass C: scatter edges into bucket-sorted packed records (9b tgt | 23b src).
__global__ __launch_bounds__(256) void bucket_scatter(
    const int* __restrict__ src, const int* __restrict__ tgt,
    int* __restrict__ bcur, unsigned* __restrict__ spk)
{
    __shared__ int h[NBUCK];
    __shared__ int base[NBUCK];
    int tid = threadIdx.x;
    for (int i = tid; i < NBUCK; i += 256) h[i] = 0;
    __syncthreads();
    int e0 = blockIdx.x * EPB;
    int n = min(EPB, N_EDGES - e0);
    for (int i = tid; i < n; i += 256)
        atomicAdd(&h[tgt[e0 + i] >> BK_BITS], 1);
    __syncthreads();
    for (int i = tid; i < NBUCK; i += 256) {
        int c = h[i];
        base[i] = c ? atomicAdd(&bcur[i], c) : 0;
        h[i] = 0;
    }
    __syncthreads();
    for (int i = tid; i < n; i += 256) {
        int t = tgt[e0 + i];
        int b = t >> BK_BITS;
        int pos = base[b] + atomicAdd(&h[b], 1);
        spk[pos] = ((unsigned)(t - (b << BK_BITS)) << 23) | (unsigned)src[e0 + i];
    }
}

// Pass D: per-bucket degree histogram -> real row_start (block scan) and
// per-bucket PADDED total (for prow).
__global__ __launch_bounds__(256) void bucket_rowstart(
    const int* __restrict__ boff, const unsigned* __restrict__ spk,
    int* __restrict__ row_start, int* __restrict__ pbsum)
{
    __shared__ int d[BK_SIZE];
    __shared__ int s[256];
    int tid = threadIdx.x;
    int b = blockIdx.x;
    d[tid] = 0; d[tid + 256] = 0;
    __syncthreads();
    int e0 = boff[b], e1 = boff[b + 1];
    for (int i = e0 + tid; i < e1; i += 256)
        atomicAdd(&d[spk[i] >> 23], 1);
    __syncthreads();
    int a0 = d[2 * tid], a1c = d[2 * tid + 1];
    int tsum = a0 + a1c;
    s[tid] = tsum;
    __syncthreads();
    for (int o = 1; o < 256; o <<= 1) {
        int t = (tid >= o) ? s[tid - o] : 0;
        __syncthreads();
        s[tid] += t;
        __syncthreads();
    }
    int excl = s[tid] - tsum;
    int nbase = b << BK_BITS;
    int n0 = nbase + 2 * tid, n1 = n0 + 1;
    int rs0 = e0 + excl;
    if (n0 < N_NODES) row_start[n0] = rs0;
    if (n1 < N_NODES) row_start[n1] = rs0 + a0;
    if (b == NBUCK - 1 && tid == 0) row_start[N_NODES] = boff[NBUCK];

    // padded bucket total
    int pc0 = (n0 < N_NODES) ? PAD8(a0) : 0;
    int pc1 = (n1 < N_NODES) ? PAD8(a1c) : 0;
    __syncthreads();
    s[tid] = pc0 + pc1;
    __syncthreads();
    for (int o = 128; o > 0; o >>= 1) {
        if (tid < o) s[tid] += s[tid + o];
        __syncthreads();
    }
    if (tid == 0) pbsum[b] = s[0];
}

// Pass D2: per-bucket scan of padded counts + pboff base -> prow.
__global__ __launch_bounds__(256) void bucket_prow(
    const int* __restrict__ row_start, const int* __restrict__ pboff,
    int* __restrict__ prow)
{
    __shared__ int s[256];
    int tid = threadIdx.x;
    int b = blockIdx.x;
    int nbase = b << BK_BITS;
    int n0 = nbase + 2 * tid, n1 = n0 + 1;
    int d0 = (n0 < N_NODES) ? row_start[n0 + 1] - row_start[n0] : 0;
    int d1 = (n1 < N_NODES) ? row_start[n1 + 1] - row_start[n1] : 0;
    int pc0 = (n0 < N_NODES) ? PAD8(d0) : 0;
    int pc1 = (n1 < N_NODES) ? PAD8(d1) : 0;
    int tsum = pc0 + pc1;
    s[tid] = tsum;
    __syncthreads();
    for (int o = 1; o < 256; o <<= 1) {
        int t = (tid >= o) ? s[tid - o] : 0;
        __syncthreads();
        s[tid] += t;
        __syncthreads();
    }
    int excl = s[tid] - tsum;
    int base = pboff[b] + excl;
    if (n0 < N_NODES) prow[n0] = base;
    if (n1 < N_NODES) prow[n1] = base + pc0;
    if (b == NBUCK - 1 && tid == 0) prow[N_NODES] = pboff[NBUCK];
}

// Pass E: fine CSR fill into padded layout + sentinel pad slots.
__global__ __launch_bounds__(256) void csr_fine_pad(
    const int* __restrict__ boff, const unsigned* __restrict__ spk,
    const int* __restrict__ prow, int* __restrict__ csr_pad)
{
    __shared__ int cur[BK_SIZE];
    int tid = threadIdx.x;
    int b = blockIdx.x;
    int nbase = b << BK_BITS;
    for (int i = tid; i < BK_SIZE; i += 256) {
        int nd = nbase + i;
        cur[i] = (nd < N_NODES) ? prow[nd] : 0;
    }
    __syncthreads();
    int e0 = boff[b], e1 = boff[b + 1];
    for (int i = e0 + tid; i < e1; i += 256) {
        unsigned pk = spk[i];
        int pos = atomicAdd(&cur[pk >> 23], 1);
        csr_pad[pos] = (int)(pk & PK_SRC_MASK);
    }
    __syncthreads();
    for (int i = tid; i < BK_SIZE; i += 256) {
        int nd = nbase + i;
        if (nd < N_NODES) {
            int kend = prow[nd + 1];
            for (int k = cur[i]; k < kend; ++k) csr_pad[k] = N_NODES;
        }
    }
}

// ---------------------------------------------------------------------------
// KAN1 via MFMA bf16 (block = 64 nodes x 128 out, 4 waves 2x2).
// Epilogue: +bias, ReLU, pack 4 cols {r, r+16, r+32, r+48}+wn into one fp8
// dword -> h1 stored fp8 in PERMUTED feature order (see gather128 for the
// inverse mapping).
// ---------------------------------------------------------------------------
__global__ __launch_bounds__(256) void kan1_mfma(
    const float* __restrict__ x, const short* __restrict__ Wb,
    const float* __restrict__ bias, unsigned* __restrict__ h1d)
{
    __shared__ float sx[64 * XLDS_STRIDE];
    const int tid  = threadIdx.x;
    const int lane = tid & 63;
    const int wave = tid >> 6;
    const int node0 = blockIdx.x * 64;
    const int q = lane >> 4, r = lane & 15;

#pragma unroll
    for (int it = 0; it < 8; ++it) {
        int idx = tid + 256 * it;
        int m = idx >> 5, c4 = (idx & 31) * 4;
        int gm = min(node0 + m, N_NODES - 1);
        float4 v = *(const float4*)(x + (size_t)gm * IN_F + c4);
        *(float4*)(sx + m * XLDS_STRIDE + c4) = v;
    }
    __syncthreads();

    const int wm = (wave & 1) * 32;
    const int wn = (wave >> 1) * 64;

    f4v acc[2][4];
#pragma unroll
    for (int i = 0; i < 2; ++i)
#pragma unroll
        for (int j = 0; j < 4; ++j)
            acc[i][j] = (f4v){0.f, 0.f, 0.f, 0.f};

    float bj[4];
#pragma unroll
    for (int j = 0; j < 4; ++j) bj[j] = bias[wn + j * 16 + r];

#pragma unroll
    for (int kb = 0; kb < 12; ++kb) {
        const int p  = kb >> 2;
        const int f0 = (kb & 3) * 32 + q * 8;

        s8v afrag[2];
#pragma unroll
        for (int i = 0; i < 2; ++i) {
            const float* xs = sx + (wm + i * 16 + r) * XLDS_STRIDE + f0;
            float4 v0 = *(const float4*)xs;
            float4 v1 = *(const float4*)(xs + 4);
            float v[8] = {v0.x, v0.y, v0.z, v0.w, v1.x, v1.y, v1.z, v1.w};
            s8v a;
#pragma unroll
            for (int t = 0; t < 8; ++t) {
                float e = v[t];
                if (p >= 1) e *= v[t];
                if (p == 2) e *= v[t];
                a[t] = f2bf(e);
            }
            afrag[i] = a;
        }
#pragma unroll
        for (int j = 0; j < 4; ++j) {
            const s8v b = *(const s8v*)(Wb + (((kb * 4 + q) * HID_F) + wn + j * 16 + r) * 8);
            acc[0][j] = __builtin_amdgcn_mfma_f32_16x16x32_bf16(afrag[0], b, acc[0][j], 0, 0, 0);
            acc[1][j] = __builtin_amdgcn_mfma_f32_16x16x32_bf16(afrag[1], b, acc[1][j], 0, 0, 0);
        }
    }

    // fp8 epilogue: storage dword d = 16*(wn>>6) + r holds features
    // {wn+r, wn+16+r, wn+32+r, wn+48+r} as bytes 0..3.
    const int dci = ((wn >> 6) << 4) + r;
#pragma unroll
    for (int i = 0; i < 2; ++i)
#pragma unroll
        for (int e = 0; e < 4; ++e) {
            int grow = node0 + wm + i * 16 + q * 4 + e;
            if (grow < N_NODES) {
                float v0 = fmaxf(acc[i][0][e] + bj[0], 0.f);
                float v1 = fmaxf(acc[i][1][e] + bj[1], 0.f);
                float v2 = fmaxf(acc[i][2][e] + bj[2], 0.f);
                float v3 = fmaxf(acc[i][3][e] + bj[3], 0.f);
                int pk = __builtin_amdgcn_cvt_pk_fp8_f32(v0, v1, 0, false);
                pk = __builtin_amdgcn_cvt_pk_fp8_f32(v2, v3, pk, true);
                h1d[(size_t)grow * 32 + dci] = (unsigned)pk;
            }
        }
}

// ---------------------------------------------------------------------------
// Gather-aggregate over 128 fp8 feats.  TWO nodes per wave: each 32-lane
// half handles one node; lane loads one dword (4 fp8 feats) per message.
// v_cvt_pk_f32_fp8 decodes 2 feats/instr.  Depth-4 independent chains.
// Epilogue un-permutes kan1's packing: dword d=hl -> features
// 64*(d>>4) + 16*b + (d&15), b = byte index.
// ---------------------------------------------------------------------------
__global__ __launch_bounds__(256) void gather128(
    const unsigned* __restrict__ h1d, const int* __restrict__ prow,
    const int* __restrict__ csr_pad, unsigned short* __restrict__ a1s)
{
    const int lane  = threadIdx.x & 63;
    const int wave  = threadIdx.x >> 6;
    const int hl    = lane & 31;
    const int half  = lane >> 5;
    const int hbase = half << 5;
    const int node  = blockIdx.x * 8 + wave * 2 + half;   // grid exact: 12500*8

    int p0 = prow[node], p1 = prow[node + 1];
    int cnt = p1 - p0;                                    // multiple of 8
    int cmax = max(cnt, __shfl_xor(cnt, 32));

    float acc[4][4];
#pragma unroll
    for (int t = 0; t < 4; ++t)
#pragma unroll
        for (int b = 0; b < 4; ++b) acc[t][b] = 0.f;

    for (int base = 0; base < cmax; base += 32) {
        int idx = max(min(p0 + base + hl, p1 - 1), 0);
        int sreg = csr_pad[idx];
        int lim = min(32, cmax - base);
        for (int j = 0; j < lim; j += 4) {
            if (base + j < cnt) {
                unsigned u[4];
#pragma unroll
                for (int t = 0; t < 4; ++t) {
                    int sj = __shfl(sreg, hbase + j + t);
                    u[t] = h1d[(size_t)sj * 32 + hl];
                }
#pragma unroll
                for (int t = 0; t < 4; ++t) {
                    f2v lo = __builtin_amdgcn_cvt_pk_f32_fp8(u[t], false);
                    f2v hi = __builtin_amdgcn_cvt_pk_f32_fp8(u[t], true);
                    acc[t][0] += lo.x; acc[t][1] += lo.y;
                    acc[t][2] += hi.x; acc[t][3] += hi.y;
                }
            }
        }
    }

    const int r  = hl & 15;
    const int jj = hl >> 4;
    size_t obase = (size_t)node * 128 + (jj << 6) + r;
#pragma unroll
    for (int b = 0; b < 4; ++b) {
        float s = (acc[0][b] + acc[1][b]) + (acc[2][b] + acc[3][b]);
        a1s[obase + (b << 4)] = (unsigned short)f2bf(s);
    }
}

// ---------------------------------------------------------------------------
// KAN2 via MFMA bf16; reads packed-bf16 a1 (canonical order), applies 1/deg
// at LDS staging.
// ---------------------------------------------------------------------------
__global__ __launch_bounds__(256) void kan2_mfma(
    const unsigned* __restrict__ a1u, const int* __restrict__ row_start,
    const short* __restrict__ Wb, const float* __restrict__ bias,
    short* __restrict__ h2)
{
    __shared__ float sx[64 * XLDS_STRIDE];
    const int tid  = threadIdx.x;
    const int lane = tid & 63;
    const int wave = tid >> 6;
    const int node0 = blockIdx.x * 64;
    const int q = lane >> 4, r = lane & 15;

    const uint2* a1v = (const uint2*)a1u;
#pragma unroll
    for (int it = 0; it < 8; ++it) {
        int idx = tid + 256 * it;              // 0..2047 = 64 rows x 32 uint2
        int m = idx >> 5, c2 = idx & 31;
        int gm = min(node0 + m, N_NODES - 1);
        float di = 1.0f / fmaxf((float)(row_start[gm + 1] - row_start[gm]), 1.0f);
        uint2 u = a1v[(size_t)gm * 32 + c2];
        float4 v;
        v.x = bflo2f(u.x) * di; v.y = bfhi2f(u.x) * di;
        v.z = bflo2f(u.y) * di; v.w = bfhi2f(u.y) * di;
        *(float4*)(sx + m * XLDS_STRIDE + 4 * c2) = v;
    }
    __syncthreads();

    const int wm = (wave & 1) * 32;
    const int wn = (wave >> 1) * 32;

    f4v acc[2][2];
#pragma unroll
    for (int i = 0; i < 2; ++i)
#pragma unroll
        for (int j = 0; j < 2; ++j)
            acc[i][j] = (f4v){0.f, 0.f, 0.f, 0.f};

    float bj[2];
#pragma unroll
    for (int j = 0; j < 2; ++j) bj[j] = bias[wn + j * 16 + r];

#pragma unroll
    for (int kb = 0; kb < 12; ++kb) {
        const int p  = kb >> 2;
        const int f0 = (kb & 3) * 32 + q * 8;

        s8v afrag[2];
#pragma unroll
        for (int i = 0; i < 2; ++i) {
            const float* xs = sx + (wm + i * 16 + r) * XLDS_STRIDE + f0;
            float4 v0 = *(const float4*)xs;
            float4 v1 = *(const float4*)(xs + 4);
            float v[8] = {v0.x, v0.y, v0.z, v0.w, v1.x, v1.y, v1.z, v1.w};
            s8v a;
#pragma unroll
            for (int t = 0; t < 8; ++t) {
                float e = v[t];
                if (p >= 1) e *= v[t];
                if (p == 2) e *= v[t];
                a[t] = f2bf(e);
            }
            afrag[i] = a;
        }
#pragma unroll
        for (int j = 0; j < 2; ++j) {
            const s8v b = *(const s8v*)(Wb + (((kb * 4 + q) * OUT_F) + wn + j * 16 + r) * 8);
            acc[0][j] = __builtin_amdgcn_mfma_f32_16x16x32_bf16(afrag[0], b, acc[0][j], 0, 0, 0);
            acc[1][j] = __builtin_amdgcn_mfma_f32_16x16x32_bf16(afrag[1], b, acc[1][j], 0, 0, 0);
        }
    }

#pragma unroll
    for (int i = 0; i < 2; ++i)
#pragma unroll
        for (int j = 0; j < 2; ++j)
#pragma unroll
            for (int e = 0; e < 4; ++e) {
                int grow = node0 + wm + i * 16 + q * 4 + e;
                if (grow < N_NODES) {
                    int gcol = wn + j * 16 + r;
                    h2[(size_t)grow * OUT_F + gcol] = f2bf(acc[i][j][e] + bj[j]);
                }
            }
}

// ---------------------------------------------------------------------------
// Gather-aggregate over 64 bf16 feats + 1/deg + log_softmax.
// TWO nodes per wave (32-lane halves), uint loads (2 feats/lane).
// ---------------------------------------------------------------------------
__global__ __launch_bounds__(256) void gather64_lsm(
    const unsigned* __restrict__ h2u, const int* __restrict__ row_start,
    const int* __restrict__ prow, const int* __restrict__ csr_pad,
    float* __restrict__ out)
{
    const int lane = threadIdx.x & 63;
    const int wave = threadIdx.x >> 6;
    const int hl   = lane & 31;
    const int half = lane >> 5;
    const int node = blockIdx.x * 8 + wave * 2 + half;   // grid exact: 12500*8

    int p0 = prow[node], p1 = prow[node + 1];
    int cnt = p1 - p0;
    int degr = row_start[node + 1] - row_start[node];
    int cmax = max(cnt, __shfl_xor(cnt, 32));

    float alo[8], ahi[8];
#pragma unroll
    for (int t = 0; t < 8; ++t) { alo[t] = 0.f; ahi[t] = 0.f; }

    for (int base = 0; base < cmax; base += 32) {
        int idx = max(min(p0 + base + hl, p1 - 1), 0);
        int sreg = csr_pad[idx];
        int lim = min(32, cmax - base);
        for (int j = 0; j < lim; j += 8) {
            if (base + j < cnt) {
                unsigned u[8];
#pragma unroll
                for (int t = 0; t < 8; ++t) {
                    int sj = __shfl(sreg, (half << 5) + j + t);
                    u[t] = h2u[(size_t)sj * 32 + hl];
                }
#pragma unroll
                for (int t = 0; t < 8; ++t) {
                    alo[t] += bflo2f(u[t]);
                    ahi[t] += bfhi2f(u[t]);
                }
            }
        }
    }
    float slo = ((alo[0] + alo[1]) + (alo[2] + alo[3])) + ((alo[4] + alo[5]) + (alo[6] + alo[7]));
    float shi = ((ahi[0] + ahi[1]) + (ahi[2] + ahi[3])) + ((ahi[4] + ahi[5]) + (ahi[6] + ahi[7]));

    float di = 1.0f / fmaxf((float)degr, 1.0f);
    float vlo = slo * di, vhi = shi * di;

    float m = fmaxf(vlo, vhi);
#pragma unroll
    for (int off = 16; off >= 1; off >>= 1)
        m = fmaxf(m, __shfl_xor(m, off));     // stays within the 32-lane half
    float e = expf(vlo - m) + expf(vhi - m);
#pragma unroll
    for (int off = 16; off >= 1; off >>= 1)
        e += __shfl_xor(e, off);
    float ls = logf(e);
    float2 o; o.x = vlo - m - ls; o.y = vhi - m - ls;
    *(float2*)(out + (size_t)node * OUT_F + 2 * hl) = o;
}

// ---------------------------------------------------------------------------
extern "C" void kernel_launch(void* const* d_in, const int* in_sizes, int n_in,
                              void* d_out, int out_size, void* d_ws, size_t ws_size,
                              hipStream_t stream)
{
    const float* x  = (const float*)d_in[0];
    const int*   ei = (const int*)d_in[1];
    const float* w1 = (const float*)d_in[2];
    const float* b1 = (const float*)d_in[3];
    const float* c1 = (const float*)d_in[4];
    const float* w2 = (const float*)d_in[5];
    const float* b2 = (const float*)d_in[6];
    const float* c2 = (const float*)d_in[7];
    float* out = (float*)d_out;

    const int* src = ei;            // edge_index[0]
    const int* tgt = ei + N_EDGES;  // edge_index[1]

    char* ws = (char*)d_ws;
    size_t off = 0;
    auto carve = [&](size_t bytes) -> void* {
        void* p = ws + off;
        off = (off + bytes + 255) & ~(size_t)255;
        return p;
    };
    short*    Wb1       = (short*)carve((size_t)K_TOT * HID_F * 2);
    short*    Wb2       = (short*)carve((size_t)K_TOT * OUT_F * 2);
    int*      row_start = (int*)carve(((size_t)N_NODES + 1) * 4);
    int*      prow      = (int*)carve(((size_t)N_NODES + 1) * 4);
    int*      bucket_cnt= (int*)carve((size_t)NBUCK * 4);
    int*      boff      = (int*)carve(((size_t)NBUCK + 1) * 4);
    int*      bcur      = (int*)carve((size_t)NBUCK * 4);
    int*      pbsum     = (int*)carve((size_t)NBUCK * 4);
    int*      pboff     = (int*)carve(((size_t)NBUCK + 1) * 4);
    int*      pbcur     = (int*)carve((size_t)NBUCK * 4);
    unsigned* spk       = (unsigned*)carve((size_t)N_EDGES * 4);
    int*      csr_pad   = (int*)carve(((size_t)N_EDGES + 7 * (size_t)N_NODES + 64) * 4);
    unsigned* h1d       = (unsigned*)carve(((size_t)N_NODES + 1) * 128);     // fp8, permuted
    unsigned* a1u       = (unsigned*)carve((size_t)N_NODES * 64 * 4);        // packed bf16
    short*    h2        = (short*)carve(((size_t)N_NODES + 1) * OUT_F * 2);  // bf16 +sentinel

    const int grid_mm = (N_NODES + 63) / 64;   // 1563

    // --- CSR build via bucket sort (padded layout) ---------------------------
    hipMemsetAsync(bucket_cnt, 0, (size_t)NBUCK * 4, stream);
    bucket_hist<<<NBLK_SORT, 256, 0, stream>>>(tgt, bucket_cnt);
    bucket_scan<<<1, 256, 0, stream>>>(bucket_cnt, boff, bcur);
    bucket_scatter<<<NBLK_SORT, 256, 0, stream>>>(src, tgt, bcur, spk);
    bucket_rowstart<<<NBUCK, 256, 0, stream>>>(boff, spk, row_start, pbsum);
    bucket_scan<<<1, 256, 0, stream>>>(pbsum, pboff, pbcur);
    bucket_prow<<<NBUCK, 256, 0, stream>>>(row_start, pboff, prow);
    csr_fine_pad<<<NBUCK, 256, 0, stream>>>(boff, spk, prow, csr_pad);

    // --- weights + sentinel zero rows + layer 1 ------------------------------
    fold_weights_bf16<<<(K_TOT * HID_F + K_TOT * OUT_F + 255) / 256, 256, 0, stream>>>(
        w1, c1, w2, c2, Wb1, Wb2, h1d, (unsigned*)h2);
    kan1_mfma<<<grid_mm, 256, 0, stream>>>(x, Wb1, b1, h1d);

    // --- aggregate 1 (gather, fp8 rows, 2 nodes/wave) ------------------------
    gather128<<<(N_NODES + 7) / 8, 256, 0, stream>>>(
        h1d, prow, csr_pad, (unsigned short*)a1u);

    // --- layer 2 -------------------------------------------------------------
    kan2_mfma<<<grid_mm, 256, 0, stream>>>(a1u, row_start, Wb2, b2, h2);

    // --- aggregate 2 + log_softmax (fused, 2 nodes/wave) ---------------------
    gather64_lsm<<<(N_NODES + 7) / 8, 256, 0, stream>>>(
        (const unsigned*)h2, row_start, prow, csr_pad, out);
}

// Round 12
// 274.633 us; speedup vs baseline: 1.6209x; 1.0311x over previous
//
#include <hip/hip_runtime.h>
#include <hip/hip_bf16.h>
#include <math.h>

#define N_NODES 100000
#define N_EDGES 1600000
#define IN_F 128
#define HID_F 128
#define OUT_F 64
#define K_TOT 384                          // 3 basis planes x 128
#define XLDS_STRIDE 132                    // 128 + 4 pad -> conflict-free b128 reads

// bucket sort parameters
#define BK_BITS 9
#define BK_SIZE 512                        // nodes per bucket
#define NBUCK ((N_NODES + BK_SIZE - 1) / BK_SIZE)   // 196
#define EPB 4096                           // edges per sort block
#define NBLK_SORT ((N_EDGES + EPB - 1) / EPB)       // 391
// packed edge record: [31:23] local tgt (9b), [22:0] src (17b used)
#define PK_SRC_MASK 0x7fffffu
#define PAD8(d) (((d) + 7) & ~7)

typedef __attribute__((ext_vector_type(8))) short s8v;   // 8 bf16 (MFMA A/B frag)
typedef __attribute__((ext_vector_type(4))) float f4v;   // MFMA C/D frag
typedef __attribute__((ext_vector_type(2))) float f2v;   // cvt_pk_f32_fp8 result

__device__ __forceinline__ short f2bf(float f) {
    __hip_bfloat16 h = __float2bfloat16(f);
    return __builtin_bit_cast(short, h);
}
__device__ __forceinline__ float bfhi2f(unsigned u) {
    return __builtin_bit_cast(float, u & 0xffff0000u);
}
__device__ __forceinline__ float bflo2f(unsigned u) {
    return __builtin_bit_cast(float, u << 16);
}

// ---------------------------------------------------------------------------
// Fold KAN weights into bf16 MFMA-B chunk layout; also zero the sentinel
// rows (index N_NODES) of h1 (fp8, 32 dwords) / h2 (fp8, 16 dwords).
// ---------------------------------------------------------------------------
__global__ __launch_bounds__(256) void fold_weights_bf16(
    const float* __restrict__ w1, const float* __restrict__ c1,
    const float* __restrict__ w2, const float* __restrict__ c2,
    short* __restrict__ Wb1, short* __restrict__ Wb2,
    unsigned* __restrict__ h1d, unsigned* __restrict__ h2d)
{
    if (blockIdx.x == 0) {
        if (threadIdx.x < 32) h1d[(size_t)N_NODES * 32 + threadIdx.x] = 0;
        if (threadIdx.x < 16) h2d[(size_t)N_NODES * 16 + threadIdx.x] = 0;
    }
    int idx = blockIdx.x * 256 + threadIdx.x;
    if (idx < K_TOT * HID_F) {
        int k = idx >> 7, n = idx & 127;
        int p = k >> 7, f = k & 127;
        int si = f * HID_F + n;
        float v = (p == 0) ? (w1[si] + 0.1f * c1[si * 3])
                           : 0.1f * c1[si * 3 + p];
        Wb1[(((k >> 3) * HID_F) + n) * 8 + (k & 7)] = f2bf(v);
    } else {
        idx -= K_TOT * HID_F;
        if (idx < K_TOT * OUT_F) {
            int k = idx >> 6, n = idx & 63;
            int p = k >> 7, f = k & 127;
            int si = f * OUT_F + n;
            float v = (p == 0) ? (w2[si] + 0.1f * c2[si * 3])
                               : 0.1f * c2[si * 3 + p];
            Wb2[(((k >> 3) * OUT_F) + n) * 8 + (k & 7)] = f2bf(v);
        }
    }
}

// ---------------------------------------------------------------------------
// Bucket sort pass A: coarse histogram (LDS) -> global bucket counts.
// ---------------------------------------------------------------------------
__global__ __launch_bounds__(256) void bucket_hist(
    const int* __restrict__ tgt, int* __restrict__ bucket_cnt)
{
    __shared__ int h[NBUCK];
    int tid = threadIdx.x;
    for (int i = tid; i < NBUCK; i += 256) h[i] = 0;
    __syncthreads();
    int e0 = blockIdx.x * EPB;
    int n = min(EPB, N_EDGES - e0);
    for (int i = tid; i < n; i += 256)
        atomicAdd(&h[tgt[e0 + i] >> BK_BITS], 1);
    __syncthreads();
    for (int i = tid; i < NBUCK; i += 256)
        if (h[i]) atomicAdd(&bucket_cnt[i], h[i]);
}

// Pass B: single-block exclusive scan of NBUCK counts -> offsets + cursors.
__global__ __launch_bounds__(256) void bucket_scan(
    const int* __restrict__ cnt, int* __restrict__ boff, int* __restrict__ bcur)
{
    __shared__ int s[256];
    int tid = threadIdx.x;
    int v = (tid < NBUCK) ? cnt[tid] : 0;
    s[tid] = v;
    __syncthreads();
    for (int o = 1; o < 256; o <<= 1) {
        int t = (tid >= o) ? s[tid - o] : 0;
        __syncthreads();
        s[tid] += t;
        __syncthreads();
    }
    int excl = s[tid] - v;
    if (tid < NBUCK) { boff[tid] = excl; bcur[tid] = excl; }
    if (tid == NBUCK - 1) boff[NBUCK] = excl + v;
}

// Pass C: scatter edges into bucket-sorted packed records (9b tgt | 23b src).
__global__ __launch_bounds__(256) void bucket_scatter(
    const int* __restrict__ src, const int* __restrict__ tgt,
    int* __restrict__ bcur, unsigned* __restrict__ spk)
{
    __shared__ int h[NBUCK];
    __shared__ int base[NBUCK];
    int tid = threadIdx.x;
    for (int i = tid; i < NBUCK; i += 256) h[i] = 0;
    __syncthreads();
    int e0 = blockIdx.x * EPB;
    int n = min(EPB, N_EDGES - e0);
    for (int i = tid; i < n; i += 256)
        atomicAdd(&h[tgt[e0 + i] >> BK_BITS], 1);
    __syncthreads();
    for (int i = tid; i < NBUCK; i += 256) {
        int c = h[i];
        base[i] = c ? atomicAdd(&bcur[i], c) : 0;
        h[i] = 0;
    }
    __syncthreads();
    for (int i = tid; i < n; i += 256) {
        int t = tgt[e0 + i];
        int b = t >> BK_BITS;
        int pos = base[b] + atomicAdd(&h[b], 1);
        spk[pos] = ((unsigned)(t - (b << BK_BITS)) << 23) | (unsigned)src[e0 + i];
    }
}

// Pass D: per-bucket degree histogram -> real row_start (block scan) and
// per-bucket PADDED total (pbsum).
__global__ __launch_bounds__(256) void bucket_rowstart(
    const int* __restrict__ boff, const unsigned* __restrict__ spk,
    int* __restrict__ row_start, int* __restrict__ pbsum)
{
    __shared__ int d[BK_SIZE];
    __shared__ int s[256];
    int tid = threadIdx.x;
    int b = blockIdx.x;
    d[tid] = 0; d[tid + 256] = 0;
    __syncthreads();
    int e0 = boff[b], e1 = boff[b + 1];
    for (int i = e0 + tid; i < e1; i += 256)
        atomicAdd(&d[spk[i] >> 23], 1);
    __syncthreads();
    int a0 = d[2 * tid], a1c = d[2 * tid + 1];
    int tsum = a0 + a1c;
    s[tid] = tsum;
    __syncthreads();
    for (int o = 1; o < 256; o <<= 1) {
        int t = (tid >= o) ? s[tid - o] : 0;
        __syncthreads();
        s[tid] += t;
        __syncthreads();
    }
    int excl = s[tid] - tsum;
    int nbase = b << BK_BITS;
    int n0 = nbase + 2 * tid, n1 = n0 + 1;
    int rs0 = e0 + excl;
    if (n0 < N_NODES) row_start[n0] = rs0;
    if (n1 < N_NODES) row_start[n1] = rs0 + a0;
    if (b == NBUCK - 1 && tid == 0) row_start[N_NODES] = boff[NBUCK];

    // padded bucket total
    int pc0 = (n0 < N_NODES) ? PAD8(a0) : 0;
    int pc1 = (n1 < N_NODES) ? PAD8(a1c) : 0;
    __syncthreads();
    s[tid] = pc0 + pc1;
    __syncthreads();
    for (int o = 128; o > 0; o >>= 1) {
        if (tid < o) s[tid] += s[tid + o];
        __syncthreads();
    }
    if (tid == 0) pbsum[b] = s[0];
}

// Pass E (merged): per-block redundant scan of pbsum -> pboff[b]; per-node
// padded prefix -> prow; fine CSR fill with LDS cursors + sentinel pads.
// Replaces the old bucket_scan#2 + bucket_prow + csr_fine_pad.
__global__ __launch_bounds__(256) void csr_finalize(
    const int* __restrict__ boff, const unsigned* __restrict__ spk,
    const int* __restrict__ row_start, const int* __restrict__ pbsum,
    int* __restrict__ prow, int* __restrict__ csr_pad)
{
    __shared__ int s[256];
    __shared__ int cur[BK_SIZE];
    int tid = threadIdx.x;
    int b = blockIdx.x;

    // 1) scan pbsum (196 entries) in LDS -> this block's padded base
    int v = (tid < NBUCK) ? pbsum[tid] : 0;
    s[tid] = v;
    __syncthreads();
    for (int o = 1; o < 256; o <<= 1) {
        int t = (tid >= o) ? s[tid - o] : 0;
        __syncthreads();
        s[tid] += t;
        __syncthreads();
    }
    int pboff_b = (b > 0) ? s[b - 1] : 0;
    int ptotal  = s[NBUCK - 1];
    __syncthreads();

    // 2) per-node padded prefix within this bucket (2 nodes/thread)
    int nbase = b << BK_BITS;
    int n0 = nbase + 2 * tid, n1 = n0 + 1;
    int d0 = (n0 < N_NODES) ? row_start[n0 + 1] - row_start[n0] : 0;
    int d1 = (n1 < N_NODES) ? row_start[n1 + 1] - row_start[n1] : 0;
    int pc0 = (n0 < N_NODES) ? PAD8(d0) : 0;
    int pc1 = (n1 < N_NODES) ? PAD8(d1) : 0;
    int tsum = pc0 + pc1;
    s[tid] = tsum;
    __syncthreads();
    for (int o = 1; o < 256; o <<= 1) {
        int t = (tid >= o) ? s[tid - o] : 0;
        __syncthreads();
        s[tid] += t;
        __syncthreads();
    }
    int excl = s[tid] - tsum;
    int base = pboff_b + excl;
    if (n0 < N_NODES) { prow[n0] = base;       cur[2 * tid]     = base; }
    if (n1 < N_NODES) { prow[n1] = base + pc0; cur[2 * tid + 1] = base + pc0; }
    if (b == NBUCK - 1 && tid == 0) prow[N_NODES] = ptotal;
    __syncthreads();

    // 3) fill from spk
    int e0 = boff[b], e1 = boff[b + 1];
    for (int i = e0 + tid; i < e1; i += 256) {
        unsigned pk = spk[i];
        int pos = atomicAdd(&cur[pk >> 23], 1);
        csr_pad[pos] = (int)(pk & PK_SRC_MASK);
    }
    __syncthreads();

    // 4) sentinel pad slots
    for (int i = tid; i < BK_SIZE; i += 256) {
        int nd = nbase + i;
        if (nd < N_NODES) {
            int kend = prow[nd] + PAD8(row_start[nd + 1] - row_start[nd]);
            for (int k = cur[i]; k < kend; ++k) csr_pad[k] = N_NODES;
        }
    }
}

// ---------------------------------------------------------------------------
// KAN1 via MFMA bf16 (block = 64 nodes x 128 out, 4 waves 2x2).
// Epilogue: +bias, ReLU, fp8-pack 4 cols into one dword (permuted order:
// dword d holds feats 64*(d>>4)+(d&15)+16b for byte b).
// ---------------------------------------------------------------------------
__global__ __launch_bounds__(256) void kan1_mfma(
    const float* __restrict__ x, const short* __restrict__ Wb,
    const float* __restrict__ bias, unsigned* __restrict__ h1d)
{
    __shared__ float sx[64 * XLDS_STRIDE];
    const int tid  = threadIdx.x;
    const int lane = tid & 63;
    const int wave = tid >> 6;
    const int node0 = blockIdx.x * 64;
    const int q = lane >> 4, r = lane & 15;

#pragma unroll
    for (int it = 0; it < 8; ++it) {
        int idx = tid + 256 * it;
        int m = idx >> 5, c4 = (idx & 31) * 4;
        int gm = min(node0 + m, N_NODES - 1);
        float4 v = *(const float4*)(x + (size_t)gm * IN_F + c4);
        *(float4*)(sx + m * XLDS_STRIDE + c4) = v;
    }
    __syncthreads();

    const int wm = (wave & 1) * 32;
    const int wn = (wave >> 1) * 64;

    f4v acc[2][4];
#pragma unroll
    for (int i = 0; i < 2; ++i)
#pragma unroll
        for (int j = 0; j < 4; ++j)
            acc[i][j] = (f4v){0.f, 0.f, 0.f, 0.f};

    float bj[4];
#pragma unroll
    for (int j = 0; j < 4; ++j) bj[j] = bias[wn + j * 16 + r];

#pragma unroll
    for (int kb = 0; kb < 12; ++kb) {
        const int p  = kb >> 2;
        const int f0 = (kb & 3) * 32 + q * 8;

        s8v afrag[2];
#pragma unroll
        for (int i = 0; i < 2; ++i) {
            const float* xs = sx + (wm + i * 16 + r) * XLDS_STRIDE + f0;
            float4 v0 = *(const float4*)xs;
            float4 v1 = *(const float4*)(xs + 4);
            float v[8] = {v0.x, v0.y, v0.z, v0.w, v1.x, v1.y, v1.z, v1.w};
            s8v a;
#pragma unroll
            for (int t = 0; t < 8; ++t) {
                float e = v[t];
                if (p >= 1) e *= v[t];
                if (p == 2) e *= v[t];
                a[t] = f2bf(e);
            }
            afrag[i] = a;
        }
#pragma unroll
        for (int j = 0; j < 4; ++j) {
            const s8v b = *(const s8v*)(Wb + (((kb * 4 + q) * HID_F) + wn + j * 16 + r) * 8);
            acc[0][j] = __builtin_amdgcn_mfma_f32_16x16x32_bf16(afrag[0], b, acc[0][j], 0, 0, 0);
            acc[1][j] = __builtin_amdgcn_mfma_f32_16x16x32_bf16(afrag[1], b, acc[1][j], 0, 0, 0);
        }
    }

    const int dci = ((wn >> 6) << 4) + r;
#pragma unroll
    for (int i = 0; i < 2; ++i)
#pragma unroll
        for (int e = 0; e < 4; ++e) {
            int grow = node0 + wm + i * 16 + q * 4 + e;
            if (grow < N_NODES) {
                float v0 = fmaxf(acc[i][0][e] + bj[0], 0.f);
                float v1 = fmaxf(acc[i][1][e] + bj[1], 0.f);
                float v2 = fmaxf(acc[i][2][e] + bj[2], 0.f);
                float v3 = fmaxf(acc[i][3][e] + bj[3], 0.f);
                int pk = __builtin_amdgcn_cvt_pk_fp8_f32(v0, v1, 0, false);
                pk = __builtin_amdgcn_cvt_pk_fp8_f32(v2, v3, pk, true);
                h1d[(size_t)grow * 32 + dci] = (unsigned)pk;
            }
        }
}

// ---------------------------------------------------------------------------
// Gather-aggregate over 128 fp8 feats.  TWO nodes per wave; lane loads one
// dword (4 fp8) per message; cvt_pk decode; depth-4 chains.  Output a1 is
// fp8 in the SAME permuted layout (register sums pack directly).
// ---------------------------------------------------------------------------
__global__ __launch_bounds__(256) void gather128(
    const unsigned* __restrict__ h1d, const int* __restrict__ prow,
    const int* __restrict__ csr_pad, unsigned* __restrict__ a1d)
{
    const int lane  = threadIdx.x & 63;
    const int wave  = threadIdx.x >> 6;
    const int hl    = lane & 31;
    const int half  = lane >> 5;
    const int hbase = half << 5;
    const int node  = blockIdx.x * 8 + wave * 2 + half;   // grid exact: 12500*8

    int p0 = prow[node], p1 = prow[node + 1];
    int cnt = p1 - p0;                                    // multiple of 8
    int cmax = max(cnt, __shfl_xor(cnt, 32));

    float acc[4][4];
#pragma unroll
    for (int t = 0; t < 4; ++t)
#pragma unroll
        for (int b = 0; b < 4; ++b) acc[t][b] = 0.f;

    for (int base = 0; base < cmax; base += 32) {
        int idx = max(min(p0 + base + hl, p1 - 1), 0);
        int sreg = csr_pad[idx];
        int lim = min(32, cmax - base);
        for (int j = 0; j < lim; j += 4) {
            if (base + j < cnt) {
                unsigned u[4];
#pragma unroll
                for (int t = 0; t < 4; ++t) {
                    int sj = __shfl(sreg, hbase + j + t);
                    u[t] = h1d[(size_t)sj * 32 + hl];
                }
#pragma unroll
                for (int t = 0; t < 4; ++t) {
                    f2v lo = __builtin_amdgcn_cvt_pk_f32_fp8(u[t], false);
                    f2v hi = __builtin_amdgcn_cvt_pk_f32_fp8(u[t], true);
                    acc[t][0] += lo.x; acc[t][1] += lo.y;
                    acc[t][2] += hi.x; acc[t][3] += hi.y;
                }
            }
        }
    }

    float s0 = (acc[0][0] + acc[1][0]) + (acc[2][0] + acc[3][0]);
    float s1 = (acc[0][1] + acc[1][1]) + (acc[2][1] + acc[3][1]);
    float s2 = (acc[0][2] + acc[1][2]) + (acc[2][2] + acc[3][2]);
    float s3 = (acc[0][3] + acc[1][3]) + (acc[2][3] + acc[3][3]);
    int pk = __builtin_amdgcn_cvt_pk_fp8_f32(s0, s1, 0, false);
    pk = __builtin_amdgcn_cvt_pk_fp8_f32(s2, s3, pk, true);
    a1d[(size_t)node * 32 + hl] = (unsigned)pk;
}

// ---------------------------------------------------------------------------
// KAN2 via MFMA bf16; reads fp8 a1 (permuted), un-permutes + applies 1/deg
// while staging to LDS (canonical order).  Epilogue: fp8 h2 pair-packed:
// ushort s = (wn>>1)+r holds feats (wn+r) [byte0], (wn+16+r) [byte1].
// ---------------------------------------------------------------------------
__global__ __launch_bounds__(256) void kan2_mfma(
    const unsigned* __restrict__ a1d, const int* __restrict__ row_start,
    const short* __restrict__ Wb, const float* __restrict__ bias,
    unsigned short* __restrict__ h2s)
{
    __shared__ float sx[64 * XLDS_STRIDE];
    const int tid  = threadIdx.x;
    const int lane = tid & 63;
    const int wave = tid >> 6;
    const int node0 = blockIdx.x * 64;
    const int q = lane >> 4, r = lane & 15;

#pragma unroll
    for (int it = 0; it < 8; ++it) {
        int idx = tid + 256 * it;              // 0..2047 = 64 rows x 32 dwords
        int m = idx >> 5, c = idx & 31;
        int gm = min(node0 + m, N_NODES - 1);
        float di = 1.0f / fmaxf((float)(row_start[gm + 1] - row_start[gm]), 1.0f);
        unsigned u = a1d[(size_t)gm * 32 + c];
        f2v lo = __builtin_amdgcn_cvt_pk_f32_fp8(u, false);
        f2v hi = __builtin_amdgcn_cvt_pk_f32_fp8(u, true);
        float* row = sx + m * XLDS_STRIDE + (((c >> 4) << 6) + (c & 15));
        row[0]  = lo.x * di;
        row[16] = lo.y * di;
        row[32] = hi.x * di;
        row[48] = hi.y * di;
    }
    __syncthreads();

    const int wm = (wave & 1) * 32;
    const int wn = (wave >> 1) * 32;

    f4v acc[2][2];
#pragma unroll
    for (int i = 0; i < 2; ++i)
#pragma unroll
        for (int j = 0; j < 2; ++j)
            acc[i][j] = (f4v){0.f, 0.f, 0.f, 0.f};

    float bj[2];
#pragma unroll
    for (int j = 0; j < 2; ++j) bj[j] = bias[wn + j * 16 + r];

#pragma unroll
    for (int kb = 0; kb < 12; ++kb) {
        const int p  = kb >> 2;
        const int f0 = (kb & 3) * 32 + q * 8;

        s8v afrag[2];
#pragma unroll
        for (int i = 0; i < 2; ++i) {
            const float* xs = sx + (wm + i * 16 + r) * XLDS_STRIDE + f0;
            float4 v0 = *(const float4*)xs;
            float4 v1 = *(const float4*)(xs + 4);
            float v[8] = {v0.x, v0.y, v0.z, v0.w, v1.x, v1.y, v1.z, v1.w};
            s8v a;
#pragma unroll
            for (int t = 0; t < 8; ++t) {
                float e = v[t];
                if (p >= 1) e *= v[t];
                if (p == 2) e *= v[t];
                a[t] = f2bf(e);
            }
            afrag[i] = a;
        }
#pragma unroll
        for (int j = 0; j < 2; ++j) {
            const s8v b = *(const s8v*)(Wb + (((kb * 4 + q) * OUT_F) + wn + j * 16 + r) * 8);
            acc[0][j] = __builtin_amdgcn_mfma_f32_16x16x32_bf16(afrag[0], b, acc[0][j], 0, 0, 0);
            acc[1][j] = __builtin_amdgcn_mfma_f32_16x16x32_bf16(afrag[1], b, acc[1][j], 0, 0, 0);
        }
    }

    const int s = (wn >> 1) + r;               // ushort slot in h2 row
#pragma unroll
    for (int i = 0; i < 2; ++i)
#pragma unroll
        for (int e = 0; e < 4; ++e) {
            int grow = node0 + wm + i * 16 + q * 4 + e;
            if (grow < N_NODES) {
                float vlo = acc[i][0][e] + bj[0];
                float vhi = acc[i][1][e] + bj[1];
                int pk = __builtin_amdgcn_cvt_pk_fp8_f32(vlo, vhi, 0, false);
                h2s[(size_t)grow * 32 + s] = (unsigned short)(pk & 0xffff);
            }
        }
}

// ---------------------------------------------------------------------------
// Gather-aggregate over 64 fp8 feats + 1/deg + log_softmax.
// TWO nodes per wave; lane hl loads ushort (2 fp8 feats):
//   f_lo = 32*(hl>>4) + (hl&15), f_hi = f_lo + 16.
// ---------------------------------------------------------------------------
__global__ __launch_bounds__(256) void gather64_lsm(
    const unsigned short* __restrict__ h2s, const int* __restrict__ row_start,
    const int* __restrict__ prow, const int* __restrict__ csr_pad,
    float* __restrict__ out)
{
    const int lane = threadIdx.x & 63;
    const int wave = threadIdx.x >> 6;
    const int hl   = lane & 31;
    const int half = lane >> 5;
    const int node = blockIdx.x * 8 + wave * 2 + half;   // grid exact: 12500*8

    int p0 = prow[node], p1 = prow[node + 1];
    int cnt = p1 - p0;
    int degr = row_start[node + 1] - row_start[node];
    int cmax = max(cnt, __shfl_xor(cnt, 32));

    float alo[8], ahi[8];
#pragma unroll
    for (int t = 0; t < 8; ++t) { alo[t] = 0.f; ahi[t] = 0.f; }

    for (int base = 0; base < cmax; base += 32) {
        int idx = max(min(p0 + base + hl, p1 - 1), 0);
        int sreg = csr_pad[idx];
        int lim = min(32, cmax - base);
        for (int j = 0; j < lim; j += 8) {
            if (base + j < cnt) {
                int u[8];
#pragma unroll
                for (int t = 0; t < 8; ++t) {
                    int sj = __shfl(sreg, (half << 5) + j + t);
                    u[t] = (int)h2s[(size_t)sj * 32 + hl];
                }
#pragma unroll
                for (int t = 0; t < 8; ++t) {
                    alo[t] += __builtin_amdgcn_cvt_f32_fp8(u[t], 0);
                    ahi[t] += __builtin_amdgcn_cvt_f32_fp8(u[t], 1);
                }
            }
        }
    }
    float slo = ((alo[0] + alo[1]) + (alo[2] + alo[3])) + ((alo[4] + alo[5]) + (alo[6] + alo[7]));
    float shi = ((ahi[0] + ahi[1]) + (ahi[2] + ahi[3])) + ((ahi[4] + ahi[5]) + (ahi[6] + ahi[7]));

    float di = 1.0f / fmaxf((float)degr, 1.0f);
    float vlo = slo * di, vhi = shi * di;

    float m = fmaxf(vlo, vhi);
#pragma unroll
    for (int off = 16; off >= 1; off >>= 1)
        m = fmaxf(m, __shfl_xor(m, off));     // stays within the 32-lane half
    float e = expf(vlo - m) + expf(vhi - m);
#pragma unroll
    for (int off = 16; off >= 1; off >>= 1)
        e += __shfl_xor(e, off);
    float ls = logf(e);

    const int f_lo = ((hl >> 4) << 5) + (hl & 15);
    out[(size_t)node * OUT_F + f_lo]      = vlo - m - ls;
    out[(size_t)node * OUT_F + f_lo + 16] = vhi - m - ls;
}

// ---------------------------------------------------------------------------
extern "C" void kernel_launch(void* const* d_in, const int* in_sizes, int n_in,
                              void* d_out, int out_size, void* d_ws, size_t ws_size,
                              hipStream_t stream)
{
    const float* x  = (const float*)d_in[0];
    const int*   ei = (const int*)d_in[1];
    const float* w1 = (const float*)d_in[2];
    const float* b1 = (const float*)d_in[3];
    const float* c1 = (const float*)d_in[4];
    const float* w2 = (const float*)d_in[5];
    const float* b2 = (const float*)d_in[6];
    const float* c2 = (const float*)d_in[7];
    float* out = (float*)d_out;

    const int* src = ei;            // edge_index[0]
    const int* tgt = ei + N_EDGES;  // edge_index[1]

    char* ws = (char*)d_ws;
    size_t off = 0;
    auto carve = [&](size_t bytes) -> void* {
        void* p = ws + off;
        off = (off + bytes + 255) & ~(size_t)255;
        return p;
    };
    short*    Wb1       = (short*)carve((size_t)K_TOT * HID_F * 2);
    short*    Wb2       = (short*)carve((size_t)K_TOT * OUT_F * 2);
    int*      row_start = (int*)carve(((size_t)N_NODES + 1) * 4);
    int*      prow      = (int*)carve(((size_t)N_NODES + 1) * 4);
    int*      bucket_cnt= (int*)carve((size_t)NBUCK * 4);
    int*      boff      = (int*)carve(((size_t)NBUCK + 1) * 4);
    int*      bcur      = (int*)carve((size_t)NBUCK * 4);
    int*      pbsum     = (int*)carve((size_t)NBUCK * 4);
    unsigned* spk       = (unsigned*)carve((size_t)N_EDGES * 4);
    int*      csr_pad   = (int*)carve(((size_t)N_EDGES + 7 * (size_t)N_NODES + 64) * 4);
    unsigned* h1d       = (unsigned*)carve(((size_t)N_NODES + 1) * 128);  // fp8, permuted
    unsigned* a1d       = (unsigned*)carve((size_t)N_NODES * 128);        // fp8, permuted
    unsigned short* h2s = (unsigned short*)carve(((size_t)N_NODES + 1) * 64); // fp8 pairs

    const int grid_mm = (N_NODES + 63) / 64;   // 1563

    // --- CSR build via bucket sort (padded layout) ---------------------------
    hipMemsetAsync(bucket_cnt, 0, (size_t)NBUCK * 4, stream);
    bucket_hist<<<NBLK_SORT, 256, 0, stream>>>(tgt, bucket_cnt);
    bucket_scan<<<1, 256, 0, stream>>>(bucket_cnt, boff, bcur);
    bucket_scatter<<<NBLK_SORT, 256, 0, stream>>>(src, tgt, bcur, spk);
    bucket_rowstart<<<NBUCK, 256, 0, stream>>>(boff, spk, row_start, pbsum);
    csr_finalize<<<NBUCK, 256, 0, stream>>>(boff, spk, row_start, pbsum, prow, csr_pad);

    // --- weights + sentinel zero rows + layer 1 ------------------------------
    fold_weights_bf16<<<(K_TOT * HID_F + K_TOT * OUT_F + 255) / 256, 256, 0, stream>>>(
        w1, c1, w2, c2, Wb1, Wb2, h1d, (unsigned*)h2s);
    kan1_mfma<<<grid_mm, 256, 0, stream>>>(x, Wb1, b1, h1d);

    // --- aggregate 1 (gather, fp8 rows, 2 nodes/wave) ------------------------
    gather128<<<(N_NODES + 7) / 8, 256, 0, stream>>>(h1d, prow, csr_pad, a1d);

    // --- layer 2 (fp8 in, fp8 out) -------------------------------------------
    kan2_mfma<<<grid_mm, 256, 0, stream>>>(a1d, row_start, Wb2, b2, h2s);

    // --- aggregate 2 + log_softmax (fused, 2 nodes/wave, fp8) ----------------
    gather64_lsm<<<(N_NODES + 7) / 8, 256, 0, stream>>>(
        h2s, row_start, prow, csr_pad, out);
}

// Round 13
// 256.053 us; speedup vs baseline: 1.7385x; 1.0726x over previous
//
#include <hip/hip_runtime.h>
#include <hip/hip_bf16.h>
#include <math.h>

#define N_NODES 100000
#define N_EDGES 1600000
#define IN_F 128
#define HID_F 128
#define OUT_F 64
#define K_TOT 384                          // 3 basis planes x 128
#define BST 392                            // basis LDS row stride (384 + 8 pad), bf16

// bucket sort parameters
#define BK_BITS 9
#define BK_SIZE 512                        // nodes per bucket
#define NBUCK ((N_NODES + BK_SIZE - 1) / BK_SIZE)   // 196
#define EPB 4096                           // edges per sort block
#define NBLK_SORT ((N_EDGES + EPB - 1) / EPB)       // 391
#define BCAP 10240                         // fixed bucket capacity (mean 8192 + 22 sigma)
// packed edge record: [31:23] local tgt (9b), [22:0] src (17b used)
#define PK_SRC_MASK 0x7fffffu
#define PAD8(d) (((d) + 7) & ~7)

typedef __attribute__((ext_vector_type(8))) short s8v;   // 8 bf16 (MFMA A/B frag)
typedef __attribute__((ext_vector_type(4))) short s4v;   // 4 bf16 (8 B LDS store)
typedef __attribute__((ext_vector_type(4))) float f4v;   // MFMA C/D frag
typedef __attribute__((ext_vector_type(2))) float f2v;   // cvt_pk_f32_fp8 result

__device__ __forceinline__ short f2bf(float f) {
    __hip_bfloat16 h = __float2bfloat16(f);
    return __builtin_bit_cast(short, h);
}

// ---------------------------------------------------------------------------
// Fold KAN weights into bf16 MFMA-B chunk layout; also zero the sentinel
// rows (index N_NODES) of h1 (fp8, 32 dwords) / h2 (fp8, 16 dwords).
// ---------------------------------------------------------------------------
__global__ __launch_bounds__(256) void fold_weights_bf16(
    const float* __restrict__ w1, const float* __restrict__ c1,
    const float* __restrict__ w2, const float* __restrict__ c2,
    short* __restrict__ Wb1, short* __restrict__ Wb2,
    unsigned* __restrict__ h1d, unsigned* __restrict__ h2d)
{
    if (blockIdx.x == 0) {
        if (threadIdx.x < 32) h1d[(size_t)N_NODES * 32 + threadIdx.x] = 0;
        if (threadIdx.x < 16) h2d[(size_t)N_NODES * 16 + threadIdx.x] = 0;
    }
    int idx = blockIdx.x * 256 + threadIdx.x;
    if (idx < K_TOT * HID_F) {
        int k = idx >> 7, n = idx & 127;
        int p = k >> 7, f = k & 127;
        int si = f * HID_F + n;
        float v = (p == 0) ? (w1[si] + 0.1f * c1[si * 3])
                           : 0.1f * c1[si * 3 + p];
        Wb1[(((k >> 3) * HID_F) + n) * 8 + (k & 7)] = f2bf(v);
    } else {
        idx -= K_TOT * HID_F;
        if (idx < K_TOT * OUT_F) {
            int k = idx >> 6, n = idx & 63;
            int p = k >> 7, f = k & 127;
            int si = f * OUT_F + n;
            float v = (p == 0) ? (w2[si] + 0.1f * c2[si * 3])
                               : 0.1f * c2[si * 3 + p];
            Wb2[(((k >> 3) * OUT_F) + n) * 8 + (k & 7)] = f2bf(v);
        }
    }
}

// ---------------------------------------------------------------------------
// Seed per-bucket global cursors to fixed-capacity windows.
// ---------------------------------------------------------------------------
__global__ __launch_bounds__(256) void bucket_init(int* __restrict__ bcur)
{
    int i = threadIdx.x;
    if (i < NBUCK) bcur[i] = i * BCAP;
}

// Scatter edges into fixed-capacity bucket windows (9b tgt | 23b src).
// Each (block,bucket) group reserves a contiguous range from the global
// cursor, then fills it via an LDS sub-cursor.
__global__ __launch_bounds__(256) void bucket_scatter(
    const int* __restrict__ src, const int* __restrict__ tgt,
    int* __restrict__ bcur, unsigned* __restrict__ spk)
{
    __shared__ int h[NBUCK];
    __shared__ int base[NBUCK];
    int tid = threadIdx.x;
    for (int i = tid; i < NBUCK; i += 256) h[i] = 0;
    __syncthreads();
    int e0 = blockIdx.x * EPB;
    int n = min(EPB, N_EDGES - e0);
    for (int i = tid; i < n; i += 256)
        atomicAdd(&h[tgt[e0 + i] >> BK_BITS], 1);
    __syncthreads();
    for (int i = tid; i < NBUCK; i += 256) {
        int c = h[i];
        base[i] = c ? atomicAdd(&bcur[i], c) : 0;
        h[i] = 0;
    }
    __syncthreads();
    for (int i = tid; i < n; i += 256) {
        int t = tgt[e0 + i];
        int b = t >> BK_BITS;
        int pos = base[b] + atomicAdd(&h[b], 1);
        spk[pos] = ((unsigned)(t - (b << BK_BITS)) << 23) | (unsigned)src[e0 + i];
    }
}

// Per-bucket degree histogram -> deg[] + padded bucket total pbsum[b].
__global__ __launch_bounds__(256) void bucket_degpad(
    const int* __restrict__ bcur, const unsigned* __restrict__ spk,
    int* __restrict__ deg, int* __restrict__ pbsum)
{
    __shared__ int d[BK_SIZE];
    __shared__ int s[256];
    int tid = threadIdx.x;
    int b = blockIdx.x;
    d[tid] = 0; d[tid + 256] = 0;
    __syncthreads();
    int e0 = b * BCAP, e1 = bcur[b];
    for (int i = e0 + tid; i < e1; i += 256)
        atomicAdd(&d[spk[i] >> 23], 1);
    __syncthreads();
    int nbase = b << BK_BITS;
    int a0 = d[2 * tid], a1c = d[2 * tid + 1];
    int n0 = nbase + 2 * tid, n1 = n0 + 1;
    if (n0 < N_NODES) deg[n0] = a0;
    if (n1 < N_NODES) deg[n1] = a1c;
    int pc0 = (n0 < N_NODES) ? PAD8(a0) : 0;
    int pc1 = (n1 < N_NODES) ? PAD8(a1c) : 0;
    s[tid] = pc0 + pc1;
    __syncthreads();
    for (int o = 128; o > 0; o >>= 1) {
        if (tid < o) s[tid] += s[tid + o];
        __syncthreads();
    }
    if (tid == 0) pbsum[b] = s[0];
}

// Finalize: redundant pbsum scan -> bucket base; per-node PAD8(deg) scan ->
// prow; fill padded CSR with LDS cursors; write sentinel pad slots.
__global__ __launch_bounds__(256) void csr_finalize(
    const int* __restrict__ bcur, const unsigned* __restrict__ spk,
    const int* __restrict__ deg, const int* __restrict__ pbsum,
    int* __restrict__ prow, int* __restrict__ csr_pad)
{
    __shared__ int s[256];
    __shared__ int cur[BK_SIZE];
    __shared__ int pst[BK_SIZE];
    int tid = threadIdx.x;
    int b = blockIdx.x;

    // 1) scan pbsum (196 entries) -> this bucket's padded base
    int v = (tid < NBUCK) ? pbsum[tid] : 0;
    s[tid] = v;
    __syncthreads();
    for (int o = 1; o < 256; o <<= 1) {
        int t = (tid >= o) ? s[tid - o] : 0;
        __syncthreads();
        s[tid] += t;
        __syncthreads();
    }
    int pboff_b = (b > 0) ? s[b - 1] : 0;
    int ptotal  = s[NBUCK - 1];
    __syncthreads();

    // 2) per-node padded prefix (2 nodes/thread)
    int nbase = b << BK_BITS;
    int n0 = nbase + 2 * tid, n1 = n0 + 1;
    int d0 = (n0 < N_NODES) ? deg[n0] : 0;
    int d1 = (n1 < N_NODES) ? deg[n1] : 0;
    int pc0 = (n0 < N_NODES) ? PAD8(d0) : 0;
    int pc1 = (n1 < N_NODES) ? PAD8(d1) : 0;
    int tsum = pc0 + pc1;
    s[tid] = tsum;
    __syncthreads();
    for (int o = 1; o < 256; o <<= 1) {
        int t = (tid >= o) ? s[tid - o] : 0;
        __syncthreads();
        s[tid] += t;
        __syncthreads();
    }
    int excl = s[tid] - tsum;
    int base = pboff_b + excl;
    if (n0 < N_NODES) { prow[n0] = base;       cur[2 * tid]     = base;       pst[2 * tid]     = base + pc0; }
    if (n1 < N_NODES) { prow[n1] = base + pc0; cur[2 * tid + 1] = base + pc0; pst[2 * tid + 1] = base + pc0 + pc1; }
    if (b == NBUCK - 1 && tid == 0) prow[N_NODES] = ptotal;
    __syncthreads();

    // 3) fill from spk
    int e0 = b * BCAP, e1 = bcur[b];
    for (int i = e0 + tid; i < e1; i += 256) {
        unsigned pk = spk[i];
        int pos = atomicAdd(&cur[pk >> 23], 1);
        csr_pad[pos] = (int)(pk & PK_SRC_MASK);
    }
    __syncthreads();

    // 4) sentinel pad slots (pst holds each node's padded end)
    for (int i = tid; i < BK_SIZE; i += 256) {
        int nd = nbase + i;
        if (nd < N_NODES) {
            int kend = pst[i];
            for (int k = cur[i]; k < kend; ++k) csr_pad[k] = N_NODES;
        }
    }
}

// ---------------------------------------------------------------------------
// KAN1 via MFMA bf16.  Staging computes the bf16 basis (x, x^2, x^3) into
// LDS once (64 x 392 bf16): A-frags become single ds_read_b128, no cvt/pow
// in the MFMA loop.  Epilogue: +bias, ReLU, fp8-pack 4 cols per dword
// (permuted order: dword d holds feats 64*(d>>4)+(d&15)+16b for byte b).
// ---------------------------------------------------------------------------
__global__ __launch_bounds__(256) void kan1_mfma(
    const float* __restrict__ x, const short* __restrict__ Wb,
    const float* __restrict__ bias, unsigned* __restrict__ h1d)
{
    __shared__ short sb[64 * BST];   // 50 KB
    const int tid  = threadIdx.x;
    const int lane = tid & 63;
    const int wave = tid >> 6;
    const int node0 = blockIdx.x * 64;
    const int q = lane >> 4, r = lane & 15;

#pragma unroll
    for (int it = 0; it < 8; ++it) {
        int idx = tid + 256 * it;            // 2048 float4 groups
        int m = idx >> 5, c4 = (idx & 31) * 4;
        int gm = min(node0 + m, N_NODES - 1);
        float4 v = *(const float4*)(x + (size_t)gm * IN_F + c4);
        float vv[4] = {v.x, v.y, v.z, v.w};
        s4v p0, p1, p2;
#pragma unroll
        for (int t = 0; t < 4; ++t) {
            float e = vv[t], e2 = e * e, e3 = e2 * e;
            p0[t] = f2bf(e); p1[t] = f2bf(e2); p2[t] = f2bf(e3);
        }
        short* row = sb + m * BST + c4;
        *(s4v*)(row)       = p0;
        *(s4v*)(row + 128) = p1;
        *(s4v*)(row + 256) = p2;
    }
    __syncthreads();

    const int wm = (wave & 1) * 32;
    const int wn = (wave >> 1) * 64;

    f4v acc[2][4];
#pragma unroll
    for (int i = 0; i < 2; ++i)
#pragma unroll
        for (int j = 0; j < 4; ++j)
            acc[i][j] = (f4v){0.f, 0.f, 0.f, 0.f};

    float bj[4];
#pragma unroll
    for (int j = 0; j < 4; ++j) bj[j] = bias[wn + j * 16 + r];

#pragma unroll
    for (int kb = 0; kb < 12; ++kb) {
        const int col = kb * 32 + q * 8;
        s8v afrag[2];
#pragma unroll
        for (int i = 0; i < 2; ++i)
            afrag[i] = *(const s8v*)(sb + (wm + i * 16 + r) * BST + col);
#pragma unroll
        for (int j = 0; j < 4; ++j) {
            const s8v b = *(const s8v*)(Wb + (((kb * 4 + q) * HID_F) + wn + j * 16 + r) * 8);
            acc[0][j] = __builtin_amdgcn_mfma_f32_16x16x32_bf16(afrag[0], b, acc[0][j], 0, 0, 0);
            acc[1][j] = __builtin_amdgcn_mfma_f32_16x16x32_bf16(afrag[1], b, acc[1][j], 0, 0, 0);
        }
    }

    const int dci = ((wn >> 6) << 4) + r;
#pragma unroll
    for (int i = 0; i < 2; ++i)
#pragma unroll
        for (int e = 0; e < 4; ++e) {
            int grow = node0 + wm + i * 16 + q * 4 + e;
            if (grow < N_NODES) {
                float v0 = fmaxf(acc[i][0][e] + bj[0], 0.f);
                float v1 = fmaxf(acc[i][1][e] + bj[1], 0.f);
                float v2 = fmaxf(acc[i][2][e] + bj[2], 0.f);
                float v3 = fmaxf(acc[i][3][e] + bj[3], 0.f);
                int pk = __builtin_amdgcn_cvt_pk_fp8_f32(v0, v1, 0, false);
                pk = __builtin_amdgcn_cvt_pk_fp8_f32(v2, v3, pk, true);
                h1d[(size_t)grow * 32 + dci] = (unsigned)pk;
            }
        }
}

// ---------------------------------------------------------------------------
// Gather-aggregate over 128 fp8 feats.  TWO nodes per wave; lane loads one
// dword (4 fp8) per message; cvt_pk decode; depth-4 chains.  Output a1 is
// fp8 in the SAME permuted layout.
// ---------------------------------------------------------------------------
__global__ __launch_bounds__(256) void gather128(
    const unsigned* __restrict__ h1d, const int* __restrict__ prow,
    const int* __restrict__ csr_pad, unsigned* __restrict__ a1d)
{
    const int lane  = threadIdx.x & 63;
    const int wave  = threadIdx.x >> 6;
    const int hl    = lane & 31;
    const int half  = lane >> 5;
    const int hbase = half << 5;
    const int node  = blockIdx.x * 8 + wave * 2 + half;   // grid exact: 12500*8

    int p0 = prow[node], p1 = prow[node + 1];
    int cnt = p1 - p0;                                    // multiple of 8
    int cmax = max(cnt, __shfl_xor(cnt, 32));

    float acc[4][4];
#pragma unroll
    for (int t = 0; t < 4; ++t)
#pragma unroll
        for (int b = 0; b < 4; ++b) acc[t][b] = 0.f;

    for (int base = 0; base < cmax; base += 32) {
        int idx = max(min(p0 + base + hl, p1 - 1), 0);
        int sreg = csr_pad[idx];
        int lim = min(32, cmax - base);
        for (int j = 0; j < lim; j += 4) {
            if (base + j < cnt) {
                unsigned u[4];
#pragma unroll
                for (int t = 0; t < 4; ++t) {
                    int sj = __shfl(sreg, hbase + j + t);
                    u[t] = h1d[(size_t)sj * 32 + hl];
                }
#pragma unroll
                for (int t = 0; t < 4; ++t) {
                    f2v lo = __builtin_amdgcn_cvt_pk_f32_fp8(u[t], false);
                    f2v hi = __builtin_amdgcn_cvt_pk_f32_fp8(u[t], true);
                    acc[t][0] += lo.x; acc[t][1] += lo.y;
                    acc[t][2] += hi.x; acc[t][3] += hi.y;
                }
            }
        }
    }

    float s0 = (acc[0][0] + acc[1][0]) + (acc[2][0] + acc[3][0]);
    float s1 = (acc[0][1] + acc[1][1]) + (acc[2][1] + acc[3][1]);
    float s2 = (acc[0][2] + acc[1][2]) + (acc[2][2] + acc[3][2]);
    float s3 = (acc[0][3] + acc[1][3]) + (acc[2][3] + acc[3][3]);
    int pk = __builtin_amdgcn_cvt_pk_fp8_f32(s0, s1, 0, false);
    pk = __builtin_amdgcn_cvt_pk_fp8_f32(s2, s3, pk, true);
    a1d[(size_t)node * 32 + hl] = (unsigned)pk;
}

// ---------------------------------------------------------------------------
// KAN2 via MFMA bf16.  Staging decodes fp8 a1 (permuted), applies 1/deg,
// computes the bf16 basis into LDS (canonical column order, 3 planes).
// Epilogue: fp8 h2 pair-packed (ushort (wn>>1)+r = feats wn+r, wn+16+r).
// ---------------------------------------------------------------------------
__global__ __launch_bounds__(256) void kan2_mfma(
    const unsigned* __restrict__ a1d, const int* __restrict__ deg,
    const short* __restrict__ Wb, const float* __restrict__ bias,
    unsigned short* __restrict__ h2s)
{
    __shared__ short sb[64 * BST];   // 50 KB
    const int tid  = threadIdx.x;
    const int lane = tid & 63;
    const int wave = tid >> 6;
    const int node0 = blockIdx.x * 64;
    const int q = lane >> 4, r = lane & 15;

    // staging: 512 groups of 4 consecutive dwords (16 fp8 feats), 2/thread
#pragma unroll
    for (int gi = 0; gi < 2; ++gi) {
        int g = tid + 256 * gi;
        int m = g >> 3, cg = (g & 7) * 4;
        int gm = min(node0 + m, N_NODES - 1);
        float di = 1.0f / fmaxf((float)deg[gm], 1.0f);
        uint4 u4 = *(const uint4*)(a1d + (size_t)gm * 32 + cg);
        unsigned uw[4] = {u4.x, u4.y, u4.z, u4.w};
        float xv[4][4];
#pragma unroll
        for (int j = 0; j < 4; ++j) {
            f2v lo = __builtin_amdgcn_cvt_pk_f32_fp8(uw[j], false);
            f2v hi = __builtin_amdgcn_cvt_pk_f32_fp8(uw[j], true);
            xv[j][0] = lo.x * di; xv[j][1] = lo.y * di;
            xv[j][2] = hi.x * di; xv[j][3] = hi.y * di;
        }
        int fb = ((cg >> 4) << 6) + (cg & 15);
#pragma unroll
        for (int b = 0; b < 4; ++b) {
            s4v p0, p1, p2;
#pragma unroll
            for (int j = 0; j < 4; ++j) {
                float e = xv[j][b], e2 = e * e, e3 = e2 * e;
                p0[j] = f2bf(e); p1[j] = f2bf(e2); p2[j] = f2bf(e3);
            }
            short* row = sb + m * BST + fb + 16 * b;
            *(s4v*)(row)       = p0;
            *(s4v*)(row + 128) = p1;
            *(s4v*)(row + 256) = p2;
        }
    }
    __syncthreads();

    const int wm = (wave & 1) * 32;
    const int wn = (wave >> 1) * 32;

    f4v acc[2][2];
#pragma unroll
    for (int i = 0; i < 2; ++i)
#pragma unroll
        for (int j = 0; j < 2; ++j)
            acc[i][j] = (f4v){0.f, 0.f, 0.f, 0.f};

    float bj[2];
#pragma unroll
    for (int j = 0; j < 2; ++j) bj[j] = bias[wn + j * 16 + r];

#pragma unroll
    for (int kb = 0; kb < 12; ++kb) {
        const int col = kb * 32 + q * 8;
        s8v afrag[2];
#pragma unroll
        for (int i = 0; i < 2; ++i)
            afrag[i] = *(const s8v*)(sb + (wm + i * 16 + r) * BST + col);
#pragma unroll
        for (int j = 0; j < 2; ++j) {
            const s8v b = *(const s8v*)(Wb + (((kb * 4 + q) * OUT_F) + wn + j * 16 + r) * 8);
            acc[0][j] = __builtin_amdgcn_mfma_f32_16x16x32_bf16(afrag[0], b, acc[0][j], 0, 0, 0);
            acc[1][j] = __builtin_amdgcn_mfma_f32_16x16x32_bf16(afrag[1], b, acc[1][j], 0, 0, 0);
        }
    }

    const int sslot = (wn >> 1) + r;           // ushort slot in h2 row
#pragma unroll
    for (int i = 0; i < 2; ++i)
#pragma unroll
        for (int e = 0; e < 4; ++e) {
            int grow = node0 + wm + i * 16 + q * 4 + e;
            if (grow < N_NODES) {
                float vlo = acc[i][0][e] + bj[0];
                float vhi = acc[i][1][e] + bj[1];
                int pk = __builtin_amdgcn_cvt_pk_fp8_f32(vlo, vhi, 0, false);
                h2s[(size_t)grow * 32 + sslot] = (unsigned short)(pk & 0xffff);
            }
        }
}

// ---------------------------------------------------------------------------
// Gather-aggregate over 64 fp8 feats + 1/deg + log_softmax.
// TWO nodes per wave; lane hl loads ushort (2 fp8 feats):
//   f_lo = 32*(hl>>4) + (hl&15), f_hi = f_lo + 16.
// ---------------------------------------------------------------------------
__global__ __launch_bounds__(256) void gather64_lsm(
    const unsigned short* __restrict__ h2s, const int* __restrict__ deg,
    const int* __restrict__ prow, const int* __restrict__ csr_pad,
    float* __restrict__ out)
{
    const int lane = threadIdx.x & 63;
    const int wave = threadIdx.x >> 6;
    const int hl   = lane & 31;
    const int half = lane >> 5;
    const int node = blockIdx.x * 8 + wave * 2 + half;   // grid exact: 12500*8

    int p0 = prow[node], p1 = prow[node + 1];
    int cnt = p1 - p0;
    int degr = deg[node];
    int cmax = max(cnt, __shfl_xor(cnt, 32));

    float alo[8], ahi[8];
#pragma unroll
    for (int t = 0; t < 8; ++t) { alo[t] = 0.f; ahi[t] = 0.f; }

    for (int base = 0; base < cmax; base += 32) {
        int idx = max(min(p0 + base + hl, p1 - 1), 0);
        int sreg = csr_pad[idx];
        int lim = min(32, cmax - base);
        for (int j = 0; j < lim; j += 8) {
            if (base + j < cnt) {
                int u[8];
#pragma unroll
                for (int t = 0; t < 8; ++t) {
                    int sj = __shfl(sreg, (half << 5) + j + t);
                    u[t] = (int)h2s[(size_t)sj * 32 + hl];
                }
#pragma unroll
                for (int t = 0; t < 8; ++t) {
                    alo[t] += __builtin_amdgcn_cvt_f32_fp8(u[t], 0);
                    ahi[t] += __builtin_amdgcn_cvt_f32_fp8(u[t], 1);
                }
            }
        }
    }
    float slo = ((alo[0] + alo[1]) + (alo[2] + alo[3])) + ((alo[4] + alo[5]) + (alo[6] + alo[7]));
    float shi = ((ahi[0] + ahi[1]) + (ahi[2] + ahi[3])) + ((ahi[4] + ahi[5]) + (ahi[6] + ahi[7]));

    float di = 1.0f / fmaxf((float)degr, 1.0f);
    float vlo = slo * di, vhi = shi * di;

    float m = fmaxf(vlo, vhi);
#pragma unroll
    for (int off = 16; off >= 1; off >>= 1)
        m = fmaxf(m, __shfl_xor(m, off));     // stays within the 32-lane half
    float e = expf(vlo - m) + expf(vhi - m);
#pragma unroll
    for (int off = 16; off >= 1; off >>= 1)
        e += __shfl_xor(e, off);
    float ls = logf(e);

    const int f_lo = ((hl >> 4) << 5) + (hl & 15);
    out[(size_t)node * OUT_F + f_lo]      = vlo - m - ls;
    out[(size_t)node * OUT_F + f_lo + 16] = vhi - m - ls;
}

// ---------------------------------------------------------------------------
extern "C" void kernel_launch(void* const* d_in, const int* in_sizes, int n_in,
                              void* d_out, int out_size, void* d_ws, size_t ws_size,
                              hipStream_t stream)
{
    const float* x  = (const float*)d_in[0];
    const int*   ei = (const int*)d_in[1];
    const float* w1 = (const float*)d_in[2];
    const float* b1 = (const float*)d_in[3];
    const float* c1 = (const float*)d_in[4];
    const float* w2 = (const float*)d_in[5];
    const float* b2 = (const float*)d_in[6];
    const float* c2 = (const float*)d_in[7];
    float* out = (float*)d_out;

    const int* src = ei;            // edge_index[0]
    const int* tgt = ei + N_EDGES;  // edge_index[1]

    char* ws = (char*)d_ws;
    size_t off = 0;
    auto carve = [&](size_t bytes) -> void* {
        void* p = ws + off;
        off = (off + bytes + 255) & ~(size_t)255;
        return p;
    };
    short*    Wb1       = (short*)carve((size_t)K_TOT * HID_F * 2);
    short*    Wb2       = (short*)carve((size_t)K_TOT * OUT_F * 2);
    int*      deg       = (int*)carve((size_t)N_NODES * 4);
    int*      prow      = (int*)carve(((size_t)N_NODES + 1) * 4);
    int*      bcur      = (int*)carve((size_t)NBUCK * 4);
    int*      pbsum     = (int*)carve((size_t)NBUCK * 4);
    unsigned* spk       = (unsigned*)carve((size_t)NBUCK * BCAP * 4);
    int*      csr_pad   = (int*)carve(((size_t)N_EDGES + 7 * (size_t)N_NODES + 64) * 4);
    unsigned* h1d       = (unsigned*)carve(((size_t)N_NODES + 1) * 128);  // fp8, permuted
    unsigned* a1d       = (unsigned*)carve((size_t)N_NODES * 128);        // fp8, permuted
    unsigned short* h2s = (unsigned short*)carve(((size_t)N_NODES + 1) * 64); // fp8 pairs

    const int grid_mm = (N_NODES + 63) / 64;   // 1563

    // --- CSR build via fixed-capacity bucket sort ----------------------------
    bucket_init<<<1, 256, 0, stream>>>(bcur);
    bucket_scatter<<<NBLK_SORT, 256, 0, stream>>>(src, tgt, bcur, spk);
    bucket_degpad<<<NBUCK, 256, 0, stream>>>(bcur, spk, deg, pbsum);
    csr_finalize<<<NBUCK, 256, 0, stream>>>(bcur, spk, deg, pbsum, prow, csr_pad);

    // --- weights + sentinel zero rows + layer 1 ------------------------------
    fold_weights_bf16<<<(K_TOT * HID_F + K_TOT * OUT_F + 255) / 256, 256, 0, stream>>>(
        w1, c1, w2, c2, Wb1, Wb2, h1d, (unsigned*)h2s);
    kan1_mfma<<<grid_mm, 256, 0, stream>>>(x, Wb1, b1, h1d);

    // --- aggregate 1 (gather, fp8 rows, 2 nodes/wave) ------------------------
    gather128<<<(N_NODES + 7) / 8, 256, 0, stream>>>(h1d, prow, csr_pad, a1d);

    // --- layer 2 (fp8 in, fp8 out) -------------------------------------------
    kan2_mfma<<<grid_mm, 256, 0, stream>>>(a1d, deg, Wb2, b2, h2s);

    // --- aggregate 2 + log_softmax (fused, 2 nodes/wave, fp8) ----------------
    gather64_lsm<<<(N_NODES + 7) / 8, 256, 0, stream>>>(
        h2s, deg, prow, csr_pad, out);
}

// Round 14
// 249.201 us; speedup vs baseline: 1.7863x; 1.0275x over previous
//
#include <hip/hip_runtime.h>
#include <hip/hip_bf16.h>
#include <math.h>

#define N_NODES 100000
#define N_EDGES 1600000
#define IN_F 128
#define HID_F 128
#define OUT_F 64
#define K_TOT 384                          // 3 basis planes x 128
#define BST 392                            // basis LDS row stride (384 + 8 pad), bf16

// bucket sort parameters
#define BK_BITS 9
#define BK_SIZE 512                        // nodes per bucket
#define NBUCK ((N_NODES + BK_SIZE - 1) / BK_SIZE)   // 196
#define EPB 4096                           // edges per sort block
#define NBLK_SORT ((N_EDGES + EPB - 1) / EPB)       // 391
#define BCAP 10240                         // fixed bucket capacity (mean 8163 + ~23 sigma)
#define PCAP (BCAP + 7 * BK_SIZE)          // padded bucket capacity: 13824
// packed edge record: [31:23] local tgt (9b), [22:0] src (17b used)
#define PK_SRC_MASK 0x7fffffu
#define PAD8(d) (((d) + 7) & ~7)

typedef __attribute__((ext_vector_type(8))) short s8v;   // 8 bf16 (MFMA A/B frag)
typedef __attribute__((ext_vector_type(4))) short s4v;   // 4 bf16 (8 B LDS store)
typedef __attribute__((ext_vector_type(4))) float f4v;   // MFMA C/D frag
typedef __attribute__((ext_vector_type(2))) float f2v;   // cvt_pk_f32_fp8 result

__device__ __forceinline__ short f2bf(float f) {
    __hip_bfloat16 h = __float2bfloat16(f);
    return __builtin_bit_cast(short, h);
}

// ---------------------------------------------------------------------------
// Fold KAN weights into bf16 MFMA-B chunk layout; zero sentinel rows of
// h1/h2; seed per-bucket scatter cursors (replaces bucket_init).
// ---------------------------------------------------------------------------
__global__ __launch_bounds__(256) void fold_weights_bf16(
    const float* __restrict__ w1, const float* __restrict__ c1,
    const float* __restrict__ w2, const float* __restrict__ c2,
    short* __restrict__ Wb1, short* __restrict__ Wb2,
    unsigned* __restrict__ h1d, unsigned* __restrict__ h2d,
    int* __restrict__ bcur)
{
    if (blockIdx.x == 0) {
        if (threadIdx.x < 32) h1d[(size_t)N_NODES * 32 + threadIdx.x] = 0;
        if (threadIdx.x < 16) h2d[(size_t)N_NODES * 16 + threadIdx.x] = 0;
        if (threadIdx.x < NBUCK) bcur[threadIdx.x] = threadIdx.x * BCAP;
    }
    int idx = blockIdx.x * 256 + threadIdx.x;
    if (idx < K_TOT * HID_F) {
        int k = idx >> 7, n = idx & 127;
        int p = k >> 7, f = k & 127;
        int si = f * HID_F + n;
        float v = (p == 0) ? (w1[si] + 0.1f * c1[si * 3])
                           : 0.1f * c1[si * 3 + p];
        Wb1[(((k >> 3) * HID_F) + n) * 8 + (k & 7)] = f2bf(v);
    } else {
        idx -= K_TOT * HID_F;
        if (idx < K_TOT * OUT_F) {
            int k = idx >> 6, n = idx & 63;
            int p = k >> 7, f = k & 127;
            int si = f * OUT_F + n;
            float v = (p == 0) ? (w2[si] + 0.1f * c2[si * 3])
                               : 0.1f * c2[si * 3 + p];
            Wb2[(((k >> 3) * OUT_F) + n) * 8 + (k & 7)] = f2bf(v);
        }
    }
}

// ---------------------------------------------------------------------------
// Scatter edges into fixed-capacity bucket windows (9b tgt | 23b src).
// tgt chunk staged in LDS once: hist and fill share one global read.
// ---------------------------------------------------------------------------
__global__ __launch_bounds__(256) void bucket_scatter(
    const int* __restrict__ src, const int* __restrict__ tgt,
    int* __restrict__ bcur, unsigned* __restrict__ spk)
{
    __shared__ int h[NBUCK];
    __shared__ int base[NBUCK];
    __shared__ int tg[EPB];                // 16 KB
    int tid = threadIdx.x;
    for (int i = tid; i < NBUCK; i += 256) h[i] = 0;
    __syncthreads();
    int e0 = blockIdx.x * EPB;
    int n = min(EPB, N_EDGES - e0);
    for (int i = tid; i < n; i += 256) {
        int t = tgt[e0 + i];
        tg[i] = t;
        atomicAdd(&h[t >> BK_BITS], 1);
    }
    __syncthreads();
    for (int i = tid; i < NBUCK; i += 256) {
        int c = h[i];
        base[i] = c ? atomicAdd(&bcur[i], c) : 0;
        h[i] = 0;
    }
    __syncthreads();
    for (int i = tid; i < n; i += 256) {
        int t = tg[i];
        int b = t >> BK_BITS;
        int pos = base[b] + atomicAdd(&h[b], 1);
        spk[pos] = ((unsigned)(t - (b << BK_BITS)) << 23) | (unsigned)src[e0 + i];
    }
}

// ---------------------------------------------------------------------------
// csr_build (merged degpad + finalize): per-bucket degree hist -> deg[];
// local padded prefix (bucket-local base b*PCAP) -> prow[]; fill padded CSR
// with LDS cursors; write sentinel pad slots.  One spk pass.
// ---------------------------------------------------------------------------
__global__ __launch_bounds__(256) void csr_build(
    const int* __restrict__ bcur, const unsigned* __restrict__ spk,
    int* __restrict__ deg, int* __restrict__ prow, int* __restrict__ csr_pad)
{
    __shared__ int d[BK_SIZE];             // hist, then cursors
    __shared__ int pst[BK_SIZE];           // padded segment ends
    __shared__ int s[256];
    int tid = threadIdx.x;
    int b = blockIdx.x;
    d[tid] = 0; d[tid + 256] = 0;
    __syncthreads();
    int e0 = b * BCAP, e1 = bcur[b];
    for (int i = e0 + tid; i < e1; i += 256)
        atomicAdd(&d[spk[i] >> 23], 1);
    __syncthreads();
    int nbase = b << BK_BITS;
    int a0 = d[2 * tid], a1c = d[2 * tid + 1];
    int n0 = nbase + 2 * tid, n1 = n0 + 1;
    if (n0 < N_NODES) deg[n0] = a0;
    if (n1 < N_NODES) deg[n1] = a1c;
    int pc0 = (n0 < N_NODES) ? PAD8(a0) : 0;
    int pc1 = (n1 < N_NODES) ? PAD8(a1c) : 0;
    int tsum = pc0 + pc1;
    s[tid] = tsum;
    __syncthreads();
    for (int o = 1; o < 256; o <<= 1) {
        int t = (tid >= o) ? s[tid - o] : 0;
        __syncthreads();
        s[tid] += t;
        __syncthreads();
    }
    int excl = s[tid] - tsum;
    int base = b * PCAP + excl;
    if (n0 < N_NODES) prow[n0] = base;
    if (n1 < N_NODES) prow[n1] = base + pc0;
    __syncthreads();                       // d[] hist consumed into a0/a1c
    d[2 * tid] = base;         pst[2 * tid]     = base + pc0;
    d[2 * tid + 1] = base + pc0; pst[2 * tid + 1] = base + pc0 + pc1;
    __syncthreads();
    // fill
    for (int i = e0 + tid; i < e1; i += 256) {
        unsigned pk = spk[i];
        int pos = atomicAdd(&d[pk >> 23], 1);
        csr_pad[pos] = (int)(pk & PK_SRC_MASK);
    }
    __syncthreads();
    // sentinel pad slots
    for (int i = tid; i < BK_SIZE; i += 256) {
        int nd = nbase + i;
        if (nd < N_NODES) {
            int kend = pst[i];
            for (int k = d[i]; k < kend; ++k) csr_pad[k] = N_NODES;
        }
    }
}

// ---------------------------------------------------------------------------
// KAN1 via MFMA bf16.  Staging computes the bf16 basis (x, x^2, x^3) into
// LDS once; A-frags are single ds_read_b128.  Epilogue: +bias, ReLU,
// fp8-pack 4 cols per dword (permuted: dword d = feats 64*(d>>4)+(d&15)+16b).
// ---------------------------------------------------------------------------
__global__ __launch_bounds__(256) void kan1_mfma(
    const float* __restrict__ x, const short* __restrict__ Wb,
    const float* __restrict__ bias, unsigned* __restrict__ h1d)
{
    __shared__ short sb[64 * BST];   // 50 KB
    const int tid  = threadIdx.x;
    const int lane = tid & 63;
    const int wave = tid >> 6;
    const int node0 = blockIdx.x * 64;
    const int q = lane >> 4, r = lane & 15;

#pragma unroll
    for (int it = 0; it < 8; ++it) {
        int idx = tid + 256 * it;            // 2048 float4 groups
        int m = idx >> 5, c4 = (idx & 31) * 4;
        int gm = min(node0 + m, N_NODES - 1);
        float4 v = *(const float4*)(x + (size_t)gm * IN_F + c4);
        float vv[4] = {v.x, v.y, v.z, v.w};
        s4v p0, p1, p2;
#pragma unroll
        for (int t = 0; t < 4; ++t) {
            float e = vv[t], e2 = e * e, e3 = e2 * e;
            p0[t] = f2bf(e); p1[t] = f2bf(e2); p2[t] = f2bf(e3);
        }
        short* row = sb + m * BST + c4;
        *(s4v*)(row)       = p0;
        *(s4v*)(row + 128) = p1;
        *(s4v*)(row + 256) = p2;
    }
    __syncthreads();

    const int wm = (wave & 1) * 32;
    const int wn = (wave >> 1) * 64;

    f4v acc[2][4];
#pragma unroll
    for (int i = 0; i < 2; ++i)
#pragma unroll
        for (int j = 0; j < 4; ++j)
            acc[i][j] = (f4v){0.f, 0.f, 0.f, 0.f};

    float bj[4];
#pragma unroll
    for (int j = 0; j < 4; ++j) bj[j] = bias[wn + j * 16 + r];

#pragma unroll
    for (int kb = 0; kb < 12; ++kb) {
        const int col = kb * 32 + q * 8;
        s8v afrag[2];
#pragma unroll
        for (int i = 0; i < 2; ++i)
            afrag[i] = *(const s8v*)(sb + (wm + i * 16 + r) * BST + col);
#pragma unroll
        for (int j = 0; j < 4; ++j) {
            const s8v b = *(const s8v*)(Wb + (((kb * 4 + q) * HID_F) + wn + j * 16 + r) * 8);
            acc[0][j] = __builtin_amdgcn_mfma_f32_16x16x32_bf16(afrag[0], b, acc[0][j], 0, 0, 0);
            acc[1][j] = __builtin_amdgcn_mfma_f32_16x16x32_bf16(afrag[1], b, acc[1][j], 0, 0, 0);
        }
    }

    const int dci = ((wn >> 6) << 4) + r;
#pragma unroll
    for (int i = 0; i < 2; ++i)
#pragma unroll
        for (int e = 0; e < 4; ++e) {
            int grow = node0 + wm + i * 16 + q * 4 + e;
            if (grow < N_NODES) {
                float v0 = fmaxf(acc[i][0][e] + bj[0], 0.f);
                float v1 = fmaxf(acc[i][1][e] + bj[1], 0.f);
                float v2 = fmaxf(acc[i][2][e] + bj[2], 0.f);
                float v3 = fmaxf(acc[i][3][e] + bj[3], 0.f);
                int pk = __builtin_amdgcn_cvt_pk_fp8_f32(v0, v1, 0, false);
                pk = __builtin_amdgcn_cvt_pk_fp8_f32(v2, v3, pk, true);
                h1d[(size_t)grow * 32 + dci] = (unsigned)pk;
            }
        }
}

// ---------------------------------------------------------------------------
// Gather-aggregate over 128 fp8 feats.  TWO nodes per wave; lane loads one
// dword (4 fp8) per message; cvt_pk decode; depth-4 chains.  Padded count
// from PAD8(deg).  Output a1 fp8, same permuted layout.
// ---------------------------------------------------------------------------
__global__ __launch_bounds__(256) void gather128(
    const unsigned* __restrict__ h1d, const int* __restrict__ prow,
    const int* __restrict__ deg, const int* __restrict__ csr_pad,
    unsigned* __restrict__ a1d)
{
    const int lane  = threadIdx.x & 63;
    const int wave  = threadIdx.x >> 6;
    const int hl    = lane & 31;
    const int half  = lane >> 5;
    const int hbase = half << 5;
    const int node  = blockIdx.x * 8 + wave * 2 + half;   // grid exact: 12500*8

    int p0 = prow[node];
    int cnt = PAD8(deg[node]);                            // multiple of 8
    int p1 = p0 + cnt;
    int cmax = max(cnt, __shfl_xor(cnt, 32));

    float acc[4][4];
#pragma unroll
    for (int t = 0; t < 4; ++t)
#pragma unroll
        for (int b = 0; b < 4; ++b) acc[t][b] = 0.f;

    for (int base = 0; base < cmax; base += 32) {
        int idx = max(min(p0 + base + hl, p1 - 1), 0);
        int sreg = csr_pad[idx];
        int lim = min(32, cmax - base);
        for (int j = 0; j < lim; j += 4) {
            if (base + j < cnt) {
                unsigned u[4];
#pragma unroll
                for (int t = 0; t < 4; ++t) {
                    int sj = __shfl(sreg, hbase + j + t);
                    u[t] = h1d[(size_t)sj * 32 + hl];
                }
#pragma unroll
                for (int t = 0; t < 4; ++t) {
                    f2v lo = __builtin_amdgcn_cvt_pk_f32_fp8(u[t], false);
                    f2v hi = __builtin_amdgcn_cvt_pk_f32_fp8(u[t], true);
                    acc[t][0] += lo.x; acc[t][1] += lo.y;
                    acc[t][2] += hi.x; acc[t][3] += hi.y;
                }
            }
        }
    }

    float s0 = (acc[0][0] + acc[1][0]) + (acc[2][0] + acc[3][0]);
    float s1 = (acc[0][1] + acc[1][1]) + (acc[2][1] + acc[3][1]);
    float s2 = (acc[0][2] + acc[1][2]) + (acc[2][2] + acc[3][2]);
    float s3 = (acc[0][3] + acc[1][3]) + (acc[2][3] + acc[3][3]);
    int pk = __builtin_amdgcn_cvt_pk_fp8_f32(s0, s1, 0, false);
    pk = __builtin_amdgcn_cvt_pk_fp8_f32(s2, s3, pk, true);
    a1d[(size_t)node * 32 + hl] = (unsigned)pk;
}

// ---------------------------------------------------------------------------
// KAN2 via MFMA bf16.  Staging decodes fp8 a1 (permuted), applies 1/deg,
// computes the bf16 basis into LDS (canonical order, 3 planes).
// Epilogue: fp8 h2 pair-packed (ushort (wn>>1)+r = feats wn+r, wn+16+r).
// ---------------------------------------------------------------------------
__global__ __launch_bounds__(256) void kan2_mfma(
    const unsigned* __restrict__ a1d, const int* __restrict__ deg,
    const short* __restrict__ Wb, const float* __restrict__ bias,
    unsigned short* __restrict__ h2s)
{
    __shared__ short sb[64 * BST];   // 50 KB
    const int tid  = threadIdx.x;
    const int lane = tid & 63;
    const int wave = tid >> 6;
    const int node0 = blockIdx.x * 64;
    const int q = lane >> 4, r = lane & 15;

#pragma unroll
    for (int gi = 0; gi < 2; ++gi) {
        int g = tid + 256 * gi;
        int m = g >> 3, cg = (g & 7) * 4;
        int gm = min(node0 + m, N_NODES - 1);
        float di = 1.0f / fmaxf((float)deg[gm], 1.0f);
        uint4 u4 = *(const uint4*)(a1d + (size_t)gm * 32 + cg);
        unsigned uw[4] = {u4.x, u4.y, u4.z, u4.w};
        float xv[4][4];
#pragma unroll
        for (int j = 0; j < 4; ++j) {
            f2v lo = __builtin_amdgcn_cvt_pk_f32_fp8(uw[j], false);
            f2v hi = __builtin_amdgcn_cvt_pk_f32_fp8(uw[j], true);
            xv[j][0] = lo.x * di; xv[j][1] = lo.y * di;
            xv[j][2] = hi.x * di; xv[j][3] = hi.y * di;
        }
        int fb = ((cg >> 4) << 6) + (cg & 15);
#pragma unroll
        for (int b = 0; b < 4; ++b) {
            s4v p0, p1, p2;
#pragma unroll
            for (int j = 0; j < 4; ++j) {
                float e = xv[j][b], e2 = e * e, e3 = e2 * e;
                p0[j] = f2bf(e); p1[j] = f2bf(e2); p2[j] = f2bf(e3);
            }
            short* row = sb + m * BST + fb + 16 * b;
            *(s4v*)(row)       = p0;
            *(s4v*)(row + 128) = p1;
            *(s4v*)(row + 256) = p2;
        }
    }
    __syncthreads();

    const int wm = (wave & 1) * 32;
    const int wn = (wave >> 1) * 32;

    f4v acc[2][2];
#pragma unroll
    for (int i = 0; i < 2; ++i)
#pragma unroll
        for (int j = 0; j < 2; ++j)
            acc[i][j] = (f4v){0.f, 0.f, 0.f, 0.f};

    float bj[2];
#pragma unroll
    for (int j = 0; j < 2; ++j) bj[j] = bias[wn + j * 16 + r];

#pragma unroll
    for (int kb = 0; kb < 12; ++kb) {
        const int col = kb * 32 + q * 8;
        s8v afrag[2];
#pragma unroll
        for (int i = 0; i < 2; ++i)
            afrag[i] = *(const s8v*)(sb + (wm + i * 16 + r) * BST + col);
#pragma unroll
        for (int j = 0; j < 2; ++j) {
            const s8v b = *(const s8v*)(Wb + (((kb * 4 + q) * OUT_F) + wn + j * 16 + r) * 8);
            acc[0][j] = __builtin_amdgcn_mfma_f32_16x16x32_bf16(afrag[0], b, acc[0][j], 0, 0, 0);
            acc[1][j] = __builtin_amdgcn_mfma_f32_16x16x32_bf16(afrag[1], b, acc[1][j], 0, 0, 0);
        }
    }

    const int sslot = (wn >> 1) + r;           // ushort slot in h2 row
#pragma unroll
    for (int i = 0; i < 2; ++i)
#pragma unroll
        for (int e = 0; e < 4; ++e) {
            int grow = node0 + wm + i * 16 + q * 4 + e;
            if (grow < N_NODES) {
                float vlo = acc[i][0][e] + bj[0];
                float vhi = acc[i][1][e] + bj[1];
                int pk = __builtin_amdgcn_cvt_pk_fp8_f32(vlo, vhi, 0, false);
                h2s[(size_t)grow * 32 + sslot] = (unsigned short)(pk & 0xffff);
            }
        }
}

// ---------------------------------------------------------------------------
// Gather-aggregate over 64 fp8 feats + 1/deg + log_softmax.
// TWO nodes per wave; lane hl loads ushort (2 fp8 feats):
//   f_lo = 32*(hl>>4) + (hl&15), f_hi = f_lo + 16.
// ---------------------------------------------------------------------------
__global__ __launch_bounds__(256) void gather64_lsm(
    const unsigned short* __restrict__ h2s, const int* __restrict__ deg,
    const int* __restrict__ prow, const int* __restrict__ csr_pad,
    float* __restrict__ out)
{
    const int lane = threadIdx.x & 63;
    const int wave = threadIdx.x >> 6;
    const int hl   = lane & 31;
    const int half = lane >> 5;
    const int node = blockIdx.x * 8 + wave * 2 + half;   // grid exact: 12500*8

    int p0 = prow[node];
    int degr = deg[node];
    int cnt = PAD8(degr);
    int p1 = p0 + cnt;
    int cmax = max(cnt, __shfl_xor(cnt, 32));

    float alo[8], ahi[8];
#pragma unroll
    for (int t = 0; t < 8; ++t) { alo[t] = 0.f; ahi[t] = 0.f; }

    for (int base = 0; base < cmax; base += 32) {
        int idx = max(min(p0 + base + hl, p1 - 1), 0);
        int sreg = csr_pad[idx];
        int lim = min(32, cmax - base);
        for (int j = 0; j < lim; j += 8) {
            if (base + j < cnt) {
                int u[8];
#pragma unroll
                for (int t = 0; t < 8; ++t) {
                    int sj = __shfl(sreg, (half << 5) + j + t);
                    u[t] = (int)h2s[(size_t)sj * 32 + hl];
                }
#pragma unroll
                for (int t = 0; t < 8; ++t) {
                    alo[t] += __builtin_amdgcn_cvt_f32_fp8(u[t], 0);
                    ahi[t] += __builtin_amdgcn_cvt_f32_fp8(u[t], 1);
                }
            }
        }
    }
    float slo = ((alo[0] + alo[1]) + (alo[2] + alo[3])) + ((alo[4] + alo[5]) + (alo[6] + alo[7]));
    float shi = ((ahi[0] + ahi[1]) + (ahi[2] + ahi[3])) + ((ahi[4] + ahi[5]) + (ahi[6] + ahi[7]));

    float di = 1.0f / fmaxf((float)degr, 1.0f);
    float vlo = slo * di, vhi = shi * di;

    float m = fmaxf(vlo, vhi);
#pragma unroll
    for (int off = 16; off >= 1; off >>= 1)
        m = fmaxf(m, __shfl_xor(m, off));     // stays within the 32-lane half
    float e = expf(vlo - m) + expf(vhi - m);
#pragma unroll
    for (int off = 16; off >= 1; off >>= 1)
        e += __shfl_xor(e, off);
    float ls = logf(e);

    const int f_lo = ((hl >> 4) << 5) + (hl & 15);
    out[(size_t)node * OUT_F + f_lo]      = vlo - m - ls;
    out[(size_t)node * OUT_F + f_lo + 16] = vhi - m - ls;
}

// ---------------------------------------------------------------------------
extern "C" void kernel_launch(void* const* d_in, const int* in_sizes, int n_in,
                              void* d_out, int out_size, void* d_ws, size_t ws_size,
                              hipStream_t stream)
{
    const float* x  = (const float*)d_in[0];
    const int*   ei = (const int*)d_in[1];
    const float* w1 = (const float*)d_in[2];
    const float* b1 = (const float*)d_in[3];
    const float* c1 = (const float*)d_in[4];
    const float* w2 = (const float*)d_in[5];
    const float* b2 = (const float*)d_in[6];
    const float* c2 = (const float*)d_in[7];
    float* out = (float*)d_out;

    const int* src = ei;            // edge_index[0]
    const int* tgt = ei + N_EDGES;  // edge_index[1]

    char* ws = (char*)d_ws;
    size_t off = 0;
    auto carve = [&](size_t bytes) -> void* {
        void* p = ws + off;
        off = (off + bytes + 255) & ~(size_t)255;
        return p;
    };
    short*    Wb1       = (short*)carve((size_t)K_TOT * HID_F * 2);
    short*    Wb2       = (short*)carve((size_t)K_TOT * OUT_F * 2);
    int*      deg       = (int*)carve((size_t)N_NODES * 4);
    int*      prow      = (int*)carve((size_t)N_NODES * 4);
    int*      bcur      = (int*)carve((size_t)NBUCK * 4);
    unsigned* spk       = (unsigned*)carve((size_t)NBUCK * BCAP * 4);
    int*      csr_pad   = (int*)carve((size_t)NBUCK * PCAP * 4);
    unsigned* h1d       = (unsigned*)carve(((size_t)N_NODES + 1) * 128);  // fp8, permuted
    unsigned* a1d       = (unsigned*)carve((size_t)N_NODES * 128);        // fp8, permuted
    unsigned short* h2s = (unsigned short*)carve(((size_t)N_NODES + 1) * 64); // fp8 pairs

    const int grid_mm = (N_NODES + 63) / 64;   // 1563

    // --- weights + sentinel rows + bucket cursor init ------------------------
    fold_weights_bf16<<<(K_TOT * HID_F + K_TOT * OUT_F + 255) / 256, 256, 0, stream>>>(
        w1, c1, w2, c2, Wb1, Wb2, h1d, (unsigned*)h2s, bcur);

    // --- CSR build: scatter + merged build (2 kernels) -----------------------
    bucket_scatter<<<NBLK_SORT, 256, 0, stream>>>(src, tgt, bcur, spk);
    csr_build<<<NBUCK, 256, 0, stream>>>(bcur, spk, deg, prow, csr_pad);

    // --- layer 1 -------------------------------------------------------------
    kan1_mfma<<<grid_mm, 256, 0, stream>>>(x, Wb1, b1, h1d);

    // --- aggregate 1 (gather, fp8 rows, 2 nodes/wave) ------------------------
    gather128<<<(N_NODES + 7) / 8, 256, 0, stream>>>(h1d, prow, deg, csr_pad, a1d);

    // --- layer 2 (fp8 in, fp8 out) -------------------------------------------
    kan2_mfma<<<grid_mm, 256, 0, stream>>>(a1d, deg, Wb2, b2, h2s);

    // --- aggregate 2 + log_softmax (fused, 2 nodes/wave, fp8) ----------------
    gather64_lsm<<<(N_NODES + 7) / 8, 256, 0, stream>>>(
        h2s, deg, prow, csr_pad, out);
}